// Round 12
// baseline (108.540 us; speedup 1.0000x reference)
//
#include <hip/hip_runtime.h>

// Problem constants
#define BB 4
#define RR 384
#define CC 384
#define EE 512
#define HH 16
#define DD 32
#define MROWS 1536   // B*R = B*C
#define MAXE 128     // edge-list stride (nE ~ 38 +- 6; 128 = 15 sigma)

typedef __attribute__((ext_vector_type(8))) short bf16x8;   // 8 bf16 = 4 VGPRs
typedef __attribute__((ext_vector_type(4))) float f32x4;

// ---------------------------------------------------------------------------
// f32 -> (hi, lo) bf16 split, RNE both times. x ~= hi + lo with ~2^-16 rel err.
// ---------------------------------------------------------------------------
__device__ __forceinline__ void split1(float x, ushort& h, ushort& l)
{
    const unsigned u = __float_as_uint(x);
    const unsigned r = (u + 0x7fffu + ((u >> 16) & 1u)) >> 16;
    h = (ushort)r;
    const float hf = __uint_as_float(r << 16);
    const float lo = x - hf;
    const unsigned u2 = __float_as_uint(lo);
    l = (ushort)((u2 + 0x7fffu + ((u2 >> 16) & 1u)) >> 16);
}

// Packed fragment address for element (r, k) of a [rows][512] matrix:
// lane l of the wave covering (r-tile, k-tile) reads elems [l*8, l*8+8).
__device__ __forceinline__ int packed_addr(int r, int k)
{
    return ((r >> 4) * 16 + (k >> 5)) * 512 + ((k >> 3) & 3) * 128 + (r & 15) * 8 + (k & 7);
}

// ---------------------------------------------------------------------------
// Split kernel: 6 arrays -> hi/lo bf16 planes in PACKED fragment layout.
// ---------------------------------------------------------------------------
__global__ __launch_bounds__(256) void split_kernel(
    const float* __restrict__ rowe, const float* __restrict__ cole,
    const float* __restrict__ Wq, const float* __restrict__ Wk,
    const float* __restrict__ Wv, const float* __restrict__ Wo,
    ushort* __restrict__ reh, ushort* __restrict__ rel,
    ushort* __restrict__ ceh, ushort* __restrict__ cel,
    ushort* __restrict__ wqh, ushort* __restrict__ wql,
    ushort* __restrict__ wkh, ushort* __restrict__ wkl,
    ushort* __restrict__ wvh, ushort* __restrict__ wvl,
    ushort* __restrict__ woh, ushort* __restrict__ wol)
{
    const float* src; ushort* dh; ushort* dl; int n;
    switch (blockIdx.y) {
    case 0: src = rowe; dh = reh; dl = rel; n = MROWS * EE; break;
    case 1: src = cole; dh = ceh; dl = cel; n = MROWS * EE; break;
    case 2: src = Wq;   dh = wqh; dl = wql; n = EE * EE;    break;
    case 3: src = Wk;   dh = wkh; dl = wkl; n = EE * EE;    break;
    case 4: src = Wv;   dh = wvh; dl = wvl; n = EE * EE;    break;
    default: src = Wo;  dh = woh; dl = wol; n = EE * EE;    break;
    }
    const int i4 = blockIdx.x * 256 + threadIdx.x;
    if (i4 * 4 >= n) return;
    const float4 v = ((const float4*)src)[i4];
    ushort4 hs, ls;
    split1(v.x, hs.x, ls.x);
    split1(v.y, hs.y, ls.y);
    split1(v.z, hs.z, ls.z);
    split1(v.w, hs.w, ls.w);
    const int e0 = i4 * 4;
    const int dst = packed_addr(e0 >> 9, e0 & 511);   // (k&7) in {0,4}: aligned
    *(ushort4*)(dh + dst) = hs;
    *(ushort4*)(dl + dst) = ls;
}

// ---------------------------------------------------------------------------
// bf16x3 emulated-f32 GEMM on packed operands.
// ---------------------------------------------------------------------------
__device__ __forceinline__ void gemm_bf16x3_body(
    const ushort* __restrict__ Ahi, const ushort* __restrict__ Alo,
    const ushort* __restrict__ Whi, const ushort* __restrict__ Wlo,
    const float* __restrict__ bias, float* __restrict__ Y,
    int Mt, int Nt0)
{
    constexpr int N = 512;
    const int lane = threadIdx.x & 63;
    const int col = lane & 15, kgrp = lane >> 4;

    const ushort* pah = Ahi + (size_t)Mt * 8192 + lane * 8;
    const ushort* pal = Alo + (size_t)Mt * 8192 + lane * 8;
    const ushort* pbh = Whi + (size_t)Nt0 * 8192 + lane * 8;
    const ushort* pbl = Wlo + (size_t)Nt0 * 8192 + lane * 8;

    f32x4 acc0 = {}, acc1 = {}, acc2 = {}, acc3 = {};

    bf16x8 ah  = *(const bf16x8*)(pah);
    bf16x8 al  = *(const bf16x8*)(pal);
    bf16x8 bh0 = *(const bf16x8*)(pbh);
    bf16x8 bh1 = *(const bf16x8*)(pbh + 8192);
    bf16x8 bh2 = *(const bf16x8*)(pbh + 16384);
    bf16x8 bh3 = *(const bf16x8*)(pbh + 24576);
    bf16x8 bl0 = *(const bf16x8*)(pbl);
    bf16x8 bl1 = *(const bf16x8*)(pbl + 8192);
    bf16x8 bl2 = *(const bf16x8*)(pbl + 16384);
    bf16x8 bl3 = *(const bf16x8*)(pbl + 24576);

#pragma unroll 4
    for (int kt = 0; kt < 16; ++kt) {
        bf16x8 nah = ah, nal = al;
        bf16x8 nbh0 = bh0, nbh1 = bh1, nbh2 = bh2, nbh3 = bh3;
        bf16x8 nbl0 = bl0, nbl1 = bl1, nbl2 = bl2, nbl3 = bl3;
        if (kt < 15) {
            const int ko = (kt + 1) * 512;
            nah  = *(const bf16x8*)(pah + ko);
            nal  = *(const bf16x8*)(pal + ko);
            nbh0 = *(const bf16x8*)(pbh + ko);
            nbh1 = *(const bf16x8*)(pbh + ko + 8192);
            nbh2 = *(const bf16x8*)(pbh + ko + 16384);
            nbh3 = *(const bf16x8*)(pbh + ko + 24576);
            nbl0 = *(const bf16x8*)(pbl + ko);
            nbl1 = *(const bf16x8*)(pbl + ko + 8192);
            nbl2 = *(const bf16x8*)(pbl + ko + 16384);
            nbl3 = *(const bf16x8*)(pbl + ko + 24576);
        }
        acc0 = __builtin_amdgcn_mfma_f32_16x16x32_bf16(ah, bh0, acc0, 0, 0, 0);
        acc0 = __builtin_amdgcn_mfma_f32_16x16x32_bf16(ah, bl0, acc0, 0, 0, 0);
        acc0 = __builtin_amdgcn_mfma_f32_16x16x32_bf16(al, bh0, acc0, 0, 0, 0);
        acc1 = __builtin_amdgcn_mfma_f32_16x16x32_bf16(ah, bh1, acc1, 0, 0, 0);
        acc1 = __builtin_amdgcn_mfma_f32_16x16x32_bf16(ah, bl1, acc1, 0, 0, 0);
        acc1 = __builtin_amdgcn_mfma_f32_16x16x32_bf16(al, bh1, acc1, 0, 0, 0);
        acc2 = __builtin_amdgcn_mfma_f32_16x16x32_bf16(ah, bh2, acc2, 0, 0, 0);
        acc2 = __builtin_amdgcn_mfma_f32_16x16x32_bf16(ah, bl2, acc2, 0, 0, 0);
        acc2 = __builtin_amdgcn_mfma_f32_16x16x32_bf16(al, bh2, acc2, 0, 0, 0);
        acc3 = __builtin_amdgcn_mfma_f32_16x16x32_bf16(ah, bh3, acc3, 0, 0, 0);
        acc3 = __builtin_amdgcn_mfma_f32_16x16x32_bf16(ah, bl3, acc3, 0, 0, 0);
        acc3 = __builtin_amdgcn_mfma_f32_16x16x32_bf16(al, bh3, acc3, 0, 0, 0);
        ah = nah; al = nal;
        bh0 = nbh0; bh1 = nbh1; bh2 = nbh2; bh3 = nbh3;
        bl0 = nbl0; bl1 = nbl1; bl2 = nbl2; bl3 = nbl3;
    }

    const f32x4 accs[4] = {acc0, acc1, acc2, acc3};
#pragma unroll
    for (int t = 0; t < 4; ++t) {
        const int n = (Nt0 + t) * 16 + col;
        const float bn = bias[n];
#pragma unroll
        for (int j = 0; j < 4; ++j) {
            const int m = Mt * 16 + kgrp * 4 + j;
            Y[m * N + n] = accs[t][j] + bn;
        }
    }
}

// XCD-grouping swizzle: l = a + 8b + 64c (a,b in [0,8), c in [0,3))
//  -> Bm = 3a + c (m-strip), Bx = b. Same-Bm blocks share l%8 -> same XCD.
__global__ __launch_bounds__(256) void qkv_kernel(
    const ushort* __restrict__ reh, const ushort* __restrict__ rel,
    const ushort* __restrict__ ceh, const ushort* __restrict__ cel,
    const ushort* __restrict__ wqh, const ushort* __restrict__ wql,
    const ushort* __restrict__ wkh, const ushort* __restrict__ wkl,
    const ushort* __restrict__ wvh, const ushort* __restrict__ wvl,
    const float* __restrict__ bq, const float* __restrict__ bk,
    const float* __restrict__ bv,
    float* __restrict__ Qo, float* __restrict__ Ko, float* __restrict__ Vo)
{
    const int l = blockIdx.x + (blockIdx.y << 3);
    const int Bm = (l & 7) * 3 + (l >> 6);
    const int Bx = (l >> 3) & 7;
    const int Mt = Bm * 4 + (threadIdx.x >> 6);
    const int Nt0 = Bx * 4;
    if (blockIdx.z == 0)      gemm_bf16x3_body(reh, rel, wqh, wql, bq, Qo, Mt, Nt0);
    else if (blockIdx.z == 1) gemm_bf16x3_body(ceh, cel, wkh, wkl, bk, Ko, Mt, Nt0);
    else                      gemm_bf16x3_body(ceh, cel, wvh, wvl, bv, Vo, Mt, Nt0);
}

__global__ __launch_bounds__(256) void oproj_kernel(
    const ushort* __restrict__ hbh, const ushort* __restrict__ hbl,
    const ushort* __restrict__ woh, const ushort* __restrict__ wol,
    const float* __restrict__ bo, float* __restrict__ out)
{
    const int l = blockIdx.x + (blockIdx.y << 3);
    const int Bm = (l & 7) * 3 + (l >> 6);
    const int Bx = (l >> 3) & 7;
    const int Mt = Bm * 4 + (threadIdx.x >> 6);
    const int Nt0 = Bx * 4;
    gemm_bf16x3_body(hbh, hbl, woh, wol, bo, out, Mt, Nt0);
}

// ---------------------------------------------------------------------------
// Vsum kernel: Vsum[b][h][d] = sum_c V[b][c][h*32+d]. Grid (16,4), 256 thr.
// ---------------------------------------------------------------------------
__global__ __launch_bounds__(256) void vsum_kernel(const float* __restrict__ Vb,
                                                   float* __restrict__ Vsum)
{
    __shared__ float part[8][32];
    const int h = blockIdx.x, b = blockIdx.y;
    const int d = threadIdx.x & 31, g = threadIdx.x >> 5;
    float acc = 0.f;
    for (int c = g; c < CC; c += 8)
        acc += Vb[(b * CC + c) * EE + h * DD + d];
    part[g][d] = acc;
    __syncthreads();
    if (g == 0) {
        float s = 0.f;
#pragma unroll
        for (int gg = 0; gg < 8; ++gg) s += part[gg][d];
        Vsum[(b * HH + h) * DD + d] = s;
    }
}

// ---------------------------------------------------------------------------
// Edge precompute: one wave per (b,r). Ballot-compacted edge lists to ws.
// ---------------------------------------------------------------------------
__global__ __launch_bounds__(64) void edges_kernel(
    const float* __restrict__ cost,
    int* __restrict__ ecb, float* __restrict__ ecwb, int* __restrict__ nEb)
{
    const int r = blockIdx.x, b = blockIdx.y;
    const int rowIdx = b * RR + r;
    const int lane = threadIdx.x;
    const float* crow = cost + (size_t)rowIdx * CC;
    const unsigned long long prefix = (1ull << lane) - 1ull;
    int nE = 0;
#pragma unroll
    for (int j = 0; j < 6; ++j) {
        const float cw = crow[lane + 64 * j];
        const unsigned long long mk = __ballot(cw > 0.f);
        if (cw > 0.f) {
            const int slot = nE + __popcll(mk & prefix);
            if (slot < MAXE) {
                ecb [rowIdx * MAXE + slot] = lane + 64 * j;
                ecwb[rowIdx * MAXE + slot] = cw;
            }
        }
        nE += __popcll(mk);
    }
    if (lane == 0) nEb[rowIdx] = (nE < MAXE) ? nE : MAXE;
}

// ---------------------------------------------------------------------------
// Edge scorer: dot(q,k) -> per-head 2x16x1 MLP -> p = exp(tanh*10 - 10).
// All q / MLP params come from wave-uniform addresses -> SGPRs.
// ---------------------------------------------------------------------------
__device__ __forceinline__ float score_edge(
    int c, float cw, int b, int h,
    const float* __restrict__ qrow, const float* __restrict__ Kb,
    const float* __restrict__ w10p, const float* __restrict__ w11p,
    const float* __restrict__ b1p, const float* __restrict__ w2p, float b2h)
{
    const float* kp = Kb + ((size_t)b * CC + c) * EE + h * DD;
    float d0 = 0.f, d1 = 0.f, d2 = 0.f, d3 = 0.f;
#pragma unroll
    for (int dq = 0; dq < 8; ++dq) {
        const float4 kv = *(const float4*)(kp + dq * 4);
        d0 = fmaf(qrow[dq * 4 + 0], kv.x, d0);
        d1 = fmaf(qrow[dq * 4 + 1], kv.y, d1);
        d2 = fmaf(qrow[dq * 4 + 2], kv.z, d2);
        d3 = fmaf(qrow[dq * 4 + 3], kv.w, d3);
    }
    const float dot = ((d0 + d1) + (d2 + d3)) * 0.17677669529663687f;
    float l0 = b2h, l1 = 0.f;
#pragma unroll
    for (int mm = 0; mm < 16; mm += 2) {
        const float h0 = fmaf(dot, w10p[mm],     fmaf(cw, w11p[mm],     b1p[mm]));
        const float h1 = fmaf(dot, w10p[mm + 1], fmaf(cw, w11p[mm + 1], b1p[mm + 1]));
        l0 = fmaf(fmaxf(h0, 0.f), w2p[mm],     l0);
        l1 = fmaf(fmaxf(h1, 0.f), w2p[mm + 1], l1);
    }
    // s = tanh(l)*10; p = exp(s-10) = exp(-20/(e^{2l}+1)); bounded (no ovf).
    const float ex = __expf(2.f * (l0 + l1));
    return __expf(-20.f / (ex + 1.f));
}

// ---------------------------------------------------------------------------
// Semi-sparse attention: TWO WAVES per block (128 thr, proven in R11); each
// wave = one (b, r, head-PAIR) using R9's exact proven per-wave code (~40
// VGPR, under the 64-VGPR occupancy cliff that sank R11's 4-head waves).
// 16 WG/CU x 2 waves = 32 waves/CU possible -> occupancy ceiling lifted.
// Waves share NOTHING (no LDS, no __syncthreads; shfl is intra-wave).
// Fixed-max-10 softmax (scores tanh*10 in (-10,10), beta<=10):
//   out = (sum_E (p_e - e^{b-10}) V_e + e^{b-10} Vsum) / (sum p + (C-nE) e^{b-10})
// Grid (8, RR, 2): blockIdx.x = (b,hh) -> XCD pin (R6: FETCH -55%).
// ---------------------------------------------------------------------------
__global__ __launch_bounds__(128, 8) void attn_kernel(
    const float* __restrict__ Qb, const float* __restrict__ Kb,
    const float* __restrict__ Vb,
    const int* __restrict__ ecb, const float* __restrict__ ecwb,
    const int* __restrict__ nEb,
    const float* __restrict__ W1, const float* __restrict__ b1,
    const float* __restrict__ W2, const float* __restrict__ b2,
    const float* __restrict__ beta,
    const float* __restrict__ Vsum,
    ushort* __restrict__ Hbh, ushort* __restrict__ Hbl)
{
    const int combo = blockIdx.x;            // 0..7 -> XCD
    const int b = combo >> 1, hh = combo & 1;
    const int r = blockIdx.y;
    const int wave = threadIdx.x >> 6;       // 0..1 -> head-pair in quad
    const int h0 = hh * 8 + blockIdx.z * 4 + wave * 2;  // heads h0, h0+1
    const int lane = threadIdx.x & 63;
    const int rowIdx = b * RR + r;

    const int nE = nEb[rowIdx];              // wave-uniform
    const float b2h0 = b2[h0], b2h1 = b2[h0 + 1];
    const float ebeta0 = __expf(beta[h0] - 10.f);
    const float ebeta1 = __expf(beta[h0 + 1] - 10.f);

    const float* qrow0 = Qb + (size_t)rowIdx * EE + h0 * DD;   // uniform -> SGPR
    const float* qrow1 = qrow0 + DD;
    const float* w10p0 = W1 + h0 * 32;       const float* w10p1 = w10p0 + 32;
    const float* w11p0 = W1 + h0 * 32 + 16;  const float* w11p1 = w11p0 + 32;
    const float* b1p0  = b1 + h0 * 16;       const float* b1p1  = b1p0 + 16;
    const float* w2p0  = W2 + h0 * 16;       const float* w2p1  = w2p0 + 16;

    // ---- scoring: lane e = edge e, both heads (independent chains) ----
    int c0 = 0, c1 = 0;
    float pA0 = 0.f, pB0 = 0.f, pA1 = 0.f, pB1 = 0.f;
    if (lane < nE) {
        c0 = ecb[rowIdx * MAXE + lane];
        const float cw = ecwb[rowIdx * MAXE + lane];
        pA0 = score_edge(c0, cw, b, h0,     qrow0, Kb, w10p0, w11p0, b1p0, w2p0, b2h0);
        pB0 = score_edge(c0, cw, b, h0 + 1, qrow1, Kb, w10p1, w11p1, b1p1, w2p1, b2h1);
    }
    if (nE > 64) {                           // wave-uniform rare branch
        const int e1 = lane + 64;
        if (e1 < nE) {
            c1 = ecb[rowIdx * MAXE + e1];
            const float cw = ecwb[rowIdx * MAXE + e1];
            pA1 = score_edge(c1, cw, b, h0,     qrow0, Kb, w10p0, w11p0, b1p0, w2p0, b2h0);
            pB1 = score_edge(c1, cw, b, h0 + 1, qrow1, Kb, w10p1, w11p1, b1p1, w2p1, b2h1);
        }
    }

    // ---- Z: full-wave reduce, both heads ----
    float ZA = pA0 + pA1, ZB = pB0 + pB1;
#pragma unroll
    for (int off = 1; off < 64; off <<= 1) {
        ZA += __shfl_xor(ZA, off);
        ZB += __shfl_xor(ZB, off);
    }

    // ---- PV: 2 edges/iter, 2 heads -> 2 loads + 2 FMA chains in flight ----
    const int half = lane >> 5, d = lane & 31;
    const float wA0 = pA0 - ebeta0, wB0 = pB0 - ebeta1;
    float accA = 0.f, accB = 0.f;
    const int lim0 = (nE < 64) ? nE : 64;
    for (int eo = 0; eo < lim0; eo += 2) {
        const int e = eo + half;
        const float wa = __shfl(wA0, e & 63);
        const float wb = __shfl(wB0, e & 63);
        const int   ce = __shfl(c0, e & 63);   // c0=0 on invalid lanes: safe
        const bool ok = e < lim0;
        const size_t vb0 = ((size_t)b * CC + ce) * EE + h0 * DD + d;
        const float vA = Vb[vb0];
        const float vB = Vb[vb0 + DD];
        accA = fmaf(ok ? wa : 0.f, vA, accA);
        accB = fmaf(ok ? wb : 0.f, vB, accB);
    }
    if (nE > 64) {
        const float wA1 = pA1 - ebeta0, wB1 = pB1 - ebeta1;
        for (int eo = 64; eo < nE; eo += 2) {
            const int e = eo + half;
            const float wa = __shfl(wA1, (e - 64) & 63);
            const float wb = __shfl(wB1, (e - 64) & 63);
            const int   ce = __shfl(c1, (e - 64) & 63);
            const bool ok = e < nE;
            const size_t vb0 = ((size_t)b * CC + ce) * EE + h0 * DD + d;
            const float vA = Vb[vb0];
            const float vB = Vb[vb0 + DD];
            accA = fmaf(ok ? wa : 0.f, vA, accA);
            accB = fmaf(ok ? wb : 0.f, vB, accB);
        }
    }
    accA += __shfl_xor(accA, 32);
    accB += __shfl_xor(accB, 32);

    // ---- epilogue: background via Vsum, write packed hi/lo bf16 ----
    if (lane < 32) {
        const float bgZ = (float)(CC - nE);
        const float invA = 1.f / (ZA + bgZ * ebeta0);
        const float invB = 1.f / (ZB + bgZ * ebeta1);
        const float vsA = Vsum[(b * HH + h0) * DD + d];
        const float vsB = Vsum[(b * HH + h0 + 1) * DD + d];
        const float oA = (accA + ebeta0 * vsA) * invA;
        const float oB = (accB + ebeta1 * vsB) * invB;
        const int rm = rowIdx;
        const int base_in = (d >> 3) * 128 + (rm & 15) * 8 + (d & 7);
        ushort oh, ol;
        split1(oA, oh, ol);
        int dst = ((rm >> 4) * 16 + h0) * 512 + base_in;
        Hbh[dst] = oh; Hbl[dst] = ol;
        split1(oB, oh, ol);
        dst = ((rm >> 4) * 16 + h0 + 1) * 512 + base_in;
        Hbh[dst] = oh; Hbl[dst] = ol;
    }
}

// ---------------------------------------------------------------------------
extern "C" void kernel_launch(void* const* d_in, const int* in_sizes, int n_in,
                              void* d_out, int out_size, void* d_ws, size_t ws_size,
                              hipStream_t stream)
{
    const float* rowe = (const float*)d_in[0];
    const float* cole = (const float*)d_in[1];
    const float* cost = (const float*)d_in[2];
    const float* Wq   = (const float*)d_in[3];
    const float* bq   = (const float*)d_in[4];
    const float* Wk   = (const float*)d_in[5];
    const float* bk   = (const float*)d_in[6];
    const float* Wv   = (const float*)d_in[7];
    const float* bv   = (const float*)d_in[8];
    const float* Wo   = (const float*)d_in[9];
    const float* bo   = (const float*)d_in[10];
    const float* W1   = (const float*)d_in[11];
    const float* b1   = (const float*)d_in[12];
    const float* W2   = (const float*)d_in[13];
    const float* b2   = (const float*)d_in[14];
    const float* beta = (const float*)d_in[15];
    float* out = (float*)d_out;

    // ---- workspace carve ----
    char* cur = (char*)d_ws;
    float* Qb   = (float*)cur; cur += (size_t)MROWS * EE * 4;
    float* Kb   = (float*)cur; cur += (size_t)MROWS * EE * 4;
    float* Vb   = (float*)cur; cur += (size_t)MROWS * EE * 4;
    float* Vsum = (float*)cur; cur += (size_t)BB * HH * DD * 4;
    ushort* reh = (ushort*)cur; cur += (size_t)MROWS * EE * 2;
    ushort* rel = (ushort*)cur; cur += (size_t)MROWS * EE * 2;
    ushort* ceh = (ushort*)cur; cur += (size_t)MROWS * EE * 2;
    ushort* cel = (ushort*)cur; cur += (size_t)MROWS * EE * 2;
    ushort* wqh = (ushort*)cur; cur += (size_t)EE * EE * 2;
    ushort* wql = (ushort*)cur; cur += (size_t)EE * EE * 2;
    ushort* wkh = (ushort*)cur; cur += (size_t)EE * EE * 2;
    ushort* wkl = (ushort*)cur; cur += (size_t)EE * EE * 2;
    ushort* wvh = (ushort*)cur; cur += (size_t)EE * EE * 2;
    ushort* wvl = (ushort*)cur; cur += (size_t)EE * EE * 2;
    ushort* woh = (ushort*)cur; cur += (size_t)EE * EE * 2;
    ushort* wol = (ushort*)cur; cur += (size_t)EE * EE * 2;
    ushort* hbh = (ushort*)cur; cur += (size_t)MROWS * EE * 2;
    ushort* hbl = (ushort*)cur; cur += (size_t)MROWS * EE * 2;
    int*    ecb = (int*)cur;   cur += (size_t)MROWS * MAXE * 4;
    float* ecwb = (float*)cur; cur += (size_t)MROWS * MAXE * 4;
    int*    nEb = (int*)cur;   cur += (size_t)MROWS * 4;

    split_kernel<<<dim3(768, 6), 256, 0, stream>>>(
        rowe, cole, Wq, Wk, Wv, Wo,
        reh, rel, ceh, cel, wqh, wql, wkh, wkl, wvh, wvl, woh, wol);

    edges_kernel<<<dim3(RR, BB), 64, 0, stream>>>(cost, ecb, ecwb, nEb);

    dim3 g1(8, 24, 3);
    qkv_kernel<<<g1, 256, 0, stream>>>(reh, rel, ceh, cel,
                                       wqh, wql, wkh, wkl, wvh, wvl,
                                       bq, bk, bv, Qb, Kb, Vb);

    dim3 gv(16, 4);
    vsum_kernel<<<gv, 256, 0, stream>>>(Vb, Vsum);

    dim3 g2(8, RR, 2);   // x = (b,hh) -> XCD pin; y = row; z = quad; 2 pairs/blk
    attn_kernel<<<g2, 128, 0, stream>>>(Qb, Kb, Vb, ecb, ecwb, nEb,
                                        W1, b1, W2, b2, beta, Vsum, hbh, hbl);

    dim3 g3(8, 24, 1);
    oproj_kernel<<<g3, 256, 0, stream>>>(hbh, hbl, woh, wol, bo, out);
}

// Round 13
// 105.815 us; speedup vs baseline: 1.0257x; 1.0257x over previous
//
#include <hip/hip_runtime.h>

// Problem constants
#define BB 4
#define RR 384
#define CC 384
#define EE 512
#define HH 16
#define DD 32
#define MROWS 1536   // B*R = B*C
#define MAXE 128     // edge-list stride (nE ~ 38 +- 6; 128 = 15 sigma)

typedef __attribute__((ext_vector_type(8))) short bf16x8;   // 8 bf16 = 4 VGPRs
typedef __attribute__((ext_vector_type(4))) float f32x4;

// ---------------------------------------------------------------------------
// f32 -> (hi, lo) bf16 split, RNE both times. x ~= hi + lo with ~2^-16 rel err.
// ---------------------------------------------------------------------------
__device__ __forceinline__ void split1(float x, ushort& h, ushort& l)
{
    const unsigned u = __float_as_uint(x);
    const unsigned r = (u + 0x7fffu + ((u >> 16) & 1u)) >> 16;
    h = (ushort)r;
    const float hf = __uint_as_float(r << 16);
    const float lo = x - hf;
    const unsigned u2 = __float_as_uint(lo);
    l = (ushort)((u2 + 0x7fffu + ((u2 >> 16) & 1u)) >> 16);
}

// Packed fragment address for element (r, k) of a [rows][512] matrix:
// lane l of the wave covering (r-tile, k-tile) reads elems [l*8, l*8+8).
__device__ __forceinline__ int packed_addr(int r, int k)
{
    return ((r >> 4) * 16 + (k >> 5)) * 512 + ((k >> 3) & 3) * 128 + (r & 15) * 8 + (k & 7);
}

// ---------------------------------------------------------------------------
// Split kernel: 6 arrays -> hi/lo bf16 planes in PACKED fragment layout.
// ---------------------------------------------------------------------------
__global__ __launch_bounds__(256) void split_kernel(
    const float* __restrict__ rowe, const float* __restrict__ cole,
    const float* __restrict__ Wq, const float* __restrict__ Wk,
    const float* __restrict__ Wv, const float* __restrict__ Wo,
    ushort* __restrict__ reh, ushort* __restrict__ rel,
    ushort* __restrict__ ceh, ushort* __restrict__ cel,
    ushort* __restrict__ wqh, ushort* __restrict__ wql,
    ushort* __restrict__ wkh, ushort* __restrict__ wkl,
    ushort* __restrict__ wvh, ushort* __restrict__ wvl,
    ushort* __restrict__ woh, ushort* __restrict__ wol)
{
    const float* src; ushort* dh; ushort* dl; int n;
    switch (blockIdx.y) {
    case 0: src = rowe; dh = reh; dl = rel; n = MROWS * EE; break;
    case 1: src = cole; dh = ceh; dl = cel; n = MROWS * EE; break;
    case 2: src = Wq;   dh = wqh; dl = wql; n = EE * EE;    break;
    case 3: src = Wk;   dh = wkh; dl = wkl; n = EE * EE;    break;
    case 4: src = Wv;   dh = wvh; dl = wvl; n = EE * EE;    break;
    default: src = Wo;  dh = woh; dl = wol; n = EE * EE;    break;
    }
    const int i4 = blockIdx.x * 256 + threadIdx.x;
    if (i4 * 4 >= n) return;
    const float4 v = ((const float4*)src)[i4];
    ushort4 hs, ls;
    split1(v.x, hs.x, ls.x);
    split1(v.y, hs.y, ls.y);
    split1(v.z, hs.z, ls.z);
    split1(v.w, hs.w, ls.w);
    const int e0 = i4 * 4;
    const int dst = packed_addr(e0 >> 9, e0 & 511);   // (k&7) in {0,4}: aligned
    *(ushort4*)(dh + dst) = hs;
    *(ushort4*)(dl + dst) = ls;
}

// ---------------------------------------------------------------------------
// bf16x3 emulated-f32 GEMM on packed operands.
// ---------------------------------------------------------------------------
__device__ __forceinline__ void gemm_bf16x3_body(
    const ushort* __restrict__ Ahi, const ushort* __restrict__ Alo,
    const ushort* __restrict__ Whi, const ushort* __restrict__ Wlo,
    const float* __restrict__ bias, float* __restrict__ Y,
    int Mt, int Nt0)
{
    constexpr int N = 512;
    const int lane = threadIdx.x & 63;
    const int col = lane & 15, kgrp = lane >> 4;

    const ushort* pah = Ahi + (size_t)Mt * 8192 + lane * 8;
    const ushort* pal = Alo + (size_t)Mt * 8192 + lane * 8;
    const ushort* pbh = Whi + (size_t)Nt0 * 8192 + lane * 8;
    const ushort* pbl = Wlo + (size_t)Nt0 * 8192 + lane * 8;

    f32x4 acc0 = {}, acc1 = {}, acc2 = {}, acc3 = {};

    bf16x8 ah  = *(const bf16x8*)(pah);
    bf16x8 al  = *(const bf16x8*)(pal);
    bf16x8 bh0 = *(const bf16x8*)(pbh);
    bf16x8 bh1 = *(const bf16x8*)(pbh + 8192);
    bf16x8 bh2 = *(const bf16x8*)(pbh + 16384);
    bf16x8 bh3 = *(const bf16x8*)(pbh + 24576);
    bf16x8 bl0 = *(const bf16x8*)(pbl);
    bf16x8 bl1 = *(const bf16x8*)(pbl + 8192);
    bf16x8 bl2 = *(const bf16x8*)(pbl + 16384);
    bf16x8 bl3 = *(const bf16x8*)(pbl + 24576);

#pragma unroll 4
    for (int kt = 0; kt < 16; ++kt) {
        bf16x8 nah = ah, nal = al;
        bf16x8 nbh0 = bh0, nbh1 = bh1, nbh2 = bh2, nbh3 = bh3;
        bf16x8 nbl0 = bl0, nbl1 = bl1, nbl2 = bl2, nbl3 = bl3;
        if (kt < 15) {
            const int ko = (kt + 1) * 512;
            nah  = *(const bf16x8*)(pah + ko);
            nal  = *(const bf16x8*)(pal + ko);
            nbh0 = *(const bf16x8*)(pbh + ko);
            nbh1 = *(const bf16x8*)(pbh + ko + 8192);
            nbh2 = *(const bf16x8*)(pbh + ko + 16384);
            nbh3 = *(const bf16x8*)(pbh + ko + 24576);
            nbl0 = *(const bf16x8*)(pbl + ko);
            nbl1 = *(const bf16x8*)(pbl + ko + 8192);
            nbl2 = *(const bf16x8*)(pbl + ko + 16384);
            nbl3 = *(const bf16x8*)(pbl + ko + 24576);
        }
        acc0 = __builtin_amdgcn_mfma_f32_16x16x32_bf16(ah, bh0, acc0, 0, 0, 0);
        acc0 = __builtin_amdgcn_mfma_f32_16x16x32_bf16(ah, bl0, acc0, 0, 0, 0);
        acc0 = __builtin_amdgcn_mfma_f32_16x16x32_bf16(al, bh0, acc0, 0, 0, 0);
        acc1 = __builtin_amdgcn_mfma_f32_16x16x32_bf16(ah, bh1, acc1, 0, 0, 0);
        acc1 = __builtin_amdgcn_mfma_f32_16x16x32_bf16(ah, bl1, acc1, 0, 0, 0);
        acc1 = __builtin_amdgcn_mfma_f32_16x16x32_bf16(al, bh1, acc1, 0, 0, 0);
        acc2 = __builtin_amdgcn_mfma_f32_16x16x32_bf16(ah, bh2, acc2, 0, 0, 0);
        acc2 = __builtin_amdgcn_mfma_f32_16x16x32_bf16(ah, bl2, acc2, 0, 0, 0);
        acc2 = __builtin_amdgcn_mfma_f32_16x16x32_bf16(al, bh2, acc2, 0, 0, 0);
        acc3 = __builtin_amdgcn_mfma_f32_16x16x32_bf16(ah, bh3, acc3, 0, 0, 0);
        acc3 = __builtin_amdgcn_mfma_f32_16x16x32_bf16(ah, bl3, acc3, 0, 0, 0);
        acc3 = __builtin_amdgcn_mfma_f32_16x16x32_bf16(al, bh3, acc3, 0, 0, 0);
        ah = nah; al = nal;
        bh0 = nbh0; bh1 = nbh1; bh2 = nbh2; bh3 = nbh3;
        bl0 = nbl0; bl1 = nbl1; bl2 = nbl2; bl3 = nbl3;
    }

    const f32x4 accs[4] = {acc0, acc1, acc2, acc3};
#pragma unroll
    for (int t = 0; t < 4; ++t) {
        const int n = (Nt0 + t) * 16 + col;
        const float bn = bias[n];
#pragma unroll
        for (int j = 0; j < 4; ++j) {
            const int m = Mt * 16 + kgrp * 4 + j;
            Y[m * N + n] = accs[t][j] + bn;
        }
    }
}

// XCD-grouping swizzle: l = a + 8b + 64c (a,b in [0,8), c in [0,3))
//  -> Bm = 3a + c (m-strip), Bx = b. Same-Bm blocks share l%8 -> same XCD.
__global__ __launch_bounds__(256) void qkv_kernel(
    const ushort* __restrict__ reh, const ushort* __restrict__ rel,
    const ushort* __restrict__ ceh, const ushort* __restrict__ cel,
    const ushort* __restrict__ wqh, const ushort* __restrict__ wql,
    const ushort* __restrict__ wkh, const ushort* __restrict__ wkl,
    const ushort* __restrict__ wvh, const ushort* __restrict__ wvl,
    const float* __restrict__ bq, const float* __restrict__ bk,
    const float* __restrict__ bv,
    float* __restrict__ Qo, float* __restrict__ Ko, float* __restrict__ Vo)
{
    const int l = blockIdx.x + (blockIdx.y << 3);
    const int Bm = (l & 7) * 3 + (l >> 6);
    const int Bx = (l >> 3) & 7;
    const int Mt = Bm * 4 + (threadIdx.x >> 6);
    const int Nt0 = Bx * 4;
    if (blockIdx.z == 0)      gemm_bf16x3_body(reh, rel, wqh, wql, bq, Qo, Mt, Nt0);
    else if (blockIdx.z == 1) gemm_bf16x3_body(ceh, cel, wkh, wkl, bk, Ko, Mt, Nt0);
    else                      gemm_bf16x3_body(ceh, cel, wvh, wvl, bv, Vo, Mt, Nt0);
}

__global__ __launch_bounds__(256) void oproj_kernel(
    const ushort* __restrict__ hbh, const ushort* __restrict__ hbl,
    const ushort* __restrict__ woh, const ushort* __restrict__ wol,
    const float* __restrict__ bo, float* __restrict__ out)
{
    const int l = blockIdx.x + (blockIdx.y << 3);
    const int Bm = (l & 7) * 3 + (l >> 6);
    const int Bx = (l >> 3) & 7;
    const int Mt = Bm * 4 + (threadIdx.x >> 6);
    const int Nt0 = Bx * 4;
    gemm_bf16x3_body(hbh, hbl, woh, wol, bo, out, Mt, Nt0);
}

// ---------------------------------------------------------------------------
// Vsum kernel: Vsum[b][h][d] = sum_c V[b][c][h*32+d]. Grid (16,4), 256 thr.
// ---------------------------------------------------------------------------
__global__ __launch_bounds__(256) void vsum_kernel(const float* __restrict__ Vb,
                                                   float* __restrict__ Vsum)
{
    __shared__ float part[8][32];
    const int h = blockIdx.x, b = blockIdx.y;
    const int d = threadIdx.x & 31, g = threadIdx.x >> 5;
    float acc = 0.f;
    for (int c = g; c < CC; c += 8)
        acc += Vb[(b * CC + c) * EE + h * DD + d];
    part[g][d] = acc;
    __syncthreads();
    if (g == 0) {
        float s = 0.f;
#pragma unroll
        for (int gg = 0; gg < 8; ++gg) s += part[gg][d];
        Vsum[(b * HH + h) * DD + d] = s;
    }
}

// ---------------------------------------------------------------------------
// Edge precompute: one wave per (b,r). Ballot-compacted edge lists to ws.
// ---------------------------------------------------------------------------
__global__ __launch_bounds__(64) void edges_kernel(
    const float* __restrict__ cost,
    int* __restrict__ ecb, float* __restrict__ ecwb, int* __restrict__ nEb)
{
    const int r = blockIdx.x, b = blockIdx.y;
    const int rowIdx = b * RR + r;
    const int lane = threadIdx.x;
    const float* crow = cost + (size_t)rowIdx * CC;
    const unsigned long long prefix = (1ull << lane) - 1ull;
    int nE = 0;
#pragma unroll
    for (int j = 0; j < 6; ++j) {
        const float cw = crow[lane + 64 * j];
        const unsigned long long mk = __ballot(cw > 0.f);
        if (cw > 0.f) {
            const int slot = nE + __popcll(mk & prefix);
            if (slot < MAXE) {
                ecb [rowIdx * MAXE + slot] = lane + 64 * j;
                ecwb[rowIdx * MAXE + slot] = cw;
            }
        }
        nE += __popcll(mk);
    }
    if (lane == 0) nEb[rowIdx] = (nE < MAXE) ? nE : MAXE;
}

// ---------------------------------------------------------------------------
// Edge scorer: dot(q,k) -> per-head 2x16x1 MLP -> p = exp(tanh*10 - 10).
// All q / MLP params come from wave-uniform addresses -> SGPRs.
// ---------------------------------------------------------------------------
__device__ __forceinline__ float score_edge(
    int c, float cw, int b, int h,
    const float* __restrict__ qrow, const float* __restrict__ Kb,
    const float* __restrict__ w10p, const float* __restrict__ w11p,
    const float* __restrict__ b1p, const float* __restrict__ w2p, float b2h)
{
    const float* kp = Kb + ((size_t)b * CC + c) * EE + h * DD;
    float d0 = 0.f, d1 = 0.f, d2 = 0.f, d3 = 0.f;
#pragma unroll
    for (int dq = 0; dq < 8; ++dq) {
        const float4 kv = *(const float4*)(kp + dq * 4);
        d0 = fmaf(qrow[dq * 4 + 0], kv.x, d0);
        d1 = fmaf(qrow[dq * 4 + 1], kv.y, d1);
        d2 = fmaf(qrow[dq * 4 + 2], kv.z, d2);
        d3 = fmaf(qrow[dq * 4 + 3], kv.w, d3);
    }
    const float dot = ((d0 + d1) + (d2 + d3)) * 0.17677669529663687f;
    float l0 = b2h, l1 = 0.f;
#pragma unroll
    for (int mm = 0; mm < 16; mm += 2) {
        const float h0 = fmaf(dot, w10p[mm],     fmaf(cw, w11p[mm],     b1p[mm]));
        const float h1 = fmaf(dot, w10p[mm + 1], fmaf(cw, w11p[mm + 1], b1p[mm + 1]));
        l0 = fmaf(fmaxf(h0, 0.f), w2p[mm],     l0);
        l1 = fmaf(fmaxf(h1, 0.f), w2p[mm + 1], l1);
    }
    // s = tanh(l)*10; p = exp(s-10) = exp(-20/(e^{2l}+1)); bounded (no ovf).
    const float ex = __expf(2.f * (l0 + l1));
    return __expf(-20.f / (ex + 1.f));
}

// ---------------------------------------------------------------------------
// Semi-sparse attention: TWO WAVES per block (128 thr); each wave = one
// (b, r, head-PAIR) -- R9's proven per-wave code. NO min-waves bound: R12's
// __launch_bounds__(128,8) forced VGPR to 32 and spilled ~11 MB to scratch
// (WRITE_SIZE 14 MB, the regression mechanism). Natural allocation ~40-48
// VGPR < 64-cliff keeps 8 waves/SIMD reachable with zero spills.
// Waves share NOTHING (no LDS, no __syncthreads; shfl is intra-wave).
// Fixed-max-10 softmax (scores tanh*10 in (-10,10), beta<=10):
//   out = (sum_E (p_e - e^{b-10}) V_e + e^{b-10} Vsum) / (sum p + (C-nE) e^{b-10})
// Grid (8, RR, 2): blockIdx.x = (b,hh) -> XCD pin (R6: FETCH -55%).
// ---------------------------------------------------------------------------
__global__ __launch_bounds__(128) void attn_kernel(
    const float* __restrict__ Qb, const float* __restrict__ Kb,
    const float* __restrict__ Vb,
    const int* __restrict__ ecb, const float* __restrict__ ecwb,
    const int* __restrict__ nEb,
    const float* __restrict__ W1, const float* __restrict__ b1,
    const float* __restrict__ W2, const float* __restrict__ b2,
    const float* __restrict__ beta,
    const float* __restrict__ Vsum,
    ushort* __restrict__ Hbh, ushort* __restrict__ Hbl)
{
    const int combo = blockIdx.x;            // 0..7 -> XCD
    const int b = combo >> 1, hh = combo & 1;
    const int r = blockIdx.y;
    const int wave = threadIdx.x >> 6;       // 0..1 -> head-pair in quad
    const int h0 = hh * 8 + blockIdx.z * 4 + wave * 2;  // heads h0, h0+1
    const int lane = threadIdx.x & 63;
    const int rowIdx = b * RR + r;

    const int nE = nEb[rowIdx];              // wave-uniform
    const float b2h0 = b2[h0], b2h1 = b2[h0 + 1];
    const float ebeta0 = __expf(beta[h0] - 10.f);
    const float ebeta1 = __expf(beta[h0 + 1] - 10.f);

    const float* qrow0 = Qb + (size_t)rowIdx * EE + h0 * DD;   // uniform -> SGPR
    const float* qrow1 = qrow0 + DD;
    const float* w10p0 = W1 + h0 * 32;       const float* w10p1 = w10p0 + 32;
    const float* w11p0 = W1 + h0 * 32 + 16;  const float* w11p1 = w11p0 + 32;
    const float* b1p0  = b1 + h0 * 16;       const float* b1p1  = b1p0 + 16;
    const float* w2p0  = W2 + h0 * 16;       const float* w2p1  = w2p0 + 16;

    // ---- scoring: lane e = edge e, both heads (independent chains) ----
    int c0 = 0, c1 = 0;
    float pA0 = 0.f, pB0 = 0.f, pA1 = 0.f, pB1 = 0.f;
    if (lane < nE) {
        c0 = ecb[rowIdx * MAXE + lane];
        const float cw = ecwb[rowIdx * MAXE + lane];
        pA0 = score_edge(c0, cw, b, h0,     qrow0, Kb, w10p0, w11p0, b1p0, w2p0, b2h0);
        pB0 = score_edge(c0, cw, b, h0 + 1, qrow1, Kb, w10p1, w11p1, b1p1, w2p1, b2h1);
    }
    if (nE > 64) {                           // wave-uniform rare branch
        const int e1 = lane + 64;
        if (e1 < nE) {
            c1 = ecb[rowIdx * MAXE + e1];
            const float cw = ecwb[rowIdx * MAXE + e1];
            pA1 = score_edge(c1, cw, b, h0,     qrow0, Kb, w10p0, w11p0, b1p0, w2p0, b2h0);
            pB1 = score_edge(c1, cw, b, h0 + 1, qrow1, Kb, w10p1, w11p1, b1p1, w2p1, b2h1);
        }
    }

    // ---- Z: full-wave reduce, both heads ----
    float ZA = pA0 + pA1, ZB = pB0 + pB1;
#pragma unroll
    for (int off = 1; off < 64; off <<= 1) {
        ZA += __shfl_xor(ZA, off);
        ZB += __shfl_xor(ZB, off);
    }

    // ---- PV: 2 edges/iter, 2 heads -> 2 loads + 2 FMA chains in flight ----
    const int half = lane >> 5, d = lane & 31;
    const float wA0 = pA0 - ebeta0, wB0 = pB0 - ebeta1;
    float accA = 0.f, accB = 0.f;
    const int lim0 = (nE < 64) ? nE : 64;
    for (int eo = 0; eo < lim0; eo += 2) {
        const int e = eo + half;
        const float wa = __shfl(wA0, e & 63);
        const float wb = __shfl(wB0, e & 63);
        const int   ce = __shfl(c0, e & 63);   // c0=0 on invalid lanes: safe
        const bool ok = e < lim0;
        const size_t vb0 = ((size_t)b * CC + ce) * EE + h0 * DD + d;
        const float vA = Vb[vb0];
        const float vB = Vb[vb0 + DD];
        accA = fmaf(ok ? wa : 0.f, vA, accA);
        accB = fmaf(ok ? wb : 0.f, vB, accB);
    }
    if (nE > 64) {
        const float wA1 = pA1 - ebeta0, wB1 = pB1 - ebeta1;
        for (int eo = 64; eo < nE; eo += 2) {
            const int e = eo + half;
            const float wa = __shfl(wA1, (e - 64) & 63);
            const float wb = __shfl(wB1, (e - 64) & 63);
            const int   ce = __shfl(c1, (e - 64) & 63);
            const bool ok = e < nE;
            const size_t vb0 = ((size_t)b * CC + ce) * EE + h0 * DD + d;
            const float vA = Vb[vb0];
            const float vB = Vb[vb0 + DD];
            accA = fmaf(ok ? wa : 0.f, vA, accA);
            accB = fmaf(ok ? wb : 0.f, vB, accB);
        }
    }
    accA += __shfl_xor(accA, 32);
    accB += __shfl_xor(accB, 32);

    // ---- epilogue: background via Vsum, write packed hi/lo bf16 ----
    if (lane < 32) {
        const float bgZ = (float)(CC - nE);
        const float invA = 1.f / (ZA + bgZ * ebeta0);
        const float invB = 1.f / (ZB + bgZ * ebeta1);
        const float vsA = Vsum[(b * HH + h0) * DD + d];
        const float vsB = Vsum[(b * HH + h0 + 1) * DD + d];
        const float oA = (accA + ebeta0 * vsA) * invA;
        const float oB = (accB + ebeta1 * vsB) * invB;
        const int rm = rowIdx;
        const int base_in = (d >> 3) * 128 + (rm & 15) * 8 + (d & 7);
        ushort oh, ol;
        split1(oA, oh, ol);
        int dst = ((rm >> 4) * 16 + h0) * 512 + base_in;
        Hbh[dst] = oh; Hbl[dst] = ol;
        split1(oB, oh, ol);
        dst = ((rm >> 4) * 16 + h0 + 1) * 512 + base_in;
        Hbh[dst] = oh; Hbl[dst] = ol;
    }
}

// ---------------------------------------------------------------------------
extern "C" void kernel_launch(void* const* d_in, const int* in_sizes, int n_in,
                              void* d_out, int out_size, void* d_ws, size_t ws_size,
                              hipStream_t stream)
{
    const float* rowe = (const float*)d_in[0];
    const float* cole = (const float*)d_in[1];
    const float* cost = (const float*)d_in[2];
    const float* Wq   = (const float*)d_in[3];
    const float* bq   = (const float*)d_in[4];
    const float* Wk   = (const float*)d_in[5];
    const float* bk   = (const float*)d_in[6];
    const float* Wv   = (const float*)d_in[7];
    const float* bv   = (const float*)d_in[8];
    const float* Wo   = (const float*)d_in[9];
    const float* bo   = (const float*)d_in[10];
    const float* W1   = (const float*)d_in[11];
    const float* b1   = (const float*)d_in[12];
    const float* W2   = (const float*)d_in[13];
    const float* b2   = (const float*)d_in[14];
    const float* beta = (const float*)d_in[15];
    float* out = (float*)d_out;

    // ---- workspace carve ----
    char* cur = (char*)d_ws;
    float* Qb   = (float*)cur; cur += (size_t)MROWS * EE * 4;
    float* Kb   = (float*)cur; cur += (size_t)MROWS * EE * 4;
    float* Vb   = (float*)cur; cur += (size_t)MROWS * EE * 4;
    float* Vsum = (float*)cur; cur += (size_t)BB * HH * DD * 4;
    ushort* reh = (ushort*)cur; cur += (size_t)MROWS * EE * 2;
    ushort* rel = (ushort*)cur; cur += (size_t)MROWS * EE * 2;
    ushort* ceh = (ushort*)cur; cur += (size_t)MROWS * EE * 2;
    ushort* cel = (ushort*)cur; cur += (size_t)MROWS * EE * 2;
    ushort* wqh = (ushort*)cur; cur += (size_t)EE * EE * 2;
    ushort* wql = (ushort*)cur; cur += (size_t)EE * EE * 2;
    ushort* wkh = (ushort*)cur; cur += (size_t)EE * EE * 2;
    ushort* wkl = (ushort*)cur; cur += (size_t)EE * EE * 2;
    ushort* wvh = (ushort*)cur; cur += (size_t)EE * EE * 2;
    ushort* wvl = (ushort*)cur; cur += (size_t)EE * EE * 2;
    ushort* woh = (ushort*)cur; cur += (size_t)EE * EE * 2;
    ushort* wol = (ushort*)cur; cur += (size_t)EE * EE * 2;
    ushort* hbh = (ushort*)cur; cur += (size_t)MROWS * EE * 2;
    ushort* hbl = (ushort*)cur; cur += (size_t)MROWS * EE * 2;
    int*    ecb = (int*)cur;   cur += (size_t)MROWS * MAXE * 4;
    float* ecwb = (float*)cur; cur += (size_t)MROWS * MAXE * 4;
    int*    nEb = (int*)cur;   cur += (size_t)MROWS * 4;

    split_kernel<<<dim3(768, 6), 256, 0, stream>>>(
        rowe, cole, Wq, Wk, Wv, Wo,
        reh, rel, ceh, cel, wqh, wql, wkh, wkl, wvh, wvl, woh, wol);

    edges_kernel<<<dim3(RR, BB), 64, 0, stream>>>(cost, ecb, ecwb, nEb);

    dim3 g1(8, 24, 3);
    qkv_kernel<<<g1, 256, 0, stream>>>(reh, rel, ceh, cel,
                                       wqh, wql, wkh, wkl, wvh, wvl,
                                       bq, bk, bv, Qb, Kb, Vb);

    dim3 gv(16, 4);
    vsum_kernel<<<gv, 256, 0, stream>>>(Vb, Vsum);

    dim3 g2(8, RR, 2);   // x = (b,hh) -> XCD pin; y = row; z = quad; 2 pairs/blk
    attn_kernel<<<g2, 128, 0, stream>>>(Qb, Kb, Vb, ecb, ecwb, nEb,
                                        W1, b1, W2, b2, beta, Vsum, hbh, hbl);

    dim3 g3(8, 24, 1);
    oproj_kernel<<<g3, 256, 0, stream>>>(hbh, hbl, woh, wol, bo, out);
}

// Round 14
// 88.427 us; speedup vs baseline: 1.2275x; 1.1966x over previous
//
#include <hip/hip_runtime.h>

// Problem constants
#define BB 4
#define RR 384
#define CC 384
#define EE 512
#define HH 16
#define DD 32
#define MROWS 1536   // B*R = B*C
#define MAXE 128     // edge-list stride (nE ~ 38 +- 6; 128 = 15 sigma)

typedef __attribute__((ext_vector_type(8))) short bf16x8;   // 8 bf16 = 4 VGPRs
typedef __attribute__((ext_vector_type(4))) float f32x4;

// ---------------------------------------------------------------------------
// f32 -> (hi, lo) bf16 split, RNE both times. x ~= hi + lo with ~2^-16 rel err.
// ---------------------------------------------------------------------------
__device__ __forceinline__ void split1(float x, ushort& h, ushort& l)
{
    const unsigned u = __float_as_uint(x);
    const unsigned r = (u + 0x7fffu + ((u >> 16) & 1u)) >> 16;
    h = (ushort)r;
    const float hf = __uint_as_float(r << 16);
    const float lo = x - hf;
    const unsigned u2 = __float_as_uint(lo);
    l = (ushort)((u2 + 0x7fffu + ((u2 >> 16) & 1u)) >> 16);
}

// Packed fragment address for element (r, k) of a [rows][512] matrix:
// lane l of the wave covering (r-tile, k-tile) reads elems [l*8, l*8+8).
__device__ __forceinline__ int packed_addr(int r, int k)
{
    return ((r >> 4) * 16 + (k >> 5)) * 512 + ((k >> 3) & 3) * 128 + (r & 15) * 8 + (k & 7);
}

// ---------------------------------------------------------------------------
// Split kernel: 6 arrays -> hi/lo bf16 planes in PACKED fragment layout.
// ---------------------------------------------------------------------------
__global__ __launch_bounds__(256) void split_kernel(
    const float* __restrict__ rowe, const float* __restrict__ cole,
    const float* __restrict__ Wq, const float* __restrict__ Wk,
    const float* __restrict__ Wv, const float* __restrict__ Wo,
    ushort* __restrict__ reh, ushort* __restrict__ rel,
    ushort* __restrict__ ceh, ushort* __restrict__ cel,
    ushort* __restrict__ wqh, ushort* __restrict__ wql,
    ushort* __restrict__ wkh, ushort* __restrict__ wkl,
    ushort* __restrict__ wvh, ushort* __restrict__ wvl,
    ushort* __restrict__ woh, ushort* __restrict__ wol)
{
    const float* src; ushort* dh; ushort* dl; int n;
    switch (blockIdx.y) {
    case 0: src = rowe; dh = reh; dl = rel; n = MROWS * EE; break;
    case 1: src = cole; dh = ceh; dl = cel; n = MROWS * EE; break;
    case 2: src = Wq;   dh = wqh; dl = wql; n = EE * EE;    break;
    case 3: src = Wk;   dh = wkh; dl = wkl; n = EE * EE;    break;
    case 4: src = Wv;   dh = wvh; dl = wvl; n = EE * EE;    break;
    default: src = Wo;  dh = woh; dl = wol; n = EE * EE;    break;
    }
    const int i4 = blockIdx.x * 256 + threadIdx.x;
    if (i4 * 4 >= n) return;
    const float4 v = ((const float4*)src)[i4];
    ushort4 hs, ls;
    split1(v.x, hs.x, ls.x);
    split1(v.y, hs.y, ls.y);
    split1(v.z, hs.z, ls.z);
    split1(v.w, hs.w, ls.w);
    const int e0 = i4 * 4;
    const int dst = packed_addr(e0 >> 9, e0 & 511);   // (k&7) in {0,4}: aligned
    *(ushort4*)(dh + dst) = hs;
    *(ushort4*)(dl + dst) = ls;
}

// ---------------------------------------------------------------------------
// bf16x3 emulated-f32 GEMM on packed operands. 4 n-tiles per wave (16x64).
// Used by oproj (unchanged, proven).
// ---------------------------------------------------------------------------
__device__ __forceinline__ void gemm_bf16x3_body(
    const ushort* __restrict__ Ahi, const ushort* __restrict__ Alo,
    const ushort* __restrict__ Whi, const ushort* __restrict__ Wlo,
    const float* __restrict__ bias, float* __restrict__ Y,
    int Mt, int Nt0)
{
    constexpr int N = 512;
    const int lane = threadIdx.x & 63;
    const int col = lane & 15, kgrp = lane >> 4;

    const ushort* pah = Ahi + (size_t)Mt * 8192 + lane * 8;
    const ushort* pal = Alo + (size_t)Mt * 8192 + lane * 8;
    const ushort* pbh = Whi + (size_t)Nt0 * 8192 + lane * 8;
    const ushort* pbl = Wlo + (size_t)Nt0 * 8192 + lane * 8;

    f32x4 acc0 = {}, acc1 = {}, acc2 = {}, acc3 = {};

    bf16x8 ah  = *(const bf16x8*)(pah);
    bf16x8 al  = *(const bf16x8*)(pal);
    bf16x8 bh0 = *(const bf16x8*)(pbh);
    bf16x8 bh1 = *(const bf16x8*)(pbh + 8192);
    bf16x8 bh2 = *(const bf16x8*)(pbh + 16384);
    bf16x8 bh3 = *(const bf16x8*)(pbh + 24576);
    bf16x8 bl0 = *(const bf16x8*)(pbl);
    bf16x8 bl1 = *(const bf16x8*)(pbl + 8192);
    bf16x8 bl2 = *(const bf16x8*)(pbl + 16384);
    bf16x8 bl3 = *(const bf16x8*)(pbl + 24576);

#pragma unroll 4
    for (int kt = 0; kt < 16; ++kt) {
        bf16x8 nah = ah, nal = al;
        bf16x8 nbh0 = bh0, nbh1 = bh1, nbh2 = bh2, nbh3 = bh3;
        bf16x8 nbl0 = bl0, nbl1 = bl1, nbl2 = bl2, nbl3 = bl3;
        if (kt < 15) {
            const int ko = (kt + 1) * 512;
            nah  = *(const bf16x8*)(pah + ko);
            nal  = *(const bf16x8*)(pal + ko);
            nbh0 = *(const bf16x8*)(pbh + ko);
            nbh1 = *(const bf16x8*)(pbh + ko + 8192);
            nbh2 = *(const bf16x8*)(pbh + ko + 16384);
            nbh3 = *(const bf16x8*)(pbh + ko + 24576);
            nbl0 = *(const bf16x8*)(pbl + ko);
            nbl1 = *(const bf16x8*)(pbl + ko + 8192);
            nbl2 = *(const bf16x8*)(pbl + ko + 16384);
            nbl3 = *(const bf16x8*)(pbl + ko + 24576);
        }
        acc0 = __builtin_amdgcn_mfma_f32_16x16x32_bf16(ah, bh0, acc0, 0, 0, 0);
        acc0 = __builtin_amdgcn_mfma_f32_16x16x32_bf16(ah, bl0, acc0, 0, 0, 0);
        acc0 = __builtin_amdgcn_mfma_f32_16x16x32_bf16(al, bh0, acc0, 0, 0, 0);
        acc1 = __builtin_amdgcn_mfma_f32_16x16x32_bf16(ah, bh1, acc1, 0, 0, 0);
        acc1 = __builtin_amdgcn_mfma_f32_16x16x32_bf16(ah, bl1, acc1, 0, 0, 0);
        acc1 = __builtin_amdgcn_mfma_f32_16x16x32_bf16(al, bh1, acc1, 0, 0, 0);
        acc2 = __builtin_amdgcn_mfma_f32_16x16x32_bf16(ah, bh2, acc2, 0, 0, 0);
        acc2 = __builtin_amdgcn_mfma_f32_16x16x32_bf16(ah, bl2, acc2, 0, 0, 0);
        acc2 = __builtin_amdgcn_mfma_f32_16x16x32_bf16(al, bh2, acc2, 0, 0, 0);
        acc3 = __builtin_amdgcn_mfma_f32_16x16x32_bf16(ah, bh3, acc3, 0, 0, 0);
        acc3 = __builtin_amdgcn_mfma_f32_16x16x32_bf16(ah, bl3, acc3, 0, 0, 0);
        acc3 = __builtin_amdgcn_mfma_f32_16x16x32_bf16(al, bh3, acc3, 0, 0, 0);
        ah = nah; al = nal;
        bh0 = nbh0; bh1 = nbh1; bh2 = nbh2; bh3 = nbh3;
        bl0 = nbl0; bl1 = nbl1; bl2 = nbl2; bl3 = nbl3;
    }

    const f32x4 accs[4] = {acc0, acc1, acc2, acc3};
#pragma unroll
    for (int t = 0; t < 4; ++t) {
        const int n = (Nt0 + t) * 16 + col;
        const float bn = bias[n];
#pragma unroll
        for (int j = 0; j < 4; ++j) {
            const int m = Mt * 16 + kgrp * 4 + j;
            Y[m * N + n] = accs[t][j] + bn;
        }
    }
}

// ---------------------------------------------------------------------------
// Fine-grained GEMM body: 2 n-tiles per wave (16x32) -> 2x the wave count
// (4608 waves, 18/CU) for the latency-bound qkv (was 9 waves/CU, MfmaUtil
// 4.4%). 6 loads + 6 MFMA per K-step; ~30-40 VGPR (under the 64 cliff).
// ---------------------------------------------------------------------------
__device__ __forceinline__ void gemm_bf16x3_body2(
    const ushort* __restrict__ Ahi, const ushort* __restrict__ Alo,
    const ushort* __restrict__ Whi, const ushort* __restrict__ Wlo,
    const float* __restrict__ bias, float* __restrict__ Y,
    int Mt, int Nt0)
{
    constexpr int N = 512;
    const int lane = threadIdx.x & 63;
    const int col = lane & 15, kgrp = lane >> 4;

    const ushort* pah = Ahi + (size_t)Mt * 8192 + lane * 8;
    const ushort* pal = Alo + (size_t)Mt * 8192 + lane * 8;
    const ushort* pbh = Whi + (size_t)Nt0 * 8192 + lane * 8;
    const ushort* pbl = Wlo + (size_t)Nt0 * 8192 + lane * 8;

    f32x4 acc0 = {}, acc1 = {};

#pragma unroll 4
    for (int kt = 0; kt < 16; ++kt) {
        const int ko = kt * 512;
        const bf16x8 ah  = *(const bf16x8*)(pah + ko);
        const bf16x8 al  = *(const bf16x8*)(pal + ko);
        const bf16x8 bh0 = *(const bf16x8*)(pbh + ko);
        const bf16x8 bh1 = *(const bf16x8*)(pbh + ko + 8192);
        const bf16x8 bl0 = *(const bf16x8*)(pbl + ko);
        const bf16x8 bl1 = *(const bf16x8*)(pbl + ko + 8192);
        acc0 = __builtin_amdgcn_mfma_f32_16x16x32_bf16(ah, bh0, acc0, 0, 0, 0);
        acc0 = __builtin_amdgcn_mfma_f32_16x16x32_bf16(ah, bl0, acc0, 0, 0, 0);
        acc0 = __builtin_amdgcn_mfma_f32_16x16x32_bf16(al, bh0, acc0, 0, 0, 0);
        acc1 = __builtin_amdgcn_mfma_f32_16x16x32_bf16(ah, bh1, acc1, 0, 0, 0);
        acc1 = __builtin_amdgcn_mfma_f32_16x16x32_bf16(ah, bl1, acc1, 0, 0, 0);
        acc1 = __builtin_amdgcn_mfma_f32_16x16x32_bf16(al, bh1, acc1, 0, 0, 0);
    }

    const f32x4 accs[2] = {acc0, acc1};
#pragma unroll
    for (int t = 0; t < 2; ++t) {
        const int n = (Nt0 + t) * 16 + col;
        const float bn = bias[n];
#pragma unroll
        for (int j = 0; j < 4; ++j) {
            const int m = Mt * 16 + kgrp * 4 + j;
            Y[m * N + n] = accs[t][j] + bn;
        }
    }
}

// qkv: grid (16, 24, 3), 256 thr (4 waves over m). l = x + 16y in [0,384);
// XCD = l&7 (16y, 384z are 0 mod 8). Bm = (l&7)*3 + (l>>3)>>4 in [0,24),
// Bx = (l>>3)&15 in [0,16): each XCD owns 3 A-strips x all W panels
// (~1.4 MB < 4 MB L2). Wave tile 16m x 32n.
__global__ __launch_bounds__(256) void qkv_kernel(
    const ushort* __restrict__ reh, const ushort* __restrict__ rel,
    const ushort* __restrict__ ceh, const ushort* __restrict__ cel,
    const ushort* __restrict__ wqh, const ushort* __restrict__ wql,
    const ushort* __restrict__ wkh, const ushort* __restrict__ wkl,
    const ushort* __restrict__ wvh, const ushort* __restrict__ wvl,
    const float* __restrict__ bq, const float* __restrict__ bk,
    const float* __restrict__ bv,
    float* __restrict__ Qo, float* __restrict__ Ko, float* __restrict__ Vo)
{
    const int l = blockIdx.x + (blockIdx.y << 4);
    const int a = l & 7;
    const int t = l >> 3;
    const int Bm = a * 3 + (t >> 4);
    const int Bx = t & 15;
    const int Mt = Bm * 4 + (threadIdx.x >> 6);
    const int Nt0 = Bx * 2;
    if (blockIdx.z == 0)      gemm_bf16x3_body2(reh, rel, wqh, wql, bq, Qo, Mt, Nt0);
    else if (blockIdx.z == 1) gemm_bf16x3_body2(ceh, cel, wkh, wkl, bk, Ko, Mt, Nt0);
    else                      gemm_bf16x3_body2(ceh, cel, wvh, wvl, bv, Vo, Mt, Nt0);
}

__global__ __launch_bounds__(256) void oproj_kernel(
    const ushort* __restrict__ hbh, const ushort* __restrict__ hbl,
    const ushort* __restrict__ woh, const ushort* __restrict__ wol,
    const float* __restrict__ bo, float* __restrict__ out)
{
    const int l = blockIdx.x + (blockIdx.y << 3);
    const int Bm = (l & 7) * 3 + (l >> 6);
    const int Bx = (l >> 3) & 7;
    const int Mt = Bm * 4 + (threadIdx.x >> 6);
    const int Nt0 = Bx * 4;
    gemm_bf16x3_body(hbh, hbl, woh, wol, bo, out, Mt, Nt0);
}

// ---------------------------------------------------------------------------
// Vsum kernel: Vsum[b][h][d] = sum_c V[b][c][h*32+d]. Grid (16,4), 256 thr.
// ---------------------------------------------------------------------------
__global__ __launch_bounds__(256) void vsum_kernel(const float* __restrict__ Vb,
                                                   float* __restrict__ Vsum)
{
    __shared__ float part[8][32];
    const int h = blockIdx.x, b = blockIdx.y;
    const int d = threadIdx.x & 31, g = threadIdx.x >> 5;
    float acc = 0.f;
    for (int c = g; c < CC; c += 8)
        acc += Vb[(b * CC + c) * EE + h * DD + d];
    part[g][d] = acc;
    __syncthreads();
    if (g == 0) {
        float s = 0.f;
#pragma unroll
        for (int gg = 0; gg < 8; ++gg) s += part[gg][d];
        Vsum[(b * HH + h) * DD + d] = s;
    }
}

// ---------------------------------------------------------------------------
// Edge precompute: one wave per (b,r). Ballot-compacted edge lists to ws.
// ---------------------------------------------------------------------------
__global__ __launch_bounds__(64) void edges_kernel(
    const float* __restrict__ cost,
    int* __restrict__ ecb, float* __restrict__ ecwb, int* __restrict__ nEb)
{
    const int r = blockIdx.x, b = blockIdx.y;
    const int rowIdx = b * RR + r;
    const int lane = threadIdx.x;
    const float* crow = cost + (size_t)rowIdx * CC;
    const unsigned long long prefix = (1ull << lane) - 1ull;
    int nE = 0;
#pragma unroll
    for (int j = 0; j < 6; ++j) {
        const float cw = crow[lane + 64 * j];
        const unsigned long long mk = __ballot(cw > 0.f);
        if (cw > 0.f) {
            const int slot = nE + __popcll(mk & prefix);
            if (slot < MAXE) {
                ecb [rowIdx * MAXE + slot] = lane + 64 * j;
                ecwb[rowIdx * MAXE + slot] = cw;
            }
        }
        nE += __popcll(mk);
    }
    if (lane == 0) nEb[rowIdx] = (nE < MAXE) ? nE : MAXE;
}

// ---------------------------------------------------------------------------
// Edge scorer: dot(q,k) -> per-head 2x16x1 MLP -> p = exp(tanh*10 - 10).
// All q / MLP params come from wave-uniform addresses -> SGPRs.
// ---------------------------------------------------------------------------
__device__ __forceinline__ float score_edge(
    int c, float cw, int b, int h,
    const float* __restrict__ qrow, const float* __restrict__ Kb,
    const float* __restrict__ w10p, const float* __restrict__ w11p,
    const float* __restrict__ b1p, const float* __restrict__ w2p, float b2h)
{
    const float* kp = Kb + ((size_t)b * CC + c) * EE + h * DD;
    float d0 = 0.f, d1 = 0.f, d2 = 0.f, d3 = 0.f;
#pragma unroll
    for (int dq = 0; dq < 8; ++dq) {
        const float4 kv = *(const float4*)(kp + dq * 4);
        d0 = fmaf(qrow[dq * 4 + 0], kv.x, d0);
        d1 = fmaf(qrow[dq * 4 + 1], kv.y, d1);
        d2 = fmaf(qrow[dq * 4 + 2], kv.z, d2);
        d3 = fmaf(qrow[dq * 4 + 3], kv.w, d3);
    }
    const float dot = ((d0 + d1) + (d2 + d3)) * 0.17677669529663687f;
    float l0 = b2h, l1 = 0.f;
#pragma unroll
    for (int mm = 0; mm < 16; mm += 2) {
        const float h0 = fmaf(dot, w10p[mm],     fmaf(cw, w11p[mm],     b1p[mm]));
        const float h1 = fmaf(dot, w10p[mm + 1], fmaf(cw, w11p[mm + 1], b1p[mm + 1]));
        l0 = fmaf(fmaxf(h0, 0.f), w2p[mm],     l0);
        l1 = fmaf(fmaxf(h1, 0.f), w2p[mm + 1], l1);
    }
    // s = tanh(l)*10; p = exp(s-10) = exp(-20/(e^{2l}+1)); bounded (no ovf).
    const float ex = __expf(2.f * (l0 + l1));
    return __expf(-20.f / (ex + 1.f));
}

// ---------------------------------------------------------------------------
// Semi-sparse attention: R10-EXACT (champion, 88.1 us total, passed
// post-timing). ONE WAVE per (b, r, head-QUAD): 4 consecutive heads make
// each edge's K-gather a contiguous 512B read and amortize edge-list reads
// + Z-shuffles 4x. R11-R13 proved 128-thread variants all lose (~50 us vs
// ~32 us) regardless of VGPR/occupancy tuning.
// Fixed-max-10 softmax (scores tanh*10 in (-10,10), beta<=10):
//   out = (sum_E (p_e - e^{b-10}) V_e + e^{b-10} Vsum) / (sum p + (C-nE) e^{b-10})
// Grid (8, RR, 2): blockIdx.x = (b,hh) -> XCD pin (R6: FETCH -55%).
// ---------------------------------------------------------------------------
__global__ __launch_bounds__(64) void attn_kernel(
    const float* __restrict__ Qb, const float* __restrict__ Kb,
    const float* __restrict__ Vb,
    const int* __restrict__ ecb, const float* __restrict__ ecwb,
    const int* __restrict__ nEb,
    const float* __restrict__ W1, const float* __restrict__ b1,
    const float* __restrict__ W2, const float* __restrict__ b2,
    const float* __restrict__ beta,
    const float* __restrict__ Vsum,
    ushort* __restrict__ Hbh, ushort* __restrict__ Hbl)
{
    const int combo = blockIdx.x;            // 0..7 -> XCD
    const int b = combo >> 1, hh = combo & 1;
    const int r = blockIdx.y;
    const int h0 = hh * 8 + blockIdx.z * 4;  // this wave: heads h0..h0+3
    const int lane = threadIdx.x;
    const int rowIdx = b * RR + r;

    const int nE = nEb[rowIdx];              // wave-uniform
    const float b2A = b2[h0], b2B = b2[h0 + 1], b2C = b2[h0 + 2], b2D = b2[h0 + 3];
    const float ebA = __expf(beta[h0]     - 10.f);
    const float ebB = __expf(beta[h0 + 1] - 10.f);
    const float ebC = __expf(beta[h0 + 2] - 10.f);
    const float ebD = __expf(beta[h0 + 3] - 10.f);

    const float* qA = Qb + (size_t)rowIdx * EE + h0 * DD;    // uniform -> SGPR
    const float* qB = qA + DD;
    const float* qC = qA + 2 * DD;
    const float* qD = qA + 3 * DD;
    const float* w10A = W1 + h0 * 32;
    const float* w11A = w10A + 16;
    const float* b1A  = b1 + h0 * 16;
    const float* w2A  = W2 + h0 * 16;

    // ---- scoring: lane e = edge e, 4 heads (independent chains) ----
    int c0 = 0, c1 = 0;
    float pA0 = 0.f, pB0 = 0.f, pC0 = 0.f, pD0 = 0.f;
    float pA1 = 0.f, pB1 = 0.f, pC1 = 0.f, pD1 = 0.f;
    if (lane < nE) {
        c0 = ecb[rowIdx * MAXE + lane];
        const float cw = ecwb[rowIdx * MAXE + lane];
        pA0 = score_edge(c0, cw, b, h0,     qA, Kb, w10A,      w11A,      b1A,      w2A,      b2A);
        pB0 = score_edge(c0, cw, b, h0 + 1, qB, Kb, w10A + 32, w11A + 32, b1A + 16, w2A + 16, b2B);
        pC0 = score_edge(c0, cw, b, h0 + 2, qC, Kb, w10A + 64, w11A + 64, b1A + 32, w2A + 32, b2C);
        pD0 = score_edge(c0, cw, b, h0 + 3, qD, Kb, w10A + 96, w11A + 96, b1A + 48, w2A + 48, b2D);
    }
    if (nE > 64) {                           // wave-uniform rare branch
        const int e1 = lane + 64;
        if (e1 < nE) {
            c1 = ecb[rowIdx * MAXE + e1];
            const float cw = ecwb[rowIdx * MAXE + e1];
            pA1 = score_edge(c1, cw, b, h0,     qA, Kb, w10A,      w11A,      b1A,      w2A,      b2A);
            pB1 = score_edge(c1, cw, b, h0 + 1, qB, Kb, w10A + 32, w11A + 32, b1A + 16, w2A + 16, b2B);
            pC1 = score_edge(c1, cw, b, h0 + 2, qC, Kb, w10A + 64, w11A + 64, b1A + 32, w2A + 32, b2C);
            pD1 = score_edge(c1, cw, b, h0 + 3, qD, Kb, w10A + 96, w11A + 96, b1A + 48, w2A + 48, b2D);
        }
    }

    // ---- Z: full-wave reduce, 4 heads ----
    float ZA = pA0 + pA1, ZB = pB0 + pB1, ZC = pC0 + pC1, ZD = pD0 + pD1;
#pragma unroll
    for (int off = 1; off < 64; off <<= 1) {
        ZA += __shfl_xor(ZA, off);
        ZB += __shfl_xor(ZB, off);
        ZC += __shfl_xor(ZC, off);
        ZD += __shfl_xor(ZD, off);
    }

    // ---- PV: 2 edges/iter, 4 heads -> 4 loads + 4 FMA chains in flight ----
    const int half = lane >> 5, d = lane & 31;
    const float wA0 = pA0 - ebA, wB0 = pB0 - ebB, wC0 = pC0 - ebC, wD0 = pD0 - ebD;
    float accA = 0.f, accB = 0.f, accC = 0.f, accD = 0.f;
    const int lim0 = (nE < 64) ? nE : 64;
    for (int eo = 0; eo < lim0; eo += 2) {
        const int e = eo + half;
        const float wa = __shfl(wA0, e & 63);
        const float wb = __shfl(wB0, e & 63);
        const float wc = __shfl(wC0, e & 63);
        const float wd = __shfl(wD0, e & 63);
        const int   ce = __shfl(c0, e & 63);   // c0=0 on invalid lanes: safe
        const bool ok = e < lim0;
        const size_t vb0 = ((size_t)b * CC + ce) * EE + h0 * DD + d;
        const float vA = Vb[vb0];
        const float vB = Vb[vb0 + DD];
        const float vC = Vb[vb0 + 2 * DD];
        const float vD = Vb[vb0 + 3 * DD];
        accA = fmaf(ok ? wa : 0.f, vA, accA);
        accB = fmaf(ok ? wb : 0.f, vB, accB);
        accC = fmaf(ok ? wc : 0.f, vC, accC);
        accD = fmaf(ok ? wd : 0.f, vD, accD);
    }
    if (nE > 64) {
        const float wA1 = pA1 - ebA, wB1 = pB1 - ebB, wC1 = pC1 - ebC, wD1 = pD1 - ebD;
        for (int eo = 64; eo < nE; eo += 2) {
            const int e = eo + half;
            const float wa = __shfl(wA1, (e - 64) & 63);
            const float wb = __shfl(wB1, (e - 64) & 63);
            const float wc = __shfl(wC1, (e - 64) & 63);
            const float wd = __shfl(wD1, (e - 64) & 63);
            const int   ce = __shfl(c1, (e - 64) & 63);
            const bool ok = e < nE;
            const size_t vb0 = ((size_t)b * CC + ce) * EE + h0 * DD + d;
            const float vA = Vb[vb0];
            const float vB = Vb[vb0 + DD];
            const float vC = Vb[vb0 + 2 * DD];
            const float vD = Vb[vb0 + 3 * DD];
            accA = fmaf(ok ? wa : 0.f, vA, accA);
            accB = fmaf(ok ? wb : 0.f, vB, accB);
            accC = fmaf(ok ? wc : 0.f, vC, accC);
            accD = fmaf(ok ? wd : 0.f, vD, accD);
        }
    }
    accA += __shfl_xor(accA, 32);
    accB += __shfl_xor(accB, 32);
    accC += __shfl_xor(accC, 32);
    accD += __shfl_xor(accD, 32);

    // ---- epilogue: background via Vsum, write packed hi/lo bf16 ----
    if (lane < 32) {
        const float bgZ = (float)(CC - nE);
        const float invA = 1.f / (ZA + bgZ * ebA);
        const float invB = 1.f / (ZB + bgZ * ebB);
        const float invC = 1.f / (ZC + bgZ * ebC);
        const float invD = 1.f / (ZD + bgZ * ebD);
        const float* vsp = Vsum + (b * HH + h0) * DD + d;
        const float oA = (accA + ebA * vsp[0])      * invA;
        const float oB = (accB + ebB * vsp[DD])     * invB;
        const float oC = (accC + ebC * vsp[2 * DD]) * invC;
        const float oD = (accD + ebD * vsp[3 * DD]) * invD;
        const int rm = rowIdx;
        const int base_in = (d >> 3) * 128 + (rm & 15) * 8 + (d & 7);
        ushort oh, ol;
        split1(oA, oh, ol);
        int dst = ((rm >> 4) * 16 + h0) * 512 + base_in;
        Hbh[dst] = oh; Hbl[dst] = ol;
        split1(oB, oh, ol);
        dst = ((rm >> 4) * 16 + h0 + 1) * 512 + base_in;
        Hbh[dst] = oh; Hbl[dst] = ol;
        split1(oC, oh, ol);
        dst = ((rm >> 4) * 16 + h0 + 2) * 512 + base_in;
        Hbh[dst] = oh; Hbl[dst] = ol;
        split1(oD, oh, ol);
        dst = ((rm >> 4) * 16 + h0 + 3) * 512 + base_in;
        Hbh[dst] = oh; Hbl[dst] = ol;
    }
}

// ---------------------------------------------------------------------------
extern "C" void kernel_launch(void* const* d_in, const int* in_sizes, int n_in,
                              void* d_out, int out_size, void* d_ws, size_t ws_size,
                              hipStream_t stream)
{
    const float* rowe = (const float*)d_in[0];
    const float* cole = (const float*)d_in[1];
    const float* cost = (const float*)d_in[2];
    const float* Wq   = (const float*)d_in[3];
    const float* bq   = (const float*)d_in[4];
    const float* Wk   = (const float*)d_in[5];
    const float* bk   = (const float*)d_in[6];
    const float* Wv   = (const float*)d_in[7];
    const float* bv   = (const float*)d_in[8];
    const float* Wo   = (const float*)d_in[9];
    const float* bo   = (const float*)d_in[10];
    const float* W1   = (const float*)d_in[11];
    const float* b1   = (const float*)d_in[12];
    const float* W2   = (const float*)d_in[13];
    const float* b2   = (const float*)d_in[14];
    const float* beta = (const float*)d_in[15];
    float* out = (float*)d_out;

    // ---- workspace carve ----
    char* cur = (char*)d_ws;
    float* Qb   = (float*)cur; cur += (size_t)MROWS * EE * 4;
    float* Kb   = (float*)cur; cur += (size_t)MROWS * EE * 4;
    float* Vb   = (float*)cur; cur += (size_t)MROWS * EE * 4;
    float* Vsum = (float*)cur; cur += (size_t)BB * HH * DD * 4;
    ushort* reh = (ushort*)cur; cur += (size_t)MROWS * EE * 2;
    ushort* rel = (ushort*)cur; cur += (size_t)MROWS * EE * 2;
    ushort* ceh = (ushort*)cur; cur += (size_t)MROWS * EE * 2;
    ushort* cel = (ushort*)cur; cur += (size_t)MROWS * EE * 2;
    ushort* wqh = (ushort*)cur; cur += (size_t)EE * EE * 2;
    ushort* wql = (ushort*)cur; cur += (size_t)EE * EE * 2;
    ushort* wkh = (ushort*)cur; cur += (size_t)EE * EE * 2;
    ushort* wkl = (ushort*)cur; cur += (size_t)EE * EE * 2;
    ushort* wvh = (ushort*)cur; cur += (size_t)EE * EE * 2;
    ushort* wvl = (ushort*)cur; cur += (size_t)EE * EE * 2;
    ushort* woh = (ushort*)cur; cur += (size_t)EE * EE * 2;
    ushort* wol = (ushort*)cur; cur += (size_t)EE * EE * 2;
    ushort* hbh = (ushort*)cur; cur += (size_t)MROWS * EE * 2;
    ushort* hbl = (ushort*)cur; cur += (size_t)MROWS * EE * 2;
    int*    ecb = (int*)cur;   cur += (size_t)MROWS * MAXE * 4;
    float* ecwb = (float*)cur; cur += (size_t)MROWS * MAXE * 4;
    int*    nEb = (int*)cur;   cur += (size_t)MROWS * 4;

    split_kernel<<<dim3(768, 6), 256, 0, stream>>>(
        rowe, cole, Wq, Wk, Wv, Wo,
        reh, rel, ceh, cel, wqh, wql, wkh, wkl, wvh, wvl, woh, wol);

    edges_kernel<<<dim3(RR, BB), 64, 0, stream>>>(cost, ecb, ecwb, nEb);

    dim3 g1(16, 24, 3);
    qkv_kernel<<<g1, 256, 0, stream>>>(reh, rel, ceh, cel,
                                       wqh, wql, wkh, wkl, wvh, wvl,
                                       bq, bk, bv, Qb, Kb, Vb);

    dim3 gv(16, 4);
    vsum_kernel<<<gv, 256, 0, stream>>>(Vb, Vsum);

    dim3 g2(8, RR, 2);   // x = (b,hh) -> XCD pin; y = row; z = head-quad
    attn_kernel<<<g2, 64, 0, stream>>>(Qb, Kb, Vb, ecb, ecwb, nEb,
                                       W1, b1, W2, b2, beta, Vsum, hbh, hbl);

    dim3 g3(8, 24, 1);
    oproj_kernel<<<g3, 256, 0, stream>>>(hbh, hbl, woh, wol, bo, out);
}

// Round 15
// 86.815 us; speedup vs baseline: 1.2502x; 1.0186x over previous
//
#include <hip/hip_runtime.h>

// Problem constants
#define BB 4
#define RR 384
#define CC 384
#define EE 512
#define HH 16
#define DD 32
#define MROWS 1536   // B*R = B*C
#define MAXE 128     // edge-list stride (nE ~ 38 +- 6; 128 = 15 sigma)

typedef __attribute__((ext_vector_type(8))) short bf16x8;   // 8 bf16 = 4 VGPRs
typedef __attribute__((ext_vector_type(4))) float f32x4;

// ---------------------------------------------------------------------------
// f32 -> (hi, lo) bf16 split, RNE both times. x ~= hi + lo with ~2^-16 rel err.
// ---------------------------------------------------------------------------
__device__ __forceinline__ void split1(float x, ushort& h, ushort& l)
{
    const unsigned u = __float_as_uint(x);
    const unsigned r = (u + 0x7fffu + ((u >> 16) & 1u)) >> 16;
    h = (ushort)r;
    const float hf = __uint_as_float(r << 16);
    const float lo = x - hf;
    const unsigned u2 = __float_as_uint(lo);
    l = (ushort)((u2 + 0x7fffu + ((u2 >> 16) & 1u)) >> 16);
}

// Packed fragment address for element (r, k) of a [rows][512] matrix:
// lane l of the wave covering (r-tile, k-tile) reads elems [l*8, l*8+8).
__device__ __forceinline__ int packed_addr(int r, int k)
{
    return ((r >> 4) * 16 + (k >> 5)) * 512 + ((k >> 3) & 3) * 128 + (r & 15) * 8 + (k & 7);
}

// ---------------------------------------------------------------------------
// Split kernel: 6 arrays -> hi/lo bf16 planes in PACKED fragment layout.
// blockIdx.y == 6: fused edge-compaction (4 rows/block, 1 per wave). This is
// the SINGLE isolated change vs R14 (R8-forensics: multi-wave packing was
// exonerated by R11-R13; this tests the fusion suspect alone).
// ---------------------------------------------------------------------------
__global__ __launch_bounds__(256) void split_kernel(
    const float* __restrict__ rowe, const float* __restrict__ cole,
    const float* __restrict__ Wq, const float* __restrict__ Wk,
    const float* __restrict__ Wv, const float* __restrict__ Wo,
    const float* __restrict__ cost,
    ushort* __restrict__ reh, ushort* __restrict__ rel,
    ushort* __restrict__ ceh, ushort* __restrict__ cel,
    ushort* __restrict__ wqh, ushort* __restrict__ wql,
    ushort* __restrict__ wkh, ushort* __restrict__ wkl,
    ushort* __restrict__ wvh, ushort* __restrict__ wvl,
    ushort* __restrict__ woh, ushort* __restrict__ wol,
    int* __restrict__ ecb, float* __restrict__ ecwb, int* __restrict__ nEb)
{
    if (blockIdx.y == 6) {
        if (blockIdx.x >= MROWS / 4) return;
        const int rowIdx = blockIdx.x * 4 + (threadIdx.x >> 6);
        const int lane = threadIdx.x & 63;
        const float* crow = cost + (size_t)rowIdx * CC;
        const unsigned long long prefix = (1ull << lane) - 1ull;
        int nE = 0;
#pragma unroll
        for (int j = 0; j < 6; ++j) {
            const float cw = crow[lane + 64 * j];
            const unsigned long long mk = __ballot(cw > 0.f);
            if (cw > 0.f) {
                const int slot = nE + __popcll(mk & prefix);
                if (slot < MAXE) {
                    ecb [rowIdx * MAXE + slot] = lane + 64 * j;
                    ecwb[rowIdx * MAXE + slot] = cw;
                }
            }
            nE += __popcll(mk);
        }
        if (lane == 0) nEb[rowIdx] = (nE < MAXE) ? nE : MAXE;
        return;
    }

    const float* src; ushort* dh; ushort* dl; int n;
    switch (blockIdx.y) {
    case 0: src = rowe; dh = reh; dl = rel; n = MROWS * EE; break;
    case 1: src = cole; dh = ceh; dl = cel; n = MROWS * EE; break;
    case 2: src = Wq;   dh = wqh; dl = wql; n = EE * EE;    break;
    case 3: src = Wk;   dh = wkh; dl = wkl; n = EE * EE;    break;
    case 4: src = Wv;   dh = wvh; dl = wvl; n = EE * EE;    break;
    default: src = Wo;  dh = woh; dl = wol; n = EE * EE;    break;
    }
    const int i4 = blockIdx.x * 256 + threadIdx.x;
    if (i4 * 4 >= n) return;
    const float4 v = ((const float4*)src)[i4];
    ushort4 hs, ls;
    split1(v.x, hs.x, ls.x);
    split1(v.y, hs.y, ls.y);
    split1(v.z, hs.z, ls.z);
    split1(v.w, hs.w, ls.w);
    const int e0 = i4 * 4;
    const int dst = packed_addr(e0 >> 9, e0 & 511);   // (k&7) in {0,4}: aligned
    *(ushort4*)(dh + dst) = hs;
    *(ushort4*)(dl + dst) = ls;
}

// ---------------------------------------------------------------------------
// bf16x3 emulated-f32 GEMM on packed operands. 4 n-tiles per wave (16x64).
// Used by oproj (unchanged, proven).
// ---------------------------------------------------------------------------
__device__ __forceinline__ void gemm_bf16x3_body(
    const ushort* __restrict__ Ahi, const ushort* __restrict__ Alo,
    const ushort* __restrict__ Whi, const ushort* __restrict__ Wlo,
    const float* __restrict__ bias, float* __restrict__ Y,
    int Mt, int Nt0)
{
    constexpr int N = 512;
    const int lane = threadIdx.x & 63;
    const int col = lane & 15, kgrp = lane >> 4;

    const ushort* pah = Ahi + (size_t)Mt * 8192 + lane * 8;
    const ushort* pal = Alo + (size_t)Mt * 8192 + lane * 8;
    const ushort* pbh = Whi + (size_t)Nt0 * 8192 + lane * 8;
    const ushort* pbl = Wlo + (size_t)Nt0 * 8192 + lane * 8;

    f32x4 acc0 = {}, acc1 = {}, acc2 = {}, acc3 = {};

    bf16x8 ah  = *(const bf16x8*)(pah);
    bf16x8 al  = *(const bf16x8*)(pal);
    bf16x8 bh0 = *(const bf16x8*)(pbh);
    bf16x8 bh1 = *(const bf16x8*)(pbh + 8192);
    bf16x8 bh2 = *(const bf16x8*)(pbh + 16384);
    bf16x8 bh3 = *(const bf16x8*)(pbh + 24576);
    bf16x8 bl0 = *(const bf16x8*)(pbl);
    bf16x8 bl1 = *(const bf16x8*)(pbl + 8192);
    bf16x8 bl2 = *(const bf16x8*)(pbl + 16384);
    bf16x8 bl3 = *(const bf16x8*)(pbl + 24576);

#pragma unroll 4
    for (int kt = 0; kt < 16; ++kt) {
        bf16x8 nah = ah, nal = al;
        bf16x8 nbh0 = bh0, nbh1 = bh1, nbh2 = bh2, nbh3 = bh3;
        bf16x8 nbl0 = bl0, nbl1 = bl1, nbl2 = bl2, nbl3 = bl3;
        if (kt < 15) {
            const int ko = (kt + 1) * 512;
            nah  = *(const bf16x8*)(pah + ko);
            nal  = *(const bf16x8*)(pal + ko);
            nbh0 = *(const bf16x8*)(pbh + ko);
            nbh1 = *(const bf16x8*)(pbh + ko + 8192);
            nbh2 = *(const bf16x8*)(pbh + ko + 16384);
            nbh3 = *(const bf16x8*)(pbh + ko + 24576);
            nbl0 = *(const bf16x8*)(pbl + ko);
            nbl1 = *(const bf16x8*)(pbl + ko + 8192);
            nbl2 = *(const bf16x8*)(pbl + ko + 16384);
            nbl3 = *(const bf16x8*)(pbl + ko + 24576);
        }
        acc0 = __builtin_amdgcn_mfma_f32_16x16x32_bf16(ah, bh0, acc0, 0, 0, 0);
        acc0 = __builtin_amdgcn_mfma_f32_16x16x32_bf16(ah, bl0, acc0, 0, 0, 0);
        acc0 = __builtin_amdgcn_mfma_f32_16x16x32_bf16(al, bh0, acc0, 0, 0, 0);
        acc1 = __builtin_amdgcn_mfma_f32_16x16x32_bf16(ah, bh1, acc1, 0, 0, 0);
        acc1 = __builtin_amdgcn_mfma_f32_16x16x32_bf16(ah, bl1, acc1, 0, 0, 0);
        acc1 = __builtin_amdgcn_mfma_f32_16x16x32_bf16(al, bh1, acc1, 0, 0, 0);
        acc2 = __builtin_amdgcn_mfma_f32_16x16x32_bf16(ah, bh2, acc2, 0, 0, 0);
        acc2 = __builtin_amdgcn_mfma_f32_16x16x32_bf16(ah, bl2, acc2, 0, 0, 0);
        acc2 = __builtin_amdgcn_mfma_f32_16x16x32_bf16(al, bh2, acc2, 0, 0, 0);
        acc3 = __builtin_amdgcn_mfma_f32_16x16x32_bf16(ah, bh3, acc3, 0, 0, 0);
        acc3 = __builtin_amdgcn_mfma_f32_16x16x32_bf16(ah, bl3, acc3, 0, 0, 0);
        acc3 = __builtin_amdgcn_mfma_f32_16x16x32_bf16(al, bh3, acc3, 0, 0, 0);
        ah = nah; al = nal;
        bh0 = nbh0; bh1 = nbh1; bh2 = nbh2; bh3 = nbh3;
        bl0 = nbl0; bl1 = nbl1; bl2 = nbl2; bl3 = nbl3;
    }

    const f32x4 accs[4] = {acc0, acc1, acc2, acc3};
#pragma unroll
    for (int t = 0; t < 4; ++t) {
        const int n = (Nt0 + t) * 16 + col;
        const float bn = bias[n];
#pragma unroll
        for (int j = 0; j < 4; ++j) {
            const int m = Mt * 16 + kgrp * 4 + j;
            Y[m * N + n] = accs[t][j] + bn;
        }
    }
}

// ---------------------------------------------------------------------------
// Fine-grained GEMM body: 2 n-tiles per wave (16x32), used by qkv (R14-proven).
// ---------------------------------------------------------------------------
__device__ __forceinline__ void gemm_bf16x3_body2(
    const ushort* __restrict__ Ahi, const ushort* __restrict__ Alo,
    const ushort* __restrict__ Whi, const ushort* __restrict__ Wlo,
    const float* __restrict__ bias, float* __restrict__ Y,
    int Mt, int Nt0)
{
    constexpr int N = 512;
    const int lane = threadIdx.x & 63;
    const int col = lane & 15, kgrp = lane >> 4;

    const ushort* pah = Ahi + (size_t)Mt * 8192 + lane * 8;
    const ushort* pal = Alo + (size_t)Mt * 8192 + lane * 8;
    const ushort* pbh = Whi + (size_t)Nt0 * 8192 + lane * 8;
    const ushort* pbl = Wlo + (size_t)Nt0 * 8192 + lane * 8;

    f32x4 acc0 = {}, acc1 = {};

#pragma unroll 4
    for (int kt = 0; kt < 16; ++kt) {
        const int ko = kt * 512;
        const bf16x8 ah  = *(const bf16x8*)(pah + ko);
        const bf16x8 al  = *(const bf16x8*)(pal + ko);
        const bf16x8 bh0 = *(const bf16x8*)(pbh + ko);
        const bf16x8 bh1 = *(const bf16x8*)(pbh + ko + 8192);
        const bf16x8 bl0 = *(const bf16x8*)(pbl + ko);
        const bf16x8 bl1 = *(const bf16x8*)(pbl + ko + 8192);
        acc0 = __builtin_amdgcn_mfma_f32_16x16x32_bf16(ah, bh0, acc0, 0, 0, 0);
        acc0 = __builtin_amdgcn_mfma_f32_16x16x32_bf16(ah, bl0, acc0, 0, 0, 0);
        acc0 = __builtin_amdgcn_mfma_f32_16x16x32_bf16(al, bh0, acc0, 0, 0, 0);
        acc1 = __builtin_amdgcn_mfma_f32_16x16x32_bf16(ah, bh1, acc1, 0, 0, 0);
        acc1 = __builtin_amdgcn_mfma_f32_16x16x32_bf16(ah, bl1, acc1, 0, 0, 0);
        acc1 = __builtin_amdgcn_mfma_f32_16x16x32_bf16(al, bh1, acc1, 0, 0, 0);
    }

    const f32x4 accs[2] = {acc0, acc1};
#pragma unroll
    for (int t = 0; t < 2; ++t) {
        const int n = (Nt0 + t) * 16 + col;
        const float bn = bias[n];
#pragma unroll
        for (int j = 0; j < 4; ++j) {
            const int m = Mt * 16 + kgrp * 4 + j;
            Y[m * N + n] = accs[t][j] + bn;
        }
    }
}

// qkv: grid (16, 24, 3), 256 thr (4 waves over m). Wave tile 16m x 32n.
__global__ __launch_bounds__(256) void qkv_kernel(
    const ushort* __restrict__ reh, const ushort* __restrict__ rel,
    const ushort* __restrict__ ceh, const ushort* __restrict__ cel,
    const ushort* __restrict__ wqh, const ushort* __restrict__ wql,
    const ushort* __restrict__ wkh, const ushort* __restrict__ wkl,
    const ushort* __restrict__ wvh, const ushort* __restrict__ wvl,
    const float* __restrict__ bq, const float* __restrict__ bk,
    const float* __restrict__ bv,
    float* __restrict__ Qo, float* __restrict__ Ko, float* __restrict__ Vo)
{
    const int l = blockIdx.x + (blockIdx.y << 4);
    const int a = l & 7;
    const int t = l >> 3;
    const int Bm = a * 3 + (t >> 4);
    const int Bx = t & 15;
    const int Mt = Bm * 4 + (threadIdx.x >> 6);
    const int Nt0 = Bx * 2;
    if (blockIdx.z == 0)      gemm_bf16x3_body2(reh, rel, wqh, wql, bq, Qo, Mt, Nt0);
    else if (blockIdx.z == 1) gemm_bf16x3_body2(ceh, cel, wkh, wkl, bk, Ko, Mt, Nt0);
    else                      gemm_bf16x3_body2(ceh, cel, wvh, wvl, bv, Vo, Mt, Nt0);
}

__global__ __launch_bounds__(256) void oproj_kernel(
    const ushort* __restrict__ hbh, const ushort* __restrict__ hbl,
    const ushort* __restrict__ woh, const ushort* __restrict__ wol,
    const float* __restrict__ bo, float* __restrict__ out)
{
    const int l = blockIdx.x + (blockIdx.y << 3);
    const int Bm = (l & 7) * 3 + (l >> 6);
    const int Bx = (l >> 3) & 7;
    const int Mt = Bm * 4 + (threadIdx.x >> 6);
    const int Nt0 = Bx * 4;
    gemm_bf16x3_body(hbh, hbl, woh, wol, bo, out, Mt, Nt0);
}

// ---------------------------------------------------------------------------
// Vsum kernel: Vsum[b][h][d] = sum_c V[b][c][h*32+d]. Grid (16,4), 256 thr.
// ---------------------------------------------------------------------------
__global__ __launch_bounds__(256) void vsum_kernel(const float* __restrict__ Vb,
                                                   float* __restrict__ Vsum)
{
    __shared__ float part[8][32];
    const int h = blockIdx.x, b = blockIdx.y;
    const int d = threadIdx.x & 31, g = threadIdx.x >> 5;
    float acc = 0.f;
    for (int c = g; c < CC; c += 8)
        acc += Vb[(b * CC + c) * EE + h * DD + d];
    part[g][d] = acc;
    __syncthreads();
    if (g == 0) {
        float s = 0.f;
#pragma unroll
        for (int gg = 0; gg < 8; ++gg) s += part[gg][d];
        Vsum[(b * HH + h) * DD + d] = s;
    }
}

// ---------------------------------------------------------------------------
// Edge scorer: dot(q,k) -> per-head 2x16x1 MLP -> p = exp(tanh*10 - 10).
// All q / MLP params come from wave-uniform addresses -> SGPRs.
// ---------------------------------------------------------------------------
__device__ __forceinline__ float score_edge(
    int c, float cw, int b, int h,
    const float* __restrict__ qrow, const float* __restrict__ Kb,
    const float* __restrict__ w10p, const float* __restrict__ w11p,
    const float* __restrict__ b1p, const float* __restrict__ w2p, float b2h)
{
    const float* kp = Kb + ((size_t)b * CC + c) * EE + h * DD;
    float d0 = 0.f, d1 = 0.f, d2 = 0.f, d3 = 0.f;
#pragma unroll
    for (int dq = 0; dq < 8; ++dq) {
        const float4 kv = *(const float4*)(kp + dq * 4);
        d0 = fmaf(qrow[dq * 4 + 0], kv.x, d0);
        d1 = fmaf(qrow[dq * 4 + 1], kv.y, d1);
        d2 = fmaf(qrow[dq * 4 + 2], kv.z, d2);
        d3 = fmaf(qrow[dq * 4 + 3], kv.w, d3);
    }
    const float dot = ((d0 + d1) + (d2 + d3)) * 0.17677669529663687f;
    float l0 = b2h, l1 = 0.f;
#pragma unroll
    for (int mm = 0; mm < 16; mm += 2) {
        const float h0 = fmaf(dot, w10p[mm],     fmaf(cw, w11p[mm],     b1p[mm]));
        const float h1 = fmaf(dot, w10p[mm + 1], fmaf(cw, w11p[mm + 1], b1p[mm + 1]));
        l0 = fmaf(fmaxf(h0, 0.f), w2p[mm],     l0);
        l1 = fmaf(fmaxf(h1, 0.f), w2p[mm + 1], l1);
    }
    // s = tanh(l)*10; p = exp(s-10) = exp(-20/(e^{2l}+1)); bounded (no ovf).
    const float ex = __expf(2.f * (l0 + l1));
    return __expf(-20.f / (ex + 1.f));
}

// ---------------------------------------------------------------------------
// Semi-sparse attention: R10-EXACT champion. ONE WAVE per (b, r, head-QUAD).
// Fixed-max-10 softmax (scores tanh*10 in (-10,10), beta<=10):
//   out = (sum_E (p_e - e^{b-10}) V_e + e^{b-10} Vsum) / (sum p + (C-nE) e^{b-10})
// Grid (8, RR, 2): blockIdx.x = (b,hh) -> XCD pin (R6: FETCH -55%).
// ---------------------------------------------------------------------------
__global__ __launch_bounds__(64) void attn_kernel(
    const float* __restrict__ Qb, const float* __restrict__ Kb,
    const float* __restrict__ Vb,
    const int* __restrict__ ecb, const float* __restrict__ ecwb,
    const int* __restrict__ nEb,
    const float* __restrict__ W1, const float* __restrict__ b1,
    const float* __restrict__ W2, const float* __restrict__ b2,
    const float* __restrict__ beta,
    const float* __restrict__ Vsum,
    ushort* __restrict__ Hbh, ushort* __restrict__ Hbl)
{
    const int combo = blockIdx.x;            // 0..7 -> XCD
    const int b = combo >> 1, hh = combo & 1;
    const int r = blockIdx.y;
    const int h0 = hh * 8 + blockIdx.z * 4;  // this wave: heads h0..h0+3
    const int lane = threadIdx.x;
    const int rowIdx = b * RR + r;

    const int nE = nEb[rowIdx];              // wave-uniform
    const float b2A = b2[h0], b2B = b2[h0 + 1], b2C = b2[h0 + 2], b2D = b2[h0 + 3];
    const float ebA = __expf(beta[h0]     - 10.f);
    const float ebB = __expf(beta[h0 + 1] - 10.f);
    const float ebC = __expf(beta[h0 + 2] - 10.f);
    const float ebD = __expf(beta[h0 + 3] - 10.f);

    const float* qA = Qb + (size_t)rowIdx * EE + h0 * DD;    // uniform -> SGPR
    const float* qB = qA + DD;
    const float* qC = qA + 2 * DD;
    const float* qD = qA + 3 * DD;
    const float* w10A = W1 + h0 * 32;
    const float* w11A = w10A + 16;
    const float* b1A  = b1 + h0 * 16;
    const float* w2A  = W2 + h0 * 16;

    // ---- scoring: lane e = edge e, 4 heads (independent chains) ----
    int c0 = 0, c1 = 0;
    float pA0 = 0.f, pB0 = 0.f, pC0 = 0.f, pD0 = 0.f;
    float pA1 = 0.f, pB1 = 0.f, pC1 = 0.f, pD1 = 0.f;
    if (lane < nE) {
        c0 = ecb[rowIdx * MAXE + lane];
        const float cw = ecwb[rowIdx * MAXE + lane];
        pA0 = score_edge(c0, cw, b, h0,     qA, Kb, w10A,      w11A,      b1A,      w2A,      b2A);
        pB0 = score_edge(c0, cw, b, h0 + 1, qB, Kb, w10A + 32, w11A + 32, b1A + 16, w2A + 16, b2B);
        pC0 = score_edge(c0, cw, b, h0 + 2, qC, Kb, w10A + 64, w11A + 64, b1A + 32, w2A + 32, b2C);
        pD0 = score_edge(c0, cw, b, h0 + 3, qD, Kb, w10A + 96, w11A + 96, b1A + 48, w2A + 48, b2D);
    }
    if (nE > 64) {                           // wave-uniform rare branch
        const int e1 = lane + 64;
        if (e1 < nE) {
            c1 = ecb[rowIdx * MAXE + e1];
            const float cw = ecwb[rowIdx * MAXE + e1];
            pA1 = score_edge(c1, cw, b, h0,     qA, Kb, w10A,      w11A,      b1A,      w2A,      b2A);
            pB1 = score_edge(c1, cw, b, h0 + 1, qB, Kb, w10A + 32, w11A + 32, b1A + 16, w2A + 16, b2B);
            pC1 = score_edge(c1, cw, b, h0 + 2, qC, Kb, w10A + 64, w11A + 64, b1A + 32, w2A + 32, b2C);
            pD1 = score_edge(c1, cw, b, h0 + 3, qD, Kb, w10A + 96, w11A + 96, b1A + 48, w2A + 48, b2D);
        }
    }

    // ---- Z: full-wave reduce, 4 heads ----
    float ZA = pA0 + pA1, ZB = pB0 + pB1, ZC = pC0 + pC1, ZD = pD0 + pD1;
#pragma unroll
    for (int off = 1; off < 64; off <<= 1) {
        ZA += __shfl_xor(ZA, off);
        ZB += __shfl_xor(ZB, off);
        ZC += __shfl_xor(ZC, off);
        ZD += __shfl_xor(ZD, off);
    }

    // ---- PV: 2 edges/iter, 4 heads -> 4 loads + 4 FMA chains in flight ----
    const int half = lane >> 5, d = lane & 31;
    const float wA0 = pA0 - ebA, wB0 = pB0 - ebB, wC0 = pC0 - ebC, wD0 = pD0 - ebD;
    float accA = 0.f, accB = 0.f, accC = 0.f, accD = 0.f;
    const int lim0 = (nE < 64) ? nE : 64;
    for (int eo = 0; eo < lim0; eo += 2) {
        const int e = eo + half;
        const float wa = __shfl(wA0, e & 63);
        const float wb = __shfl(wB0, e & 63);
        const float wc = __shfl(wC0, e & 63);
        const float wd = __shfl(wD0, e & 63);
        const int   ce = __shfl(c0, e & 63);   // c0=0 on invalid lanes: safe
        const bool ok = e < lim0;
        const size_t vb0 = ((size_t)b * CC + ce) * EE + h0 * DD + d;
        const float vA = Vb[vb0];
        const float vB = Vb[vb0 + DD];
        const float vC = Vb[vb0 + 2 * DD];
        const float vD = Vb[vb0 + 3 * DD];
        accA = fmaf(ok ? wa : 0.f, vA, accA);
        accB = fmaf(ok ? wb : 0.f, vB, accB);
        accC = fmaf(ok ? wc : 0.f, vC, accC);
        accD = fmaf(ok ? wd : 0.f, vD, accD);
    }
    if (nE > 64) {
        const float wA1 = pA1 - ebA, wB1 = pB1 - ebB, wC1 = pC1 - ebC, wD1 = pD1 - ebD;
        for (int eo = 64; eo < nE; eo += 2) {
            const int e = eo + half;
            const float wa = __shfl(wA1, (e - 64) & 63);
            const float wb = __shfl(wB1, (e - 64) & 63);
            const float wc = __shfl(wC1, (e - 64) & 63);
            const float wd = __shfl(wD1, (e - 64) & 63);
            const int   ce = __shfl(c1, (e - 64) & 63);
            const bool ok = e < nE;
            const size_t vb0 = ((size_t)b * CC + ce) * EE + h0 * DD + d;
            const float vA = Vb[vb0];
            const float vB = Vb[vb0 + DD];
            const float vC = Vb[vb0 + 2 * DD];
            const float vD = Vb[vb0 + 3 * DD];
            accA = fmaf(ok ? wa : 0.f, vA, accA);
            accB = fmaf(ok ? wb : 0.f, vB, accB);
            accC = fmaf(ok ? wc : 0.f, vC, accC);
            accD = fmaf(ok ? wd : 0.f, vD, accD);
        }
    }
    accA += __shfl_xor(accA, 32);
    accB += __shfl_xor(accB, 32);
    accC += __shfl_xor(accC, 32);
    accD += __shfl_xor(accD, 32);

    // ---- epilogue: background via Vsum, write packed hi/lo bf16 ----
    if (lane < 32) {
        const float bgZ = (float)(CC - nE);
        const float invA = 1.f / (ZA + bgZ * ebA);
        const float invB = 1.f / (ZB + bgZ * ebB);
        const float invC = 1.f / (ZC + bgZ * ebC);
        const float invD = 1.f / (ZD + bgZ * ebD);
        const float* vsp = Vsum + (b * HH + h0) * DD + d;
        const float oA = (accA + ebA * vsp[0])      * invA;
        const float oB = (accB + ebB * vsp[DD])     * invB;
        const float oC = (accC + ebC * vsp[2 * DD]) * invC;
        const float oD = (accD + ebD * vsp[3 * DD]) * invD;
        const int rm = rowIdx;
        const int base_in = (d >> 3) * 128 + (rm & 15) * 8 + (d & 7);
        ushort oh, ol;
        split1(oA, oh, ol);
        int dst = ((rm >> 4) * 16 + h0) * 512 + base_in;
        Hbh[dst] = oh; Hbl[dst] = ol;
        split1(oB, oh, ol);
        dst = ((rm >> 4) * 16 + h0 + 1) * 512 + base_in;
        Hbh[dst] = oh; Hbl[dst] = ol;
        split1(oC, oh, ol);
        dst = ((rm >> 4) * 16 + h0 + 2) * 512 + base_in;
        Hbh[dst] = oh; Hbl[dst] = ol;
        split1(oD, oh, ol);
        dst = ((rm >> 4) * 16 + h0 + 3) * 512 + base_in;
        Hbh[dst] = oh; Hbl[dst] = ol;
    }
}

// ---------------------------------------------------------------------------
extern "C" void kernel_launch(void* const* d_in, const int* in_sizes, int n_in,
                              void* d_out, int out_size, void* d_ws, size_t ws_size,
                              hipStream_t stream)
{
    const float* rowe = (const float*)d_in[0];
    const float* cole = (const float*)d_in[1];
    const float* cost = (const float*)d_in[2];
    const float* Wq   = (const float*)d_in[3];
    const float* bq   = (const float*)d_in[4];
    const float* Wk   = (const float*)d_in[5];
    const float* bk   = (const float*)d_in[6];
    const float* Wv   = (const float*)d_in[7];
    const float* bv   = (const float*)d_in[8];
    const float* Wo   = (const float*)d_in[9];
    const float* bo   = (const float*)d_in[10];
    const float* W1   = (const float*)d_in[11];
    const float* b1   = (const float*)d_in[12];
    const float* W2   = (const float*)d_in[13];
    const float* b2   = (const float*)d_in[14];
    const float* beta = (const float*)d_in[15];
    float* out = (float*)d_out;

    // ---- workspace carve ----
    char* cur = (char*)d_ws;
    float* Qb   = (float*)cur; cur += (size_t)MROWS * EE * 4;
    float* Kb   = (float*)cur; cur += (size_t)MROWS * EE * 4;
    float* Vb   = (float*)cur; cur += (size_t)MROWS * EE * 4;
    float* Vsum = (float*)cur; cur += (size_t)BB * HH * DD * 4;
    ushort* reh = (ushort*)cur; cur += (size_t)MROWS * EE * 2;
    ushort* rel = (ushort*)cur; cur += (size_t)MROWS * EE * 2;
    ushort* ceh = (ushort*)cur; cur += (size_t)MROWS * EE * 2;
    ushort* cel = (ushort*)cur; cur += (size_t)MROWS * EE * 2;
    ushort* wqh = (ushort*)cur; cur += (size_t)EE * EE * 2;
    ushort* wql = (ushort*)cur; cur += (size_t)EE * EE * 2;
    ushort* wkh = (ushort*)cur; cur += (size_t)EE * EE * 2;
    ushort* wkl = (ushort*)cur; cur += (size_t)EE * EE * 2;
    ushort* wvh = (ushort*)cur; cur += (size_t)EE * EE * 2;
    ushort* wvl = (ushort*)cur; cur += (size_t)EE * EE * 2;
    ushort* woh = (ushort*)cur; cur += (size_t)EE * EE * 2;
    ushort* wol = (ushort*)cur; cur += (size_t)EE * EE * 2;
    ushort* hbh = (ushort*)cur; cur += (size_t)MROWS * EE * 2;
    ushort* hbl = (ushort*)cur; cur += (size_t)MROWS * EE * 2;
    int*    ecb = (int*)cur;   cur += (size_t)MROWS * MAXE * 4;
    float* ecwb = (float*)cur; cur += (size_t)MROWS * MAXE * 4;
    int*    nEb = (int*)cur;   cur += (size_t)MROWS * 4;

    split_kernel<<<dim3(768, 7), 256, 0, stream>>>(
        rowe, cole, Wq, Wk, Wv, Wo, cost,
        reh, rel, ceh, cel, wqh, wql, wkh, wkl, wvh, wvl, woh, wol,
        ecb, ecwb, nEb);

    dim3 g1(16, 24, 3);
    qkv_kernel<<<g1, 256, 0, stream>>>(reh, rel, ceh, cel,
                                       wqh, wql, wkh, wkl, wvh, wvl,
                                       bq, bk, bv, Qb, Kb, Vb);

    dim3 gv(16, 4);
    vsum_kernel<<<gv, 256, 0, stream>>>(Vb, Vsum);

    dim3 g2(8, RR, 2);   // x = (b,hh) -> XCD pin; y = row; z = head-quad
    attn_kernel<<<g2, 64, 0, stream>>>(Qb, Kb, Vb, ecb, ecwb, nEb,
                                       W1, b1, W2, b2, beta, Vsum, hbh, hbl);

    dim3 g3(8, 24, 1);
    oproj_kernel<<<g3, 256, 0, stream>>>(hbh, hbl, woh, wol, bo, out);
}

// Round 16
// 85.486 us; speedup vs baseline: 1.2697x; 1.0156x over previous
//
#include <hip/hip_runtime.h>

// Problem constants
#define BB 4
#define RR 384
#define CC 384
#define EE 512
#define HH 16
#define DD 32
#define MROWS 1536   // B*R = B*C
#define MAXE 128     // edge-list stride (nE ~ 38 +- 6; 128 = 15 sigma)

typedef __attribute__((ext_vector_type(8))) short bf16x8;   // 8 bf16 = 4 VGPRs
typedef __attribute__((ext_vector_type(4))) float f32x4;

// ---------------------------------------------------------------------------
// f32 -> (hi, lo) bf16 split, RNE both times. x ~= hi + lo with ~2^-16 rel err.
// ---------------------------------------------------------------------------
__device__ __forceinline__ void split1(float x, ushort& h, ushort& l)
{
    const unsigned u = __float_as_uint(x);
    const unsigned r = (u + 0x7fffu + ((u >> 16) & 1u)) >> 16;
    h = (ushort)r;
    const float hf = __uint_as_float(r << 16);
    const float lo = x - hf;
    const unsigned u2 = __float_as_uint(lo);
    l = (ushort)((u2 + 0x7fffu + ((u2 >> 16) & 1u)) >> 16);
}

// Packed fragment address for element (r, k) of a [rows][512] matrix:
// lane l of the wave covering (r-tile, k-tile) reads elems [l*8, l*8+8).
__device__ __forceinline__ int packed_addr(int r, int k)
{
    return ((r >> 4) * 16 + (k >> 5)) * 512 + ((k >> 3) & 3) * 128 + (r & 15) * 8 + (k & 7);
}

// ---------------------------------------------------------------------------
// Split kernel: 6 arrays -> hi/lo bf16 planes in PACKED fragment layout.
// blockIdx.y == 6: fused edge-compaction (4 rows/block, 1 per wave) [R15-proven].
// ---------------------------------------------------------------------------
__global__ __launch_bounds__(256) void split_kernel(
    const float* __restrict__ rowe, const float* __restrict__ cole,
    const float* __restrict__ Wq, const float* __restrict__ Wk,
    const float* __restrict__ Wv, const float* __restrict__ Wo,
    const float* __restrict__ cost,
    ushort* __restrict__ reh, ushort* __restrict__ rel,
    ushort* __restrict__ ceh, ushort* __restrict__ cel,
    ushort* __restrict__ wqh, ushort* __restrict__ wql,
    ushort* __restrict__ wkh, ushort* __restrict__ wkl,
    ushort* __restrict__ wvh, ushort* __restrict__ wvl,
    ushort* __restrict__ woh, ushort* __restrict__ wol,
    int* __restrict__ ecb, float* __restrict__ ecwb, int* __restrict__ nEb)
{
    if (blockIdx.y == 6) {
        if (blockIdx.x >= MROWS / 4) return;
        const int rowIdx = blockIdx.x * 4 + (threadIdx.x >> 6);
        const int lane = threadIdx.x & 63;
        const float* crow = cost + (size_t)rowIdx * CC;
        const unsigned long long prefix = (1ull << lane) - 1ull;
        int nE = 0;
#pragma unroll
        for (int j = 0; j < 6; ++j) {
            const float cw = crow[lane + 64 * j];
            const unsigned long long mk = __ballot(cw > 0.f);
            if (cw > 0.f) {
                const int slot = nE + __popcll(mk & prefix);
                if (slot < MAXE) {
                    ecb [rowIdx * MAXE + slot] = lane + 64 * j;
                    ecwb[rowIdx * MAXE + slot] = cw;
                }
            }
            nE += __popcll(mk);
        }
        if (lane == 0) nEb[rowIdx] = (nE < MAXE) ? nE : MAXE;
        return;
    }

    const float* src; ushort* dh; ushort* dl; int n;
    switch (blockIdx.y) {
    case 0: src = rowe; dh = reh; dl = rel; n = MROWS * EE; break;
    case 1: src = cole; dh = ceh; dl = cel; n = MROWS * EE; break;
    case 2: src = Wq;   dh = wqh; dl = wql; n = EE * EE;    break;
    case 3: src = Wk;   dh = wkh; dl = wkl; n = EE * EE;    break;
    case 4: src = Wv;   dh = wvh; dl = wvl; n = EE * EE;    break;
    default: src = Wo;  dh = woh; dl = wol; n = EE * EE;    break;
    }
    const int i4 = blockIdx.x * 256 + threadIdx.x;
    if (i4 * 4 >= n) return;
    const float4 v = ((const float4*)src)[i4];
    ushort4 hs, ls;
    split1(v.x, hs.x, ls.x);
    split1(v.y, hs.y, ls.y);
    split1(v.z, hs.z, ls.z);
    split1(v.w, hs.w, ls.w);
    const int e0 = i4 * 4;
    const int dst = packed_addr(e0 >> 9, e0 & 511);   // (k&7) in {0,4}: aligned
    *(ushort4*)(dh + dst) = hs;
    *(ushort4*)(dl + dst) = ls;
}

// ---------------------------------------------------------------------------
// Fine-grained GEMM body: 2 n-tiles per wave (16x32). Used by qkv (R14) and
// now oproj (same transformation class, proven safe): doubles block count for
// the worst-subscribed kernel (oproj was 192 blocks = 0.75/CU).
// ---------------------------------------------------------------------------
__device__ __forceinline__ void gemm_bf16x3_body2(
    const ushort* __restrict__ Ahi, const ushort* __restrict__ Alo,
    const ushort* __restrict__ Whi, const ushort* __restrict__ Wlo,
    const float* __restrict__ bias, float* __restrict__ Y,
    int Mt, int Nt0)
{
    constexpr int N = 512;
    const int lane = threadIdx.x & 63;
    const int col = lane & 15, kgrp = lane >> 4;

    const ushort* pah = Ahi + (size_t)Mt * 8192 + lane * 8;
    const ushort* pal = Alo + (size_t)Mt * 8192 + lane * 8;
    const ushort* pbh = Whi + (size_t)Nt0 * 8192 + lane * 8;
    const ushort* pbl = Wlo + (size_t)Nt0 * 8192 + lane * 8;

    f32x4 acc0 = {}, acc1 = {};

#pragma unroll 4
    for (int kt = 0; kt < 16; ++kt) {
        const int ko = kt * 512;
        const bf16x8 ah  = *(const bf16x8*)(pah + ko);
        const bf16x8 al  = *(const bf16x8*)(pal + ko);
        const bf16x8 bh0 = *(const bf16x8*)(pbh + ko);
        const bf16x8 bh1 = *(const bf16x8*)(pbh + ko + 8192);
        const bf16x8 bl0 = *(const bf16x8*)(pbl + ko);
        const bf16x8 bl1 = *(const bf16x8*)(pbl + ko + 8192);
        acc0 = __builtin_amdgcn_mfma_f32_16x16x32_bf16(ah, bh0, acc0, 0, 0, 0);
        acc0 = __builtin_amdgcn_mfma_f32_16x16x32_bf16(ah, bl0, acc0, 0, 0, 0);
        acc0 = __builtin_amdgcn_mfma_f32_16x16x32_bf16(al, bh0, acc0, 0, 0, 0);
        acc1 = __builtin_amdgcn_mfma_f32_16x16x32_bf16(ah, bh1, acc1, 0, 0, 0);
        acc1 = __builtin_amdgcn_mfma_f32_16x16x32_bf16(ah, bl1, acc1, 0, 0, 0);
        acc1 = __builtin_amdgcn_mfma_f32_16x16x32_bf16(al, bh1, acc1, 0, 0, 0);
    }

    const f32x4 accs[2] = {acc0, acc1};
#pragma unroll
    for (int t = 0; t < 2; ++t) {
        const int n = (Nt0 + t) * 16 + col;
        const float bn = bias[n];
#pragma unroll
        for (int j = 0; j < 4; ++j) {
            const int m = Mt * 16 + kgrp * 4 + j;
            Y[m * N + n] = accs[t][j] + bn;
        }
    }
}

// qkv: grid (16, 24, 3), 256 thr (4 waves over m). Wave tile 16m x 32n.
__global__ __launch_bounds__(256) void qkv_kernel(
    const ushort* __restrict__ reh, const ushort* __restrict__ rel,
    const ushort* __restrict__ ceh, const ushort* __restrict__ cel,
    const ushort* __restrict__ wqh, const ushort* __restrict__ wql,
    const ushort* __restrict__ wkh, const ushort* __restrict__ wkl,
    const ushort* __restrict__ wvh, const ushort* __restrict__ wvl,
    const float* __restrict__ bq, const float* __restrict__ bk,
    const float* __restrict__ bv,
    float* __restrict__ Qo, float* __restrict__ Ko, float* __restrict__ Vo)
{
    const int l = blockIdx.x + (blockIdx.y << 4);
    const int a = l & 7;
    const int t = l >> 3;
    const int Bm = a * 3 + (t >> 4);
    const int Bx = t & 15;
    const int Mt = Bm * 4 + (threadIdx.x >> 6);
    const int Nt0 = Bx * 2;
    if (blockIdx.z == 0)      gemm_bf16x3_body2(reh, rel, wqh, wql, bq, Qo, Mt, Nt0);
    else if (blockIdx.z == 1) gemm_bf16x3_body2(ceh, cel, wkh, wkl, bk, Ko, Mt, Nt0);
    else                      gemm_bf16x3_body2(ceh, cel, wvh, wvl, bv, Vo, Mt, Nt0);
}

// oproj: grid (16, 24, 1), fine-grained body2 (was 4-tile, 192 blocks).
__global__ __launch_bounds__(256) void oproj_kernel(
    const ushort* __restrict__ hbh, const ushort* __restrict__ hbl,
    const ushort* __restrict__ woh, const ushort* __restrict__ wol,
    const float* __restrict__ bo, float* __restrict__ out)
{
    const int l = blockIdx.x + (blockIdx.y << 4);
    const int a = l & 7;
    const int t = l >> 3;
    const int Bm = a * 3 + (t >> 4);
    const int Bx = t & 15;
    const int Mt = Bm * 4 + (threadIdx.x >> 6);
    const int Nt0 = Bx * 2;
    gemm_bf16x3_body2(hbh, hbl, woh, wol, bo, out, Mt, Nt0);
}

// ---------------------------------------------------------------------------
// Vsum kernel: Vsum[b][h][d] = sum_c V[b][c][h*32+d]. Grid (16,4), 256 thr.
// ---------------------------------------------------------------------------
__global__ __launch_bounds__(256) void vsum_kernel(const float* __restrict__ Vb,
                                                   float* __restrict__ Vsum)
{
    __shared__ float part[8][32];
    const int h = blockIdx.x, b = blockIdx.y;
    const int d = threadIdx.x & 31, g = threadIdx.x >> 5;
    float acc = 0.f;
    for (int c = g; c < CC; c += 8)
        acc += Vb[(b * CC + c) * EE + h * DD + d];
    part[g][d] = acc;
    __syncthreads();
    if (g == 0) {
        float s = 0.f;
#pragma unroll
        for (int gg = 0; gg < 8; ++gg) s += part[gg][d];
        Vsum[(b * HH + h) * DD + d] = s;
    }
}

// ---------------------------------------------------------------------------
// Edge scorer: dot(q,k) -> per-head 2x16x1 MLP -> p = exp(tanh*10 - 10).
// All q / MLP params come from wave-uniform addresses -> SGPRs.
// ---------------------------------------------------------------------------
__device__ __forceinline__ float score_edge(
    int c, float cw, int b, int h,
    const float* __restrict__ qrow, const float* __restrict__ Kb,
    const float* __restrict__ w10p, const float* __restrict__ w11p,
    const float* __restrict__ b1p, const float* __restrict__ w2p, float b2h)
{
    const float* kp = Kb + ((size_t)b * CC + c) * EE + h * DD;
    float d0 = 0.f, d1 = 0.f, d2 = 0.f, d3 = 0.f;
#pragma unroll
    for (int dq = 0; dq < 8; ++dq) {
        const float4 kv = *(const float4*)(kp + dq * 4);
        d0 = fmaf(qrow[dq * 4 + 0], kv.x, d0);
        d1 = fmaf(qrow[dq * 4 + 1], kv.y, d1);
        d2 = fmaf(qrow[dq * 4 + 2], kv.z, d2);
        d3 = fmaf(qrow[dq * 4 + 3], kv.w, d3);
    }
    const float dot = ((d0 + d1) + (d2 + d3)) * 0.17677669529663687f;
    float l0 = b2h, l1 = 0.f;
#pragma unroll
    for (int mm = 0; mm < 16; mm += 2) {
        const float h0 = fmaf(dot, w10p[mm],     fmaf(cw, w11p[mm],     b1p[mm]));
        const float h1 = fmaf(dot, w10p[mm + 1], fmaf(cw, w11p[mm + 1], b1p[mm + 1]));
        l0 = fmaf(fmaxf(h0, 0.f), w2p[mm],     l0);
        l1 = fmaf(fmaxf(h1, 0.f), w2p[mm + 1], l1);
    }
    // s = tanh(l)*10; p = exp(s-10) = exp(-20/(e^{2l}+1)); bounded (no ovf).
    const float ex = __expf(2.f * (l0 + l1));
    return __expf(-20.f / (ex + 1.f));
}

// ---------------------------------------------------------------------------
// Semi-sparse attention: R10 champion structure; ONLY change vs R15 is
// `#pragma unroll 4` on the PV loop (no semantic change) to get ~16 V-loads
// in flight instead of ~4 across the serial eo iterations.
// Fixed-max-10 softmax (scores tanh*10 in (-10,10), beta<=10):
//   out = (sum_E (p_e - e^{b-10}) V_e + e^{b-10} Vsum) / (sum p + (C-nE) e^{b-10})
// Grid (8, RR, 2): blockIdx.x = (b,hh) -> XCD pin (R6: FETCH -55%).
// ---------------------------------------------------------------------------
__global__ __launch_bounds__(64) void attn_kernel(
    const float* __restrict__ Qb, const float* __restrict__ Kb,
    const float* __restrict__ Vb,
    const int* __restrict__ ecb, const float* __restrict__ ecwb,
    const int* __restrict__ nEb,
    const float* __restrict__ W1, const float* __restrict__ b1,
    const float* __restrict__ W2, const float* __restrict__ b2,
    const float* __restrict__ beta,
    const float* __restrict__ Vsum,
    ushort* __restrict__ Hbh, ushort* __restrict__ Hbl)
{
    const int combo = blockIdx.x;            // 0..7 -> XCD
    const int b = combo >> 1, hh = combo & 1;
    const int r = blockIdx.y;
    const int h0 = hh * 8 + blockIdx.z * 4;  // this wave: heads h0..h0+3
    const int lane = threadIdx.x;
    const int rowIdx = b * RR + r;

    const int nE = nEb[rowIdx];              // wave-uniform
    const float b2A = b2[h0], b2B = b2[h0 + 1], b2C = b2[h0 + 2], b2D = b2[h0 + 3];
    const float ebA = __expf(beta[h0]     - 10.f);
    const float ebB = __expf(beta[h0 + 1] - 10.f);
    const float ebC = __expf(beta[h0 + 2] - 10.f);
    const float ebD = __expf(beta[h0 + 3] - 10.f);

    const float* qA = Qb + (size_t)rowIdx * EE + h0 * DD;    // uniform -> SGPR
    const float* qB = qA + DD;
    const float* qC = qA + 2 * DD;
    const float* qD = qA + 3 * DD;
    const float* w10A = W1 + h0 * 32;
    const float* w11A = w10A + 16;
    const float* b1A  = b1 + h0 * 16;
    const float* w2A  = W2 + h0 * 16;

    // ---- scoring: lane e = edge e, 4 heads (independent chains) ----
    int c0 = 0, c1 = 0;
    float pA0 = 0.f, pB0 = 0.f, pC0 = 0.f, pD0 = 0.f;
    float pA1 = 0.f, pB1 = 0.f, pC1 = 0.f, pD1 = 0.f;
    if (lane < nE) {
        c0 = ecb[rowIdx * MAXE + lane];
        const float cw = ecwb[rowIdx * MAXE + lane];
        pA0 = score_edge(c0, cw, b, h0,     qA, Kb, w10A,      w11A,      b1A,      w2A,      b2A);
        pB0 = score_edge(c0, cw, b, h0 + 1, qB, Kb, w10A + 32, w11A + 32, b1A + 16, w2A + 16, b2B);
        pC0 = score_edge(c0, cw, b, h0 + 2, qC, Kb, w10A + 64, w11A + 64, b1A + 32, w2A + 32, b2C);
        pD0 = score_edge(c0, cw, b, h0 + 3, qD, Kb, w10A + 96, w11A + 96, b1A + 48, w2A + 48, b2D);
    }
    if (nE > 64) {                           // wave-uniform rare branch
        const int e1 = lane + 64;
        if (e1 < nE) {
            c1 = ecb[rowIdx * MAXE + e1];
            const float cw = ecwb[rowIdx * MAXE + e1];
            pA1 = score_edge(c1, cw, b, h0,     qA, Kb, w10A,      w11A,      b1A,      w2A,      b2A);
            pB1 = score_edge(c1, cw, b, h0 + 1, qB, Kb, w10A + 32, w11A + 32, b1A + 16, w2A + 16, b2B);
            pC1 = score_edge(c1, cw, b, h0 + 2, qC, Kb, w10A + 64, w11A + 64, b1A + 32, w2A + 32, b2C);
            pD1 = score_edge(c1, cw, b, h0 + 3, qD, Kb, w10A + 96, w11A + 96, b1A + 48, w2A + 48, b2D);
        }
    }

    // ---- Z: full-wave reduce, 4 heads ----
    float ZA = pA0 + pA1, ZB = pB0 + pB1, ZC = pC0 + pC1, ZD = pD0 + pD1;
#pragma unroll
    for (int off = 1; off < 64; off <<= 1) {
        ZA += __shfl_xor(ZA, off);
        ZB += __shfl_xor(ZB, off);
        ZC += __shfl_xor(ZC, off);
        ZD += __shfl_xor(ZD, off);
    }

    // ---- PV: 2 edges/iter, 4 heads; unroll 4 -> ~16 loads in flight ----
    const int half = lane >> 5, d = lane & 31;
    const float wA0 = pA0 - ebA, wB0 = pB0 - ebB, wC0 = pC0 - ebC, wD0 = pD0 - ebD;
    float accA = 0.f, accB = 0.f, accC = 0.f, accD = 0.f;
    const int lim0 = (nE < 64) ? nE : 64;
#pragma unroll 4
    for (int eo = 0; eo < lim0; eo += 2) {
        const int e = eo + half;
        const float wa = __shfl(wA0, e & 63);
        const float wb = __shfl(wB0, e & 63);
        const float wc = __shfl(wC0, e & 63);
        const float wd = __shfl(wD0, e & 63);
        const int   ce = __shfl(c0, e & 63);   // c0=0 on invalid lanes: safe
        const bool ok = e < lim0;
        const size_t vb0 = ((size_t)b * CC + ce) * EE + h0 * DD + d;
        const float vA = Vb[vb0];
        const float vB = Vb[vb0 + DD];
        const float vC = Vb[vb0 + 2 * DD];
        const float vD = Vb[vb0 + 3 * DD];
        accA = fmaf(ok ? wa : 0.f, vA, accA);
        accB = fmaf(ok ? wb : 0.f, vB, accB);
        accC = fmaf(ok ? wc : 0.f, vC, accC);
        accD = fmaf(ok ? wd : 0.f, vD, accD);
    }
    if (nE > 64) {
        const float wA1 = pA1 - ebA, wB1 = pB1 - ebB, wC1 = pC1 - ebC, wD1 = pD1 - ebD;
        for (int eo = 64; eo < nE; eo += 2) {
            const int e = eo + half;
            const float wa = __shfl(wA1, (e - 64) & 63);
            const float wb = __shfl(wB1, (e - 64) & 63);
            const float wc = __shfl(wC1, (e - 64) & 63);
            const float wd = __shfl(wD1, (e - 64) & 63);
            const int   ce = __shfl(c1, (e - 64) & 63);
            const bool ok = e < nE;
            const size_t vb0 = ((size_t)b * CC + ce) * EE + h0 * DD + d;
            const float vA = Vb[vb0];
            const float vB = Vb[vb0 + DD];
            const float vC = Vb[vb0 + 2 * DD];
            const float vD = Vb[vb0 + 3 * DD];
            accA = fmaf(ok ? wa : 0.f, vA, accA);
            accB = fmaf(ok ? wb : 0.f, vB, accB);
            accC = fmaf(ok ? wc : 0.f, vC, accC);
            accD = fmaf(ok ? wd : 0.f, vD, accD);
        }
    }
    accA += __shfl_xor(accA, 32);
    accB += __shfl_xor(accB, 32);
    accC += __shfl_xor(accC, 32);
    accD += __shfl_xor(accD, 32);

    // ---- epilogue: background via Vsum, write packed hi/lo bf16 ----
    if (lane < 32) {
        const float bgZ = (float)(CC - nE);
        const float invA = 1.f / (ZA + bgZ * ebA);
        const float invB = 1.f / (ZB + bgZ * ebB);
        const float invC = 1.f / (ZC + bgZ * ebC);
        const float invD = 1.f / (ZD + bgZ * ebD);
        const float* vsp = Vsum + (b * HH + h0) * DD + d;
        const float oA = (accA + ebA * vsp[0])      * invA;
        const float oB = (accB + ebB * vsp[DD])     * invB;
        const float oC = (accC + ebC * vsp[2 * DD]) * invC;
        const float oD = (accD + ebD * vsp[3 * DD]) * invD;
        const int rm = rowIdx;
        const int base_in = (d >> 3) * 128 + (rm & 15) * 8 + (d & 7);
        ushort oh, ol;
        split1(oA, oh, ol);
        int dst = ((rm >> 4) * 16 + h0) * 512 + base_in;
        Hbh[dst] = oh; Hbl[dst] = ol;
        split1(oB, oh, ol);
        dst = ((rm >> 4) * 16 + h0 + 1) * 512 + base_in;
        Hbh[dst] = oh; Hbl[dst] = ol;
        split1(oC, oh, ol);
        dst = ((rm >> 4) * 16 + h0 + 2) * 512 + base_in;
        Hbh[dst] = oh; Hbl[dst] = ol;
        split1(oD, oh, ol);
        dst = ((rm >> 4) * 16 + h0 + 3) * 512 + base_in;
        Hbh[dst] = oh; Hbl[dst] = ol;
    }
}

// ---------------------------------------------------------------------------
extern "C" void kernel_launch(void* const* d_in, const int* in_sizes, int n_in,
                              void* d_out, int out_size, void* d_ws, size_t ws_size,
                              hipStream_t stream)
{
    const float* rowe = (const float*)d_in[0];
    const float* cole = (const float*)d_in[1];
    const float* cost = (const float*)d_in[2];
    const float* Wq   = (const float*)d_in[3];
    const float* bq   = (const float*)d_in[4];
    const float* Wk   = (const float*)d_in[5];
    const float* bk   = (const float*)d_in[6];
    const float* Wv   = (const float*)d_in[7];
    const float* bv   = (const float*)d_in[8];
    const float* Wo   = (const float*)d_in[9];
    const float* bo   = (const float*)d_in[10];
    const float* W1   = (const float*)d_in[11];
    const float* b1   = (const float*)d_in[12];
    const float* W2   = (const float*)d_in[13];
    const float* b2   = (const float*)d_in[14];
    const float* beta = (const float*)d_in[15];
    float* out = (float*)d_out;

    // ---- workspace carve ----
    char* cur = (char*)d_ws;
    float* Qb   = (float*)cur; cur += (size_t)MROWS * EE * 4;
    float* Kb   = (float*)cur; cur += (size_t)MROWS * EE * 4;
    float* Vb   = (float*)cur; cur += (size_t)MROWS * EE * 4;
    float* Vsum = (float*)cur; cur += (size_t)BB * HH * DD * 4;
    ushort* reh = (ushort*)cur; cur += (size_t)MROWS * EE * 2;
    ushort* rel = (ushort*)cur; cur += (size_t)MROWS * EE * 2;
    ushort* ceh = (ushort*)cur; cur += (size_t)MROWS * EE * 2;
    ushort* cel = (ushort*)cur; cur += (size_t)MROWS * EE * 2;
    ushort* wqh = (ushort*)cur; cur += (size_t)EE * EE * 2;
    ushort* wql = (ushort*)cur; cur += (size_t)EE * EE * 2;
    ushort* wkh = (ushort*)cur; cur += (size_t)EE * EE * 2;
    ushort* wkl = (ushort*)cur; cur += (size_t)EE * EE * 2;
    ushort* wvh = (ushort*)cur; cur += (size_t)EE * EE * 2;
    ushort* wvl = (ushort*)cur; cur += (size_t)EE * EE * 2;
    ushort* woh = (ushort*)cur; cur += (size_t)EE * EE * 2;
    ushort* wol = (ushort*)cur; cur += (size_t)EE * EE * 2;
    ushort* hbh = (ushort*)cur; cur += (size_t)MROWS * EE * 2;
    ushort* hbl = (ushort*)cur; cur += (size_t)MROWS * EE * 2;
    int*    ecb = (int*)cur;   cur += (size_t)MROWS * MAXE * 4;
    float* ecwb = (float*)cur; cur += (size_t)MROWS * MAXE * 4;
    int*    nEb = (int*)cur;   cur += (size_t)MROWS * 4;

    split_kernel<<<dim3(768, 7), 256, 0, stream>>>(
        rowe, cole, Wq, Wk, Wv, Wo, cost,
        reh, rel, ceh, cel, wqh, wql, wkh, wkl, wvh, wvl, woh, wol,
        ecb, ecwb, nEb);

    dim3 g1(16, 24, 3);
    qkv_kernel<<<g1, 256, 0, stream>>>(reh, rel, ceh, cel,
                                       wqh, wql, wkh, wkl, wvh, wvl,
                                       bq, bk, bv, Qb, Kb, Vb);

    dim3 gv(16, 4);
    vsum_kernel<<<gv, 256, 0, stream>>>(Vb, Vsum);

    dim3 g2(8, RR, 2);   // x = (b,hh) -> XCD pin; y = row; z = head-quad
    attn_kernel<<<g2, 64, 0, stream>>>(Qb, Kb, Vb, ecb, ecwb, nEb,
                                       W1, b1, W2, b2, beta, Vsum, hbh, hbl);

    dim3 g3(16, 24, 1);
    oproj_kernel<<<g3, 256, 0, stream>>>(hbh, hbl, woh, wol, bo, out);
}

// Round 17
// 85.439 us; speedup vs baseline: 1.2704x; 1.0005x over previous
//
#include <hip/hip_runtime.h>

// Problem constants
#define BB 4
#define RR 384
#define CC 384
#define EE 512
#define HH 16
#define DD 32
#define MROWS 1536   // B*R = B*C
#define MAXE 128     // edge-list stride (nE ~ 38 +- 6; 128 = 15 sigma)

typedef __attribute__((ext_vector_type(8))) short bf16x8;   // 8 bf16 = 4 VGPRs
typedef __attribute__((ext_vector_type(4))) float f32x4;

// ---------------------------------------------------------------------------
// f32 -> (hi, lo) bf16 split, RNE both times. x ~= hi + lo with ~2^-16 rel err.
// ---------------------------------------------------------------------------
__device__ __forceinline__ void split1(float x, ushort& h, ushort& l)
{
    const unsigned u = __float_as_uint(x);
    const unsigned r = (u + 0x7fffu + ((u >> 16) & 1u)) >> 16;
    h = (ushort)r;
    const float hf = __uint_as_float(r << 16);
    const float lo = x - hf;
    const unsigned u2 = __float_as_uint(lo);
    l = (ushort)((u2 + 0x7fffu + ((u2 >> 16) & 1u)) >> 16);
}

// Packed fragment address for element (r, k) of a [rows][512] matrix:
// lane l of the wave covering (r-tile, k-tile) reads elems [l*8, l*8+8).
__device__ __forceinline__ int packed_addr(int r, int k)
{
    return ((r >> 4) * 16 + (k >> 5)) * 512 + ((k >> 3) & 3) * 128 + (r & 15) * 8 + (k & 7);
}

// ---------------------------------------------------------------------------
// Split kernel: 6 arrays -> hi/lo bf16 planes in PACKED fragment layout.
// blockIdx.y == 6: fused edge-compaction (4 rows/block, 1 per wave) [R15-proven].
// ---------------------------------------------------------------------------
__global__ __launch_bounds__(256) void split_kernel(
    const float* __restrict__ rowe, const float* __restrict__ cole,
    const float* __restrict__ Wq, const float* __restrict__ Wk,
    const float* __restrict__ Wv, const float* __restrict__ Wo,
    const float* __restrict__ cost,
    ushort* __restrict__ reh, ushort* __restrict__ rel,
    ushort* __restrict__ ceh, ushort* __restrict__ cel,
    ushort* __restrict__ wqh, ushort* __restrict__ wql,
    ushort* __restrict__ wkh, ushort* __restrict__ wkl,
    ushort* __restrict__ wvh, ushort* __restrict__ wvl,
    ushort* __restrict__ woh, ushort* __restrict__ wol,
    int* __restrict__ ecb, float* __restrict__ ecwb, int* __restrict__ nEb)
{
    if (blockIdx.y == 6) {
        if (blockIdx.x >= MROWS / 4) return;
        const int rowIdx = blockIdx.x * 4 + (threadIdx.x >> 6);
        const int lane = threadIdx.x & 63;
        const float* crow = cost + (size_t)rowIdx * CC;
        const unsigned long long prefix = (1ull << lane) - 1ull;
        int nE = 0;
#pragma unroll
        for (int j = 0; j < 6; ++j) {
            const float cw = crow[lane + 64 * j];
            const unsigned long long mk = __ballot(cw > 0.f);
            if (cw > 0.f) {
                const int slot = nE + __popcll(mk & prefix);
                if (slot < MAXE) {
                    ecb [rowIdx * MAXE + slot] = lane + 64 * j;
                    ecwb[rowIdx * MAXE + slot] = cw;
                }
            }
            nE += __popcll(mk);
        }
        if (lane == 0) nEb[rowIdx] = (nE < MAXE) ? nE : MAXE;
        return;
    }

    const float* src; ushort* dh; ushort* dl; int n;
    switch (blockIdx.y) {
    case 0: src = rowe; dh = reh; dl = rel; n = MROWS * EE; break;
    case 1: src = cole; dh = ceh; dl = cel; n = MROWS * EE; break;
    case 2: src = Wq;   dh = wqh; dl = wql; n = EE * EE;    break;
    case 3: src = Wk;   dh = wkh; dl = wkl; n = EE * EE;    break;
    case 4: src = Wv;   dh = wvh; dl = wvl; n = EE * EE;    break;
    default: src = Wo;  dh = woh; dl = wol; n = EE * EE;    break;
    }
    const int i4 = blockIdx.x * 256 + threadIdx.x;
    if (i4 * 4 >= n) return;
    const float4 v = ((const float4*)src)[i4];
    ushort4 hs, ls;
    split1(v.x, hs.x, ls.x);
    split1(v.y, hs.y, ls.y);
    split1(v.z, hs.z, ls.z);
    split1(v.w, hs.w, ls.w);
    const int e0 = i4 * 4;
    const int dst = packed_addr(e0 >> 9, e0 & 511);   // (k&7) in {0,4}: aligned
    *(ushort4*)(dh + dst) = hs;
    *(ushort4*)(dl + dst) = ls;
}

// ---------------------------------------------------------------------------
// Fine-grained GEMM body: 2 n-tiles per wave (16x32), SPLIT ACCUMULATORS.
// R16's body issued 3 serial MFMAs per acc per K-step (C-in dependency chain
// of 48 MFMAs). Here each split term (hi*hi, hi*lo, lo*hi) gets its own
// accumulator: 6 independent 16-MFMA chains, summed in f32 at the end.
// VGPR +16 (~56 total), still under the 64-VGPR occupancy cliff.
// ---------------------------------------------------------------------------
__device__ __forceinline__ void gemm_bf16x3_body2(
    const ushort* __restrict__ Ahi, const ushort* __restrict__ Alo,
    const ushort* __restrict__ Whi, const ushort* __restrict__ Wlo,
    const float* __restrict__ bias, float* __restrict__ Y,
    int Mt, int Nt0)
{
    constexpr int N = 512;
    const int lane = threadIdx.x & 63;
    const int col = lane & 15, kgrp = lane >> 4;

    const ushort* pah = Ahi + (size_t)Mt * 8192 + lane * 8;
    const ushort* pal = Alo + (size_t)Mt * 8192 + lane * 8;
    const ushort* pbh = Whi + (size_t)Nt0 * 8192 + lane * 8;
    const ushort* pbl = Wlo + (size_t)Nt0 * 8192 + lane * 8;

    f32x4 a0hh = {}, a0hl = {}, a0lh = {};
    f32x4 a1hh = {}, a1hl = {}, a1lh = {};

#pragma unroll 4
    for (int kt = 0; kt < 16; ++kt) {
        const int ko = kt * 512;
        const bf16x8 ah  = *(const bf16x8*)(pah + ko);
        const bf16x8 al  = *(const bf16x8*)(pal + ko);
        const bf16x8 bh0 = *(const bf16x8*)(pbh + ko);
        const bf16x8 bh1 = *(const bf16x8*)(pbh + ko + 8192);
        const bf16x8 bl0 = *(const bf16x8*)(pbl + ko);
        const bf16x8 bl1 = *(const bf16x8*)(pbl + ko + 8192);
        a0hh = __builtin_amdgcn_mfma_f32_16x16x32_bf16(ah, bh0, a0hh, 0, 0, 0);
        a0hl = __builtin_amdgcn_mfma_f32_16x16x32_bf16(ah, bl0, a0hl, 0, 0, 0);
        a0lh = __builtin_amdgcn_mfma_f32_16x16x32_bf16(al, bh0, a0lh, 0, 0, 0);
        a1hh = __builtin_amdgcn_mfma_f32_16x16x32_bf16(ah, bh1, a1hh, 0, 0, 0);
        a1hl = __builtin_amdgcn_mfma_f32_16x16x32_bf16(ah, bl1, a1hl, 0, 0, 0);
        a1lh = __builtin_amdgcn_mfma_f32_16x16x32_bf16(al, bh1, a1lh, 0, 0, 0);
    }

    f32x4 accs[2];
#pragma unroll
    for (int j = 0; j < 4; ++j) {
        accs[0][j] = (a0hh[j] + a0hl[j]) + a0lh[j];
        accs[1][j] = (a1hh[j] + a1hl[j]) + a1lh[j];
    }
#pragma unroll
    for (int t = 0; t < 2; ++t) {
        const int n = (Nt0 + t) * 16 + col;
        const float bn = bias[n];
#pragma unroll
        for (int j = 0; j < 4; ++j) {
            const int m = Mt * 16 + kgrp * 4 + j;
            Y[m * N + n] = accs[t][j] + bn;
        }
    }
}

// qkv: grid (16, 24, 3), 256 thr (4 waves over m). Wave tile 16m x 32n.
__global__ __launch_bounds__(256) void qkv_kernel(
    const ushort* __restrict__ reh, const ushort* __restrict__ rel,
    const ushort* __restrict__ ceh, const ushort* __restrict__ cel,
    const ushort* __restrict__ wqh, const ushort* __restrict__ wql,
    const ushort* __restrict__ wkh, const ushort* __restrict__ wkl,
    const ushort* __restrict__ wvh, const ushort* __restrict__ wvl,
    const float* __restrict__ bq, const float* __restrict__ bk,
    const float* __restrict__ bv,
    float* __restrict__ Qo, float* __restrict__ Ko, float* __restrict__ Vo)
{
    const int l = blockIdx.x + (blockIdx.y << 4);
    const int a = l & 7;
    const int t = l >> 3;
    const int Bm = a * 3 + (t >> 4);
    const int Bx = t & 15;
    const int Mt = Bm * 4 + (threadIdx.x >> 6);
    const int Nt0 = Bx * 2;
    if (blockIdx.z == 0)      gemm_bf16x3_body2(reh, rel, wqh, wql, bq, Qo, Mt, Nt0);
    else if (blockIdx.z == 1) gemm_bf16x3_body2(ceh, cel, wkh, wkl, bk, Ko, Mt, Nt0);
    else                      gemm_bf16x3_body2(ceh, cel, wvh, wvl, bv, Vo, Mt, Nt0);
}

// oproj: grid (16, 24, 1), fine-grained body2.
__global__ __launch_bounds__(256) void oproj_kernel(
    const ushort* __restrict__ hbh, const ushort* __restrict__ hbl,
    const ushort* __restrict__ woh, const ushort* __restrict__ wol,
    const float* __restrict__ bo, float* __restrict__ out)
{
    const int l = blockIdx.x + (blockIdx.y << 4);
    const int a = l & 7;
    const int t = l >> 3;
    const int Bm = a * 3 + (t >> 4);
    const int Bx = t & 15;
    const int Mt = Bm * 4 + (threadIdx.x >> 6);
    const int Nt0 = Bx * 2;
    gemm_bf16x3_body2(hbh, hbl, woh, wol, bo, out, Mt, Nt0);
}

// ---------------------------------------------------------------------------
// Vsum kernel: Vsum[b][h][d] = sum_c V[b][c][h*32+d]. Grid (16,4), 256 thr.
// ---------------------------------------------------------------------------
__global__ __launch_bounds__(256) void vsum_kernel(const float* __restrict__ Vb,
                                                   float* __restrict__ Vsum)
{
    __shared__ float part[8][32];
    const int h = blockIdx.x, b = blockIdx.y;
    const int d = threadIdx.x & 31, g = threadIdx.x >> 5;
    float acc = 0.f;
    for (int c = g; c < CC; c += 8)
        acc += Vb[(b * CC + c) * EE + h * DD + d];
    part[g][d] = acc;
    __syncthreads();
    if (g == 0) {
        float s = 0.f;
#pragma unroll
        for (int gg = 0; gg < 8; ++gg) s += part[gg][d];
        Vsum[(b * HH + h) * DD + d] = s;
    }
}

// ---------------------------------------------------------------------------
// Edge scorer: dot(q,k) -> per-head 2x16x1 MLP -> p = exp(tanh*10 - 10).
// All q / MLP params come from wave-uniform addresses -> SGPRs.
// ---------------------------------------------------------------------------
__device__ __forceinline__ float score_edge(
    int c, float cw, int b, int h,
    const float* __restrict__ qrow, const float* __restrict__ Kb,
    const float* __restrict__ w10p, const float* __restrict__ w11p,
    const float* __restrict__ b1p, const float* __restrict__ w2p, float b2h)
{
    const float* kp = Kb + ((size_t)b * CC + c) * EE + h * DD;
    float d0 = 0.f, d1 = 0.f, d2 = 0.f, d3 = 0.f;
#pragma unroll
    for (int dq = 0; dq < 8; ++dq) {
        const float4 kv = *(const float4*)(kp + dq * 4);
        d0 = fmaf(qrow[dq * 4 + 0], kv.x, d0);
        d1 = fmaf(qrow[dq * 4 + 1], kv.y, d1);
        d2 = fmaf(qrow[dq * 4 + 2], kv.z, d2);
        d3 = fmaf(qrow[dq * 4 + 3], kv.w, d3);
    }
    const float dot = ((d0 + d1) + (d2 + d3)) * 0.17677669529663687f;
    float l0 = b2h, l1 = 0.f;
#pragma unroll
    for (int mm = 0; mm < 16; mm += 2) {
        const float h0 = fmaf(dot, w10p[mm],     fmaf(cw, w11p[mm],     b1p[mm]));
        const float h1 = fmaf(dot, w10p[mm + 1], fmaf(cw, w11p[mm + 1], b1p[mm + 1]));
        l0 = fmaf(fmaxf(h0, 0.f), w2p[mm],     l0);
        l1 = fmaf(fmaxf(h1, 0.f), w2p[mm + 1], l1);
    }
    // s = tanh(l)*10; p = exp(s-10) = exp(-20/(e^{2l}+1)); bounded (no ovf).
    const float ex = __expf(2.f * (l0 + l1));
    return __expf(-20.f / (ex + 1.f));
}

// ---------------------------------------------------------------------------
// Semi-sparse attention: R16 champion, UNCHANGED. ONE WAVE per (b,r,head-quad),
// PV loop unroll 4. Fixed-max-10 softmax:
//   out = (sum_E (p_e - e^{b-10}) V_e + e^{b-10} Vsum) / (sum p + (C-nE) e^{b-10})
// Grid (8, RR, 2): blockIdx.x = (b,hh) -> XCD pin (R6: FETCH -55%).
// ---------------------------------------------------------------------------
__global__ __launch_bounds__(64) void attn_kernel(
    const float* __restrict__ Qb, const float* __restrict__ Kb,
    const float* __restrict__ Vb,
    const int* __restrict__ ecb, const float* __restrict__ ecwb,
    const int* __restrict__ nEb,
    const float* __restrict__ W1, const float* __restrict__ b1,
    const float* __restrict__ W2, const float* __restrict__ b2,
    const float* __restrict__ beta,
    const float* __restrict__ Vsum,
    ushort* __restrict__ Hbh, ushort* __restrict__ Hbl)
{
    const int combo = blockIdx.x;            // 0..7 -> XCD
    const int b = combo >> 1, hh = combo & 1;
    const int r = blockIdx.y;
    const int h0 = hh * 8 + blockIdx.z * 4;  // this wave: heads h0..h0+3
    const int lane = threadIdx.x;
    const int rowIdx = b * RR + r;

    const int nE = nEb[rowIdx];              // wave-uniform
    const float b2A = b2[h0], b2B = b2[h0 + 1], b2C = b2[h0 + 2], b2D = b2[h0 + 3];
    const float ebA = __expf(beta[h0]     - 10.f);
    const float ebB = __expf(beta[h0 + 1] - 10.f);
    const float ebC = __expf(beta[h0 + 2] - 10.f);
    const float ebD = __expf(beta[h0 + 3] - 10.f);

    const float* qA = Qb + (size_t)rowIdx * EE + h0 * DD;    // uniform -> SGPR
    const float* qB = qA + DD;
    const float* qC = qA + 2 * DD;
    const float* qD = qA + 3 * DD;
    const float* w10A = W1 + h0 * 32;
    const float* w11A = w10A + 16;
    const float* b1A  = b1 + h0 * 16;
    const float* w2A  = W2 + h0 * 16;

    // ---- scoring: lane e = edge e, 4 heads (independent chains) ----
    int c0 = 0, c1 = 0;
    float pA0 = 0.f, pB0 = 0.f, pC0 = 0.f, pD0 = 0.f;
    float pA1 = 0.f, pB1 = 0.f, pC1 = 0.f, pD1 = 0.f;
    if (lane < nE) {
        c0 = ecb[rowIdx * MAXE + lane];
        const float cw = ecwb[rowIdx * MAXE + lane];
        pA0 = score_edge(c0, cw, b, h0,     qA, Kb, w10A,      w11A,      b1A,      w2A,      b2A);
        pB0 = score_edge(c0, cw, b, h0 + 1, qB, Kb, w10A + 32, w11A + 32, b1A + 16, w2A + 16, b2B);
        pC0 = score_edge(c0, cw, b, h0 + 2, qC, Kb, w10A + 64, w11A + 64, b1A + 32, w2A + 32, b2C);
        pD0 = score_edge(c0, cw, b, h0 + 3, qD, Kb, w10A + 96, w11A + 96, b1A + 48, w2A + 48, b2D);
    }
    if (nE > 64) {                           // wave-uniform rare branch
        const int e1 = lane + 64;
        if (e1 < nE) {
            c1 = ecb[rowIdx * MAXE + e1];
            const float cw = ecwb[rowIdx * MAXE + e1];
            pA1 = score_edge(c1, cw, b, h0,     qA, Kb, w10A,      w11A,      b1A,      w2A,      b2A);
            pB1 = score_edge(c1, cw, b, h0 + 1, qB, Kb, w10A + 32, w11A + 32, b1A + 16, w2A + 16, b2B);
            pC1 = score_edge(c1, cw, b, h0 + 2, qC, Kb, w10A + 64, w11A + 64, b1A + 32, w2A + 32, b2C);
            pD1 = score_edge(c1, cw, b, h0 + 3, qD, Kb, w10A + 96, w11A + 96, b1A + 48, w2A + 48, b2D);
        }
    }

    // ---- Z: full-wave reduce, 4 heads ----
    float ZA = pA0 + pA1, ZB = pB0 + pB1, ZC = pC0 + pC1, ZD = pD0 + pD1;
#pragma unroll
    for (int off = 1; off < 64; off <<= 1) {
        ZA += __shfl_xor(ZA, off);
        ZB += __shfl_xor(ZB, off);
        ZC += __shfl_xor(ZC, off);
        ZD += __shfl_xor(ZD, off);
    }

    // ---- PV: 2 edges/iter, 4 heads; unroll 4 -> ~16 loads in flight ----
    const int half = lane >> 5, d = lane & 31;
    const float wA0 = pA0 - ebA, wB0 = pB0 - ebB, wC0 = pC0 - ebC, wD0 = pD0 - ebD;
    float accA = 0.f, accB = 0.f, accC = 0.f, accD = 0.f;
    const int lim0 = (nE < 64) ? nE : 64;
#pragma unroll 4
    for (int eo = 0; eo < lim0; eo += 2) {
        const int e = eo + half;
        const float wa = __shfl(wA0, e & 63);
        const float wb = __shfl(wB0, e & 63);
        const float wc = __shfl(wC0, e & 63);
        const float wd = __shfl(wD0, e & 63);
        const int   ce = __shfl(c0, e & 63);   // c0=0 on invalid lanes: safe
        const bool ok = e < lim0;
        const size_t vb0 = ((size_t)b * CC + ce) * EE + h0 * DD + d;
        const float vA = Vb[vb0];
        const float vB = Vb[vb0 + DD];
        const float vC = Vb[vb0 + 2 * DD];
        const float vD = Vb[vb0 + 3 * DD];
        accA = fmaf(ok ? wa : 0.f, vA, accA);
        accB = fmaf(ok ? wb : 0.f, vB, accB);
        accC = fmaf(ok ? wc : 0.f, vC, accC);
        accD = fmaf(ok ? wd : 0.f, vD, accD);
    }
    if (nE > 64) {
        const float wA1 = pA1 - ebA, wB1 = pB1 - ebB, wC1 = pC1 - ebC, wD1 = pD1 - ebD;
        for (int eo = 64; eo < nE; eo += 2) {
            const int e = eo + half;
            const float wa = __shfl(wA1, (e - 64) & 63);
            const float wb = __shfl(wB1, (e - 64) & 63);
            const float wc = __shfl(wC1, (e - 64) & 63);
            const float wd = __shfl(wD1, (e - 64) & 63);
            const int   ce = __shfl(c1, (e - 64) & 63);
            const bool ok = e < nE;
            const size_t vb0 = ((size_t)b * CC + ce) * EE + h0 * DD + d;
            const float vA = Vb[vb0];
            const float vB = Vb[vb0 + DD];
            const float vC = Vb[vb0 + 2 * DD];
            const float vD = Vb[vb0 + 3 * DD];
            accA = fmaf(ok ? wa : 0.f, vA, accA);
            accB = fmaf(ok ? wb : 0.f, vB, accB);
            accC = fmaf(ok ? wc : 0.f, vC, accC);
            accD = fmaf(ok ? wd : 0.f, vD, accD);
        }
    }
    accA += __shfl_xor(accA, 32);
    accB += __shfl_xor(accB, 32);
    accC += __shfl_xor(accC, 32);
    accD += __shfl_xor(accD, 32);

    // ---- epilogue: background via Vsum, write packed hi/lo bf16 ----
    if (lane < 32) {
        const float bgZ = (float)(CC - nE);
        const float invA = 1.f / (ZA + bgZ * ebA);
        const float invB = 1.f / (ZB + bgZ * ebB);
        const float invC = 1.f / (ZC + bgZ * ebC);
        const float invD = 1.f / (ZD + bgZ * ebD);
        const float* vsp = Vsum + (b * HH + h0) * DD + d;
        const float oA = (accA + ebA * vsp[0])      * invA;
        const float oB = (accB + ebB * vsp[DD])     * invB;
        const float oC = (accC + ebC * vsp[2 * DD]) * invC;
        const float oD = (accD + ebD * vsp[3 * DD]) * invD;
        const int rm = rowIdx;
        const int base_in = (d >> 3) * 128 + (rm & 15) * 8 + (d & 7);
        ushort oh, ol;
        split1(oA, oh, ol);
        int dst = ((rm >> 4) * 16 + h0) * 512 + base_in;
        Hbh[dst] = oh; Hbl[dst] = ol;
        split1(oB, oh, ol);
        dst = ((rm >> 4) * 16 + h0 + 1) * 512 + base_in;
        Hbh[dst] = oh; Hbl[dst] = ol;
        split1(oC, oh, ol);
        dst = ((rm >> 4) * 16 + h0 + 2) * 512 + base_in;
        Hbh[dst] = oh; Hbl[dst] = ol;
        split1(oD, oh, ol);
        dst = ((rm >> 4) * 16 + h0 + 3) * 512 + base_in;
        Hbh[dst] = oh; Hbl[dst] = ol;
    }
}

// ---------------------------------------------------------------------------
extern "C" void kernel_launch(void* const* d_in, const int* in_sizes, int n_in,
                              void* d_out, int out_size, void* d_ws, size_t ws_size,
                              hipStream_t stream)
{
    const float* rowe = (const float*)d_in[0];
    const float* cole = (const float*)d_in[1];
    const float* cost = (const float*)d_in[2];
    const float* Wq   = (const float*)d_in[3];
    const float* bq   = (const float*)d_in[4];
    const float* Wk   = (const float*)d_in[5];
    const float* bk   = (const float*)d_in[6];
    const float* Wv   = (const float*)d_in[7];
    const float* bv   = (const float*)d_in[8];
    const float* Wo   = (const float*)d_in[9];
    const float* bo   = (const float*)d_in[10];
    const float* W1   = (const float*)d_in[11];
    const float* b1   = (const float*)d_in[12];
    const float* W2   = (const float*)d_in[13];
    const float* b2   = (const float*)d_in[14];
    const float* beta = (const float*)d_in[15];
    float* out = (float*)d_out;

    // ---- workspace carve ----
    char* cur = (char*)d_ws;
    float* Qb   = (float*)cur; cur += (size_t)MROWS * EE * 4;
    float* Kb   = (float*)cur; cur += (size_t)MROWS * EE * 4;
    float* Vb   = (float*)cur; cur += (size_t)MROWS * EE * 4;
    float* Vsum = (float*)cur; cur += (size_t)BB * HH * DD * 4;
    ushort* reh = (ushort*)cur; cur += (size_t)MROWS * EE * 2;
    ushort* rel = (ushort*)cur; cur += (size_t)MROWS * EE * 2;
    ushort* ceh = (ushort*)cur; cur += (size_t)MROWS * EE * 2;
    ushort* cel = (ushort*)cur; cur += (size_t)MROWS * EE * 2;
    ushort* wqh = (ushort*)cur; cur += (size_t)EE * EE * 2;
    ushort* wql = (ushort*)cur; cur += (size_t)EE * EE * 2;
    ushort* wkh = (ushort*)cur; cur += (size_t)EE * EE * 2;
    ushort* wkl = (ushort*)cur; cur += (size_t)EE * EE * 2;
    ushort* wvh = (ushort*)cur; cur += (size_t)EE * EE * 2;
    ushort* wvl = (ushort*)cur; cur += (size_t)EE * EE * 2;
    ushort* woh = (ushort*)cur; cur += (size_t)EE * EE * 2;
    ushort* wol = (ushort*)cur; cur += (size_t)EE * EE * 2;
    ushort* hbh = (ushort*)cur; cur += (size_t)MROWS * EE * 2;
    ushort* hbl = (ushort*)cur; cur += (size_t)MROWS * EE * 2;
    int*    ecb = (int*)cur;   cur += (size_t)MROWS * MAXE * 4;
    float* ecwb = (float*)cur; cur += (size_t)MROWS * MAXE * 4;
    int*    nEb = (int*)cur;   cur += (size_t)MROWS * 4;

    split_kernel<<<dim3(768, 7), 256, 0, stream>>>(
        rowe, cole, Wq, Wk, Wv, Wo, cost,
        reh, rel, ceh, cel, wqh, wql, wkh, wkl, wvh, wvl, woh, wol,
        ecb, ecwb, nEb);

    dim3 g1(16, 24, 3);
    qkv_kernel<<<g1, 256, 0, stream>>>(reh, rel, ceh, cel,
                                       wqh, wql, wkh, wkl, wvh, wvl,
                                       bq, bk, bv, Qb, Kb, Vb);

    dim3 gv(16, 4);
    vsum_kernel<<<gv, 256, 0, stream>>>(Vb, Vsum);

    dim3 g2(8, RR, 2);   // x = (b,hh) -> XCD pin; y = row; z = head-quad
    attn_kernel<<<g2, 64, 0, stream>>>(Qb, Kb, Vb, ecb, ecwb, nEb,
                                       W1, b1, W2, b2, beta, Vsum, hbh, hbl);

    dim3 g3(16, 24, 1);
    oproj_kernel<<<g3, 256, 0, stream>>>(hbh, hbl, woh, wol, bo, out);
}

// Round 18
// 83.421 us; speedup vs baseline: 1.3011x; 1.0242x over previous
//
#include <hip/hip_runtime.h>

// Problem constants
#define BB 4
#define RR 384
#define CC 384
#define EE 512
#define HH 16
#define DD 32
#define MROWS 1536   // B*R = B*C
#define MAXE 128     // edge-list stride (nE ~ 38 +- 6; 128 = 15 sigma)

typedef __attribute__((ext_vector_type(8))) short bf16x8;   // 8 bf16 = 4 VGPRs
typedef __attribute__((ext_vector_type(4))) float f32x4;

// ---------------------------------------------------------------------------
// f32 -> (hi, lo) bf16 split, RNE both times. x ~= hi + lo with ~2^-16 rel err.
// ---------------------------------------------------------------------------
__device__ __forceinline__ void split1(float x, ushort& h, ushort& l)
{
    const unsigned u = __float_as_uint(x);
    const unsigned r = (u + 0x7fffu + ((u >> 16) & 1u)) >> 16;
    h = (ushort)r;
    const float hf = __uint_as_float(r << 16);
    const float lo = x - hf;
    const unsigned u2 = __float_as_uint(lo);
    l = (ushort)((u2 + 0x7fffu + ((u2 >> 16) & 1u)) >> 16);
}

// Packed fragment address for element (r, k) of a [rows][512] matrix:
// lane l of the wave covering (r-tile, k-tile) reads elems [l*8, l*8+8).
__device__ __forceinline__ int packed_addr(int r, int k)
{
    return ((r >> 4) * 16 + (k >> 5)) * 512 + ((k >> 3) & 3) * 128 + (r & 15) * 8 + (k & 7);
}

// ---------------------------------------------------------------------------
// Split kernel: 6 arrays -> hi/lo bf16 planes in PACKED fragment layout.
// y == 6: fused edge-compaction [R15-proven].
// y == 7: colesum[b][e] = sum_c cole[b][c][e]  (8 blocks; feeds Vsum GEMV --
//         algebraic replacement for the 12MB Vb reduction).
// ---------------------------------------------------------------------------
__global__ __launch_bounds__(256) void split_kernel(
    const float* __restrict__ rowe, const float* __restrict__ cole,
    const float* __restrict__ Wq, const float* __restrict__ Wk,
    const float* __restrict__ Wv, const float* __restrict__ Wo,
    const float* __restrict__ cost,
    ushort* __restrict__ reh, ushort* __restrict__ rel,
    ushort* __restrict__ ceh, ushort* __restrict__ cel,
    ushort* __restrict__ wqh, ushort* __restrict__ wql,
    ushort* __restrict__ wkh, ushort* __restrict__ wkl,
    ushort* __restrict__ wvh, ushort* __restrict__ wvl,
    ushort* __restrict__ woh, ushort* __restrict__ wol,
    int* __restrict__ ecb, float* __restrict__ ecwb, int* __restrict__ nEb,
    float* __restrict__ colesum)
{
    if (blockIdx.y == 6) {
        if (blockIdx.x >= MROWS / 4) return;
        const int rowIdx = blockIdx.x * 4 + (threadIdx.x >> 6);
        const int lane = threadIdx.x & 63;
        const float* crow = cost + (size_t)rowIdx * CC;
        const unsigned long long prefix = (1ull << lane) - 1ull;
        int nE = 0;
#pragma unroll
        for (int j = 0; j < 6; ++j) {
            const float cw = crow[lane + 64 * j];
            const unsigned long long mk = __ballot(cw > 0.f);
            if (cw > 0.f) {
                const int slot = nE + __popcll(mk & prefix);
                if (slot < MAXE) {
                    ecb [rowIdx * MAXE + slot] = lane + 64 * j;
                    ecwb[rowIdx * MAXE + slot] = cw;
                }
            }
            nE += __popcll(mk);
        }
        if (lane == 0) nEb[rowIdx] = (nE < MAXE) ? nE : MAXE;
        return;
    }
    if (blockIdx.y == 7) {
        // colesum: 8 blocks, (b, e-half). Coalesced 1KB reads per c-step.
        if (blockIdx.x >= 8) return;
        const int b = blockIdx.x >> 1;
        const int e = (blockIdx.x & 1) * 256 + threadIdx.x;
        float s = 0.f;
        const float* cp = cole + (size_t)b * CC * EE + e;
        for (int c = 0; c < CC; ++c) s += cp[(size_t)c * EE];
        colesum[b * EE + e] = s;
        return;
    }

    const float* src; ushort* dh; ushort* dl; int n;
    switch (blockIdx.y) {
    case 0: src = rowe; dh = reh; dl = rel; n = MROWS * EE; break;
    case 1: src = cole; dh = ceh; dl = cel; n = MROWS * EE; break;
    case 2: src = Wq;   dh = wqh; dl = wql; n = EE * EE;    break;
    case 3: src = Wk;   dh = wkh; dl = wkl; n = EE * EE;    break;
    case 4: src = Wv;   dh = wvh; dl = wvl; n = EE * EE;    break;
    default: src = Wo;  dh = woh; dl = wol; n = EE * EE;    break;
    }
    const int i4 = blockIdx.x * 256 + threadIdx.x;
    if (i4 * 4 >= n) return;
    const float4 v = ((const float4*)src)[i4];
    ushort4 hs, ls;
    split1(v.x, hs.x, ls.x);
    split1(v.y, hs.y, ls.y);
    split1(v.z, hs.z, ls.z);
    split1(v.w, hs.w, ls.w);
    const int e0 = i4 * 4;
    const int dst = packed_addr(e0 >> 9, e0 & 511);   // (k&7) in {0,4}: aligned
    *(ushort4*)(dh + dst) = hs;
    *(ushort4*)(dl + dst) = ls;
}

// ---------------------------------------------------------------------------
// Vsum GEMV: Vsum[b][h][d] = dot(colesum[b], Wv[h*32+d]) + 384*bv[h*32+d].
// Exact-math identical to sum_c V[b][c][h*32+d]; reads 1 MB instead of 12 MB.
// Grid (16,4) = (h,b), 256 thr = 32 d x 8 partial-sums.
// ---------------------------------------------------------------------------
__global__ __launch_bounds__(256) void vsum_kernel(
    const float* __restrict__ colesum, const float* __restrict__ Wv,
    const float* __restrict__ bv, float* __restrict__ Vsum)
{
    __shared__ float part[256];
    const int h = blockIdx.x, b = blockIdx.y;
    const int d = threadIdx.x >> 3;      // 0..31
    const int pt = threadIdx.x & 7;      // 0..7
    const float* cs = colesum + b * EE + pt * 64;
    const float* wr = Wv + (size_t)(h * DD + d) * EE + pt * 64;
    float acc = 0.f;
#pragma unroll 8
    for (int k = 0; k < 64; ++k) acc = fmaf(cs[k], wr[k], acc);
    part[threadIdx.x] = acc;
    __syncthreads();
    if (pt == 0) {
        float s = 0.f;
#pragma unroll
        for (int q = 0; q < 8; ++q) s += part[d * 8 + q];
        Vsum[(b * HH + h) * DD + d] = s + 384.f * bv[h * DD + d];
    }
}

// ---------------------------------------------------------------------------
// Fine-grained GEMM body: 2 n-tiles per wave (16x32), split accumulators
// (6 independent MFMA chains) [R17].
// ---------------------------------------------------------------------------
__device__ __forceinline__ void gemm_bf16x3_body2(
    const ushort* __restrict__ Ahi, const ushort* __restrict__ Alo,
    const ushort* __restrict__ Whi, const ushort* __restrict__ Wlo,
    const float* __restrict__ bias, float* __restrict__ Y,
    int Mt, int Nt0)
{
    constexpr int N = 512;
    const int lane = threadIdx.x & 63;
    const int col = lane & 15, kgrp = lane >> 4;

    const ushort* pah = Ahi + (size_t)Mt * 8192 + lane * 8;
    const ushort* pal = Alo + (size_t)Mt * 8192 + lane * 8;
    const ushort* pbh = Whi + (size_t)Nt0 * 8192 + lane * 8;
    const ushort* pbl = Wlo + (size_t)Nt0 * 8192 + lane * 8;

    f32x4 a0hh = {}, a0hl = {}, a0lh = {};
    f32x4 a1hh = {}, a1hl = {}, a1lh = {};

#pragma unroll 4
    for (int kt = 0; kt < 16; ++kt) {
        const int ko = kt * 512;
        const bf16x8 ah  = *(const bf16x8*)(pah + ko);
        const bf16x8 al  = *(const bf16x8*)(pal + ko);
        const bf16x8 bh0 = *(const bf16x8*)(pbh + ko);
        const bf16x8 bh1 = *(const bf16x8*)(pbh + ko + 8192);
        const bf16x8 bl0 = *(const bf16x8*)(pbl + ko);
        const bf16x8 bl1 = *(const bf16x8*)(pbl + ko + 8192);
        a0hh = __builtin_amdgcn_mfma_f32_16x16x32_bf16(ah, bh0, a0hh, 0, 0, 0);
        a0hl = __builtin_amdgcn_mfma_f32_16x16x32_bf16(ah, bl0, a0hl, 0, 0, 0);
        a0lh = __builtin_amdgcn_mfma_f32_16x16x32_bf16(al, bh0, a0lh, 0, 0, 0);
        a1hh = __builtin_amdgcn_mfma_f32_16x16x32_bf16(ah, bh1, a1hh, 0, 0, 0);
        a1hl = __builtin_amdgcn_mfma_f32_16x16x32_bf16(ah, bl1, a1hl, 0, 0, 0);
        a1lh = __builtin_amdgcn_mfma_f32_16x16x32_bf16(al, bh1, a1lh, 0, 0, 0);
    }

    f32x4 accs[2];
#pragma unroll
    for (int j = 0; j < 4; ++j) {
        accs[0][j] = (a0hh[j] + a0hl[j]) + a0lh[j];
        accs[1][j] = (a1hh[j] + a1hl[j]) + a1lh[j];
    }
#pragma unroll
    for (int t = 0; t < 2; ++t) {
        const int n = (Nt0 + t) * 16 + col;
        const float bn = bias[n];
#pragma unroll
        for (int j = 0; j < 4; ++j) {
            const int m = Mt * 16 + kgrp * 4 + j;
            Y[m * N + n] = accs[t][j] + bn;
        }
    }
}

// qkv: grid (16, 24, 3), 256 thr (4 waves over m). Wave tile 16m x 32n.
__global__ __launch_bounds__(256) void qkv_kernel(
    const ushort* __restrict__ reh, const ushort* __restrict__ rel,
    const ushort* __restrict__ ceh, const ushort* __restrict__ cel,
    const ushort* __restrict__ wqh, const ushort* __restrict__ wql,
    const ushort* __restrict__ wkh, const ushort* __restrict__ wkl,
    const ushort* __restrict__ wvh, const ushort* __restrict__ wvl,
    const float* __restrict__ bq, const float* __restrict__ bk,
    const float* __restrict__ bv,
    float* __restrict__ Qo, float* __restrict__ Ko, float* __restrict__ Vo)
{
    const int l = blockIdx.x + (blockIdx.y << 4);
    const int a = l & 7;
    const int t = l >> 3;
    const int Bm = a * 3 + (t >> 4);
    const int Bx = t & 15;
    const int Mt = Bm * 4 + (threadIdx.x >> 6);
    const int Nt0 = Bx * 2;
    if (blockIdx.z == 0)      gemm_bf16x3_body2(reh, rel, wqh, wql, bq, Qo, Mt, Nt0);
    else if (blockIdx.z == 1) gemm_bf16x3_body2(ceh, cel, wkh, wkl, bk, Ko, Mt, Nt0);
    else                      gemm_bf16x3_body2(ceh, cel, wvh, wvl, bv, Vo, Mt, Nt0);
}

// oproj: grid (16, 24, 1), fine-grained body2.
__global__ __launch_bounds__(256) void oproj_kernel(
    const ushort* __restrict__ hbh, const ushort* __restrict__ hbl,
    const ushort* __restrict__ woh, const ushort* __restrict__ wol,
    const float* __restrict__ bo, float* __restrict__ out)
{
    const int l = blockIdx.x + (blockIdx.y << 4);
    const int a = l & 7;
    const int t = l >> 3;
    const int Bm = a * 3 + (t >> 4);
    const int Bx = t & 15;
    const int Mt = Bm * 4 + (threadIdx.x >> 6);
    const int Nt0 = Bx * 2;
    gemm_bf16x3_body2(hbh, hbl, woh, wol, bo, out, Mt, Nt0);
}

// ---------------------------------------------------------------------------
// Edge scorer: dot(q,k) -> per-head 2x16x1 MLP -> p = exp(tanh*10 - 10).
// All q / MLP params come from wave-uniform addresses -> SGPRs.
// ---------------------------------------------------------------------------
__device__ __forceinline__ float score_edge(
    int c, float cw, int b, int h,
    const float* __restrict__ qrow, const float* __restrict__ Kb,
    const float* __restrict__ w10p, const float* __restrict__ w11p,
    const float* __restrict__ b1p, const float* __restrict__ w2p, float b2h)
{
    const float* kp = Kb + ((size_t)b * CC + c) * EE + h * DD;
    float d0 = 0.f, d1 = 0.f, d2 = 0.f, d3 = 0.f;
#pragma unroll
    for (int dq = 0; dq < 8; ++dq) {
        const float4 kv = *(const float4*)(kp + dq * 4);
        d0 = fmaf(qrow[dq * 4 + 0], kv.x, d0);
        d1 = fmaf(qrow[dq * 4 + 1], kv.y, d1);
        d2 = fmaf(qrow[dq * 4 + 2], kv.z, d2);
        d3 = fmaf(qrow[dq * 4 + 3], kv.w, d3);
    }
    const float dot = ((d0 + d1) + (d2 + d3)) * 0.17677669529663687f;
    float l0 = b2h, l1 = 0.f;
#pragma unroll
    for (int mm = 0; mm < 16; mm += 2) {
        const float h0 = fmaf(dot, w10p[mm],     fmaf(cw, w11p[mm],     b1p[mm]));
        const float h1 = fmaf(dot, w10p[mm + 1], fmaf(cw, w11p[mm + 1], b1p[mm + 1]));
        l0 = fmaf(fmaxf(h0, 0.f), w2p[mm],     l0);
        l1 = fmaf(fmaxf(h1, 0.f), w2p[mm + 1], l1);
    }
    // s = tanh(l)*10; p = exp(s-10) = exp(-20/(e^{2l}+1)); bounded (no ovf).
    const float ex = __expf(2.f * (l0 + l1));
    return __expf(-20.f / (ex + 1.f));
}

// ---------------------------------------------------------------------------
// Semi-sparse attention: R16/R17 champion, UNCHANGED. ONE WAVE per
// (b,r,head-quad), PV loop unroll 4. Fixed-max-10 softmax:
//   out = (sum_E (p_e - e^{b-10}) V_e + e^{b-10} Vsum) / (sum p + (C-nE) e^{b-10})
// Grid (8, RR, 2): blockIdx.x = (b,hh) -> XCD pin (R6: FETCH -55%).
// ---------------------------------------------------------------------------
__global__ __launch_bounds__(64) void attn_kernel(
    const float* __restrict__ Qb, const float* __restrict__ Kb,
    const float* __restrict__ Vb,
    const int* __restrict__ ecb, const float* __restrict__ ecwb,
    const int* __restrict__ nEb,
    const float* __restrict__ W1, const float* __restrict__ b1,
    const float* __restrict__ W2, const float* __restrict__ b2,
    const float* __restrict__ beta,
    const float* __restrict__ Vsum,
    ushort* __restrict__ Hbh, ushort* __restrict__ Hbl)
{
    const int combo = blockIdx.x;            // 0..7 -> XCD
    const int b = combo >> 1, hh = combo & 1;
    const int r = blockIdx.y;
    const int h0 = hh * 8 + blockIdx.z * 4;  // this wave: heads h0..h0+3
    const int lane = threadIdx.x;
    const int rowIdx = b * RR + r;

    const int nE = nEb[rowIdx];              // wave-uniform
    const float b2A = b2[h0], b2B = b2[h0 + 1], b2C = b2[h0 + 2], b2D = b2[h0 + 3];
    const float ebA = __expf(beta[h0]     - 10.f);
    const float ebB = __expf(beta[h0 + 1] - 10.f);
    const float ebC = __expf(beta[h0 + 2] - 10.f);
    const float ebD = __expf(beta[h0 + 3] - 10.f);

    const float* qA = Qb + (size_t)rowIdx * EE + h0 * DD;    // uniform -> SGPR
    const float* qB = qA + DD;
    const float* qC = qA + 2 * DD;
    const float* qD = qA + 3 * DD;
    const float* w10A = W1 + h0 * 32;
    const float* w11A = w10A + 16;
    const float* b1A  = b1 + h0 * 16;
    const float* w2A  = W2 + h0 * 16;

    // ---- scoring: lane e = edge e, 4 heads (independent chains) ----
    int c0 = 0, c1 = 0;
    float pA0 = 0.f, pB0 = 0.f, pC0 = 0.f, pD0 = 0.f;
    float pA1 = 0.f, pB1 = 0.f, pC1 = 0.f, pD1 = 0.f;
    if (lane < nE) {
        c0 = ecb[rowIdx * MAXE + lane];
        const float cw = ecwb[rowIdx * MAXE + lane];
        pA0 = score_edge(c0, cw, b, h0,     qA, Kb, w10A,      w11A,      b1A,      w2A,      b2A);
        pB0 = score_edge(c0, cw, b, h0 + 1, qB, Kb, w10A + 32, w11A + 32, b1A + 16, w2A + 16, b2B);
        pC0 = score_edge(c0, cw, b, h0 + 2, qC, Kb, w10A + 64, w11A + 64, b1A + 32, w2A + 32, b2C);
        pD0 = score_edge(c0, cw, b, h0 + 3, qD, Kb, w10A + 96, w11A + 96, b1A + 48, w2A + 48, b2D);
    }
    if (nE > 64) {                           // wave-uniform rare branch
        const int e1 = lane + 64;
        if (e1 < nE) {
            c1 = ecb[rowIdx * MAXE + e1];
            const float cw = ecwb[rowIdx * MAXE + e1];
            pA1 = score_edge(c1, cw, b, h0,     qA, Kb, w10A,      w11A,      b1A,      w2A,      b2A);
            pB1 = score_edge(c1, cw, b, h0 + 1, qB, Kb, w10A + 32, w11A + 32, b1A + 16, w2A + 16, b2B);
            pC1 = score_edge(c1, cw, b, h0 + 2, qC, Kb, w10A + 64, w11A + 64, b1A + 32, w2A + 32, b2C);
            pD1 = score_edge(c1, cw, b, h0 + 3, qD, Kb, w10A + 96, w11A + 96, b1A + 48, w2A + 48, b2D);
        }
    }

    // ---- Z: full-wave reduce, 4 heads ----
    float ZA = pA0 + pA1, ZB = pB0 + pB1, ZC = pC0 + pC1, ZD = pD0 + pD1;
#pragma unroll
    for (int off = 1; off < 64; off <<= 1) {
        ZA += __shfl_xor(ZA, off);
        ZB += __shfl_xor(ZB, off);
        ZC += __shfl_xor(ZC, off);
        ZD += __shfl_xor(ZD, off);
    }

    // ---- PV: 2 edges/iter, 4 heads; unroll 4 -> ~16 loads in flight ----
    const int half = lane >> 5, d = lane & 31;
    const float wA0 = pA0 - ebA, wB0 = pB0 - ebB, wC0 = pC0 - ebC, wD0 = pD0 - ebD;
    float accA = 0.f, accB = 0.f, accC = 0.f, accD = 0.f;
    const int lim0 = (nE < 64) ? nE : 64;
#pragma unroll 4
    for (int eo = 0; eo < lim0; eo += 2) {
        const int e = eo + half;
        const float wa = __shfl(wA0, e & 63);
        const float wb = __shfl(wB0, e & 63);
        const float wc = __shfl(wC0, e & 63);
        const float wd = __shfl(wD0, e & 63);
        const int   ce = __shfl(c0, e & 63);   // c0=0 on invalid lanes: safe
        const bool ok = e < lim0;
        const size_t vb0 = ((size_t)b * CC + ce) * EE + h0 * DD + d;
        const float vA = Vb[vb0];
        const float vB = Vb[vb0 + DD];
        const float vC = Vb[vb0 + 2 * DD];
        const float vD = Vb[vb0 + 3 * DD];
        accA = fmaf(ok ? wa : 0.f, vA, accA);
        accB = fmaf(ok ? wb : 0.f, vB, accB);
        accC = fmaf(ok ? wc : 0.f, vC, accC);
        accD = fmaf(ok ? wd : 0.f, vD, accD);
    }
    if (nE > 64) {
        const float wA1 = pA1 - ebA, wB1 = pB1 - ebB, wC1 = pC1 - ebC, wD1 = pD1 - ebD;
        for (int eo = 64; eo < nE; eo += 2) {
            const int e = eo + half;
            const float wa = __shfl(wA1, (e - 64) & 63);
            const float wb = __shfl(wB1, (e - 64) & 63);
            const float wc = __shfl(wC1, (e - 64) & 63);
            const float wd = __shfl(wD1, (e - 64) & 63);
            const int   ce = __shfl(c1, (e - 64) & 63);
            const bool ok = e < nE;
            const size_t vb0 = ((size_t)b * CC + ce) * EE + h0 * DD + d;
            const float vA = Vb[vb0];
            const float vB = Vb[vb0 + DD];
            const float vC = Vb[vb0 + 2 * DD];
            const float vD = Vb[vb0 + 3 * DD];
            accA = fmaf(ok ? wa : 0.f, vA, accA);
            accB = fmaf(ok ? wb : 0.f, vB, accB);
            accC = fmaf(ok ? wc : 0.f, vC, accC);
            accD = fmaf(ok ? wd : 0.f, vD, accD);
        }
    }
    accA += __shfl_xor(accA, 32);
    accB += __shfl_xor(accB, 32);
    accC += __shfl_xor(accC, 32);
    accD += __shfl_xor(accD, 32);

    // ---- epilogue: background via Vsum, write packed hi/lo bf16 ----
    if (lane < 32) {
        const float bgZ = (float)(CC - nE);
        const float invA = 1.f / (ZA + bgZ * ebA);
        const float invB = 1.f / (ZB + bgZ * ebB);
        const float invC = 1.f / (ZC + bgZ * ebC);
        const float invD = 1.f / (ZD + bgZ * ebD);
        const float* vsp = Vsum + (b * HH + h0) * DD + d;
        const float oA = (accA + ebA * vsp[0])      * invA;
        const float oB = (accB + ebB * vsp[DD])     * invB;
        const float oC = (accC + ebC * vsp[2 * DD]) * invC;
        const float oD = (accD + ebD * vsp[3 * DD]) * invD;
        const int rm = rowIdx;
        const int base_in = (d >> 3) * 128 + (rm & 15) * 8 + (d & 7);
        ushort oh, ol;
        split1(oA, oh, ol);
        int dst = ((rm >> 4) * 16 + h0) * 512 + base_in;
        Hbh[dst] = oh; Hbl[dst] = ol;
        split1(oB, oh, ol);
        dst = ((rm >> 4) * 16 + h0 + 1) * 512 + base_in;
        Hbh[dst] = oh; Hbl[dst] = ol;
        split1(oC, oh, ol);
        dst = ((rm >> 4) * 16 + h0 + 2) * 512 + base_in;
        Hbh[dst] = oh; Hbl[dst] = ol;
        split1(oD, oh, ol);
        dst = ((rm >> 4) * 16 + h0 + 3) * 512 + base_in;
        Hbh[dst] = oh; Hbl[dst] = ol;
    }
}

// ---------------------------------------------------------------------------
extern "C" void kernel_launch(void* const* d_in, const int* in_sizes, int n_in,
                              void* d_out, int out_size, void* d_ws, size_t ws_size,
                              hipStream_t stream)
{
    const float* rowe = (const float*)d_in[0];
    const float* cole = (const float*)d_in[1];
    const float* cost = (const float*)d_in[2];
    const float* Wq   = (const float*)d_in[3];
    const float* bq   = (const float*)d_in[4];
    const float* Wk   = (const float*)d_in[5];
    const float* bk   = (const float*)d_in[6];
    const float* Wv   = (const float*)d_in[7];
    const float* bv   = (const float*)d_in[8];
    const float* Wo   = (const float*)d_in[9];
    const float* bo   = (const float*)d_in[10];
    const float* W1   = (const float*)d_in[11];
    const float* b1   = (const float*)d_in[12];
    const float* W2   = (const float*)d_in[13];
    const float* b2   = (const float*)d_in[14];
    const float* beta = (const float*)d_in[15];
    float* out = (float*)d_out;

    // ---- workspace carve ----
    char* cur = (char*)d_ws;
    float* Qb   = (float*)cur; cur += (size_t)MROWS * EE * 4;
    float* Kb   = (float*)cur; cur += (size_t)MROWS * EE * 4;
    float* Vb   = (float*)cur; cur += (size_t)MROWS * EE * 4;
    float* Vsum = (float*)cur; cur += (size_t)BB * HH * DD * 4;
    ushort* reh = (ushort*)cur; cur += (size_t)MROWS * EE * 2;
    ushort* rel = (ushort*)cur; cur += (size_t)MROWS * EE * 2;
    ushort* ceh = (ushort*)cur; cur += (size_t)MROWS * EE * 2;
    ushort* cel = (ushort*)cur; cur += (size_t)MROWS * EE * 2;
    ushort* wqh = (ushort*)cur; cur += (size_t)EE * EE * 2;
    ushort* wql = (ushort*)cur; cur += (size_t)EE * EE * 2;
    ushort* wkh = (ushort*)cur; cur += (size_t)EE * EE * 2;
    ushort* wkl = (ushort*)cur; cur += (size_t)EE * EE * 2;
    ushort* wvh = (ushort*)cur; cur += (size_t)EE * EE * 2;
    ushort* wvl = (ushort*)cur; cur += (size_t)EE * EE * 2;
    ushort* woh = (ushort*)cur; cur += (size_t)EE * EE * 2;
    ushort* wol = (ushort*)cur; cur += (size_t)EE * EE * 2;
    ushort* hbh = (ushort*)cur; cur += (size_t)MROWS * EE * 2;
    ushort* hbl = (ushort*)cur; cur += (size_t)MROWS * EE * 2;
    int*    ecb = (int*)cur;   cur += (size_t)MROWS * MAXE * 4;
    float* ecwb = (float*)cur; cur += (size_t)MROWS * MAXE * 4;
    int*    nEb = (int*)cur;   cur += (size_t)MROWS * 4;
    float* colesum = (float*)cur; cur += (size_t)BB * EE * 4;

    split_kernel<<<dim3(768, 8), 256, 0, stream>>>(
        rowe, cole, Wq, Wk, Wv, Wo, cost,
        reh, rel, ceh, cel, wqh, wql, wkh, wkl, wvh, wvl, woh, wol,
        ecb, ecwb, nEb, colesum);

    dim3 gv(16, 4);
    vsum_kernel<<<gv, 256, 0, stream>>>(colesum, Wv, bv, Vsum);

    dim3 g1(16, 24, 3);
    qkv_kernel<<<g1, 256, 0, stream>>>(reh, rel, ceh, cel,
                                       wqh, wql, wkh, wkl, wvh, wvl,
                                       bq, bk, bv, Qb, Kb, Vb);

    dim3 g2(8, RR, 2);   // x = (b,hh) -> XCD pin; y = row; z = head-quad
    attn_kernel<<<g2, 64, 0, stream>>>(Qb, Kb, Vb, ecb, ecwb, nEb,
                                       W1, b1, W2, b2, beta, Vsum, hbh, hbl);

    dim3 g3(16, 24, 1);
    oproj_kernel<<<g3, 256, 0, stream>>>(hbh, hbl, woh, wol, bo, out);
}

// Round 19
// 79.084 us; speedup vs baseline: 1.3725x; 1.0548x over previous
//
#include <hip/hip_runtime.h>

// Problem constants
#define BB 4
#define RR 384
#define CC 384
#define EE 512
#define HH 16
#define DD 32
#define MROWS 1536   // B*R = B*C
#define MAXE 128     // edge-list stride (nE ~ 38 +- 6; 128 = 15 sigma)

typedef __attribute__((ext_vector_type(8))) short bf16x8;   // 8 bf16 = 4 VGPRs
typedef __attribute__((ext_vector_type(4))) float f32x4;

// ---------------------------------------------------------------------------
// f32 -> (hi, lo) bf16 split, RNE both times. x ~= hi + lo with ~2^-16 rel err.
// ---------------------------------------------------------------------------
__device__ __forceinline__ void split1(float x, ushort& h, ushort& l)
{
    const unsigned u = __float_as_uint(x);
    const unsigned r = (u + 0x7fffu + ((u >> 16) & 1u)) >> 16;
    h = (ushort)r;
    const float hf = __uint_as_float(r << 16);
    const float lo = x - hf;
    const unsigned u2 = __float_as_uint(lo);
    l = (ushort)((u2 + 0x7fffu + ((u2 >> 16) & 1u)) >> 16);
}

// Packed fragment address for element (r, k) of a [rows][512] matrix:
// lane l of the wave covering (r-tile, k-tile) reads elems [l*8, l*8+8).
__device__ __forceinline__ int packed_addr(int r, int k)
{
    return ((r >> 4) * 16 + (k >> 5)) * 512 + ((k >> 3) & 3) * 128 + (r & 15) * 8 + (k & 7);
}

// ---------------------------------------------------------------------------
// Split kernel: 6 arrays -> hi/lo bf16 planes in PACKED fragment layout.
// y == 6: fused edge-compaction [R15-proven].
// y == 7: colesum[b][e] = sum_c cole[b][c][e]  (8 blocks; feeds Vsum GEMV).
// ---------------------------------------------------------------------------
__global__ __launch_bounds__(256) void split_kernel(
    const float* __restrict__ rowe, const float* __restrict__ cole,
    const float* __restrict__ Wq, const float* __restrict__ Wk,
    const float* __restrict__ Wv, const float* __restrict__ Wo,
    const float* __restrict__ cost,
    ushort* __restrict__ reh, ushort* __restrict__ rel,
    ushort* __restrict__ ceh, ushort* __restrict__ cel,
    ushort* __restrict__ wqh, ushort* __restrict__ wql,
    ushort* __restrict__ wkh, ushort* __restrict__ wkl,
    ushort* __restrict__ wvh, ushort* __restrict__ wvl,
    ushort* __restrict__ woh, ushort* __restrict__ wol,
    int* __restrict__ ecb, float* __restrict__ ecwb, int* __restrict__ nEb,
    float* __restrict__ colesum)
{
    if (blockIdx.y == 6) {
        if (blockIdx.x >= MROWS / 4) return;
        const int rowIdx = blockIdx.x * 4 + (threadIdx.x >> 6);
        const int lane = threadIdx.x & 63;
        const float* crow = cost + (size_t)rowIdx * CC;
        const unsigned long long prefix = (1ull << lane) - 1ull;
        int nE = 0;
#pragma unroll
        for (int j = 0; j < 6; ++j) {
            const float cw = crow[lane + 64 * j];
            const unsigned long long mk = __ballot(cw > 0.f);
            if (cw > 0.f) {
                const int slot = nE + __popcll(mk & prefix);
                if (slot < MAXE) {
                    ecb [rowIdx * MAXE + slot] = lane + 64 * j;
                    ecwb[rowIdx * MAXE + slot] = cw;
                }
            }
            nE += __popcll(mk);
        }
        if (lane == 0) nEb[rowIdx] = (nE < MAXE) ? nE : MAXE;
        return;
    }
    if (blockIdx.y == 7) {
        // colesum: 8 blocks, (b, e-half). Coalesced 1KB reads per c-step.
        if (blockIdx.x >= 8) return;
        const int b = blockIdx.x >> 1;
        const int e = (blockIdx.x & 1) * 256 + threadIdx.x;
        float s = 0.f;
        const float* cp = cole + (size_t)b * CC * EE + e;
        for (int c = 0; c < CC; ++c) s += cp[(size_t)c * EE];
        colesum[b * EE + e] = s;
        return;
    }

    const float* src; ushort* dh; ushort* dl; int n;
    switch (blockIdx.y) {
    case 0: src = rowe; dh = reh; dl = rel; n = MROWS * EE; break;
    case 1: src = cole; dh = ceh; dl = cel; n = MROWS * EE; break;
    case 2: src = Wq;   dh = wqh; dl = wql; n = EE * EE;    break;
    case 3: src = Wk;   dh = wkh; dl = wkl; n = EE * EE;    break;
    case 4: src = Wv;   dh = wvh; dl = wvl; n = EE * EE;    break;
    default: src = Wo;  dh = woh; dl = wol; n = EE * EE;    break;
    }
    const int i4 = blockIdx.x * 256 + threadIdx.x;
    if (i4 * 4 >= n) return;
    const float4 v = ((const float4*)src)[i4];
    ushort4 hs, ls;
    split1(v.x, hs.x, ls.x);
    split1(v.y, hs.y, ls.y);
    split1(v.z, hs.z, ls.z);
    split1(v.w, hs.w, ls.w);
    const int e0 = i4 * 4;
    const int dst = packed_addr(e0 >> 9, e0 & 511);   // (k&7) in {0,4}: aligned
    *(ushort4*)(dh + dst) = hs;
    *(ushort4*)(dl + dst) = ls;
}

// ---------------------------------------------------------------------------
// Fine-grained GEMM body: 2 n-tiles per wave (16x32), split accumulators
// (6 independent MFMA chains) [R17].
// ---------------------------------------------------------------------------
__device__ __forceinline__ void gemm_bf16x3_body2(
    const ushort* __restrict__ Ahi, const ushort* __restrict__ Alo,
    const ushort* __restrict__ Whi, const ushort* __restrict__ Wlo,
    const float* __restrict__ bias, float* __restrict__ Y,
    int Mt, int Nt0)
{
    constexpr int N = 512;
    const int lane = threadIdx.x & 63;
    const int col = lane & 15, kgrp = lane >> 4;

    const ushort* pah = Ahi + (size_t)Mt * 8192 + lane * 8;
    const ushort* pal = Alo + (size_t)Mt * 8192 + lane * 8;
    const ushort* pbh = Whi + (size_t)Nt0 * 8192 + lane * 8;
    const ushort* pbl = Wlo + (size_t)Nt0 * 8192 + lane * 8;

    f32x4 a0hh = {}, a0hl = {}, a0lh = {};
    f32x4 a1hh = {}, a1hl = {}, a1lh = {};

#pragma unroll 4
    for (int kt = 0; kt < 16; ++kt) {
        const int ko = kt * 512;
        const bf16x8 ah  = *(const bf16x8*)(pah + ko);
        const bf16x8 al  = *(const bf16x8*)(pal + ko);
        const bf16x8 bh0 = *(const bf16x8*)(pbh + ko);
        const bf16x8 bh1 = *(const bf16x8*)(pbh + ko + 8192);
        const bf16x8 bl0 = *(const bf16x8*)(pbl + ko);
        const bf16x8 bl1 = *(const bf16x8*)(pbl + ko + 8192);
        a0hh = __builtin_amdgcn_mfma_f32_16x16x32_bf16(ah, bh0, a0hh, 0, 0, 0);
        a0hl = __builtin_amdgcn_mfma_f32_16x16x32_bf16(ah, bl0, a0hl, 0, 0, 0);
        a0lh = __builtin_amdgcn_mfma_f32_16x16x32_bf16(al, bh0, a0lh, 0, 0, 0);
        a1hh = __builtin_amdgcn_mfma_f32_16x16x32_bf16(ah, bh1, a1hh, 0, 0, 0);
        a1hl = __builtin_amdgcn_mfma_f32_16x16x32_bf16(ah, bl1, a1hl, 0, 0, 0);
        a1lh = __builtin_amdgcn_mfma_f32_16x16x32_bf16(al, bh1, a1lh, 0, 0, 0);
    }

    f32x4 accs[2];
#pragma unroll
    for (int j = 0; j < 4; ++j) {
        accs[0][j] = (a0hh[j] + a0hl[j]) + a0lh[j];
        accs[1][j] = (a1hh[j] + a1hl[j]) + a1lh[j];
    }
#pragma unroll
    for (int t = 0; t < 2; ++t) {
        const int n = (Nt0 + t) * 16 + col;
        const float bn = bias[n];
#pragma unroll
        for (int j = 0; j < 4; ++j) {
            const int m = Mt * 16 + kgrp * 4 + j;
            Y[m * N + n] = accs[t][j] + bn;
        }
    }
}

// ---------------------------------------------------------------------------
// qkv: grid (16, 24, 4), 256 thr. z<3: GEMMs (wave tile 16m x 32n).
// z==3: fused Vsum GEMV (64 blocks) -- Vsum[b][h][d] =
//   dot(colesum[b], Wv[h*32+d]) + 384*bv[h*32+d]. Inputs are all from the
//   PRIOR split launch or kernel inputs; output consumed by the NEXT (attn)
//   launch -> no intra-launch ordering needed.
// ---------------------------------------------------------------------------
__global__ __launch_bounds__(256) void qkv_kernel(
    const ushort* __restrict__ reh, const ushort* __restrict__ rel,
    const ushort* __restrict__ ceh, const ushort* __restrict__ cel,
    const ushort* __restrict__ wqh, const ushort* __restrict__ wql,
    const ushort* __restrict__ wkh, const ushort* __restrict__ wkl,
    const ushort* __restrict__ wvh, const ushort* __restrict__ wvl,
    const float* __restrict__ bq, const float* __restrict__ bk,
    const float* __restrict__ bv,
    const float* __restrict__ colesum, const float* __restrict__ Wvf,
    float* __restrict__ Vsum,
    float* __restrict__ Qo, float* __restrict__ Ko, float* __restrict__ Vo)
{
    __shared__ float part[256];
    if (blockIdx.z == 3) {
        if (blockIdx.y >= 4) return;
        const int h = blockIdx.x, b = blockIdx.y;
        const int d = threadIdx.x >> 3;      // 0..31
        const int pt = threadIdx.x & 7;      // 0..7
        const float* cs = colesum + b * EE + pt * 64;
        const float* wr = Wvf + (size_t)(h * DD + d) * EE + pt * 64;
        float acc = 0.f;
#pragma unroll 8
        for (int k = 0; k < 64; ++k) acc = fmaf(cs[k], wr[k], acc);
        part[threadIdx.x] = acc;
        __syncthreads();
        if (pt == 0) {
            float s = 0.f;
#pragma unroll
            for (int q = 0; q < 8; ++q) s += part[d * 8 + q];
            Vsum[(b * HH + h) * DD + d] = s + 384.f * bv[h * DD + d];
        }
        return;
    }

    const int l = blockIdx.x + (blockIdx.y << 4);
    const int a = l & 7;
    const int t = l >> 3;
    const int Bm = a * 3 + (t >> 4);
    const int Bx = t & 15;
    const int Mt = Bm * 4 + (threadIdx.x >> 6);
    const int Nt0 = Bx * 2;
    if (blockIdx.z == 0)      gemm_bf16x3_body2(reh, rel, wqh, wql, bq, Qo, Mt, Nt0);
    else if (blockIdx.z == 1) gemm_bf16x3_body2(ceh, cel, wkh, wkl, bk, Ko, Mt, Nt0);
    else                      gemm_bf16x3_body2(ceh, cel, wvh, wvl, bv, Vo, Mt, Nt0);
}

// oproj: grid (16, 24, 1), fine-grained body2.
__global__ __launch_bounds__(256) void oproj_kernel(
    const ushort* __restrict__ hbh, const ushort* __restrict__ hbl,
    const ushort* __restrict__ woh, const ushort* __restrict__ wol,
    const float* __restrict__ bo, float* __restrict__ out)
{
    const int l = blockIdx.x + (blockIdx.y << 4);
    const int a = l & 7;
    const int t = l >> 3;
    const int Bm = a * 3 + (t >> 4);
    const int Bx = t & 15;
    const int Mt = Bm * 4 + (threadIdx.x >> 6);
    const int Nt0 = Bx * 2;
    gemm_bf16x3_body2(hbh, hbl, woh, wol, bo, out, Mt, Nt0);
}

// ---------------------------------------------------------------------------
// Edge scorer: dot(q,k) -> per-head 2x16x1 MLP -> p = exp(tanh*10 - 10).
// All q / MLP params come from wave-uniform addresses -> SGPRs.
// ---------------------------------------------------------------------------
__device__ __forceinline__ float score_edge(
    int c, float cw, int b, int h,
    const float* __restrict__ qrow, const float* __restrict__ Kb,
    const float* __restrict__ w10p, const float* __restrict__ w11p,
    const float* __restrict__ b1p, const float* __restrict__ w2p, float b2h)
{
    const float* kp = Kb + ((size_t)b * CC + c) * EE + h * DD;
    float d0 = 0.f, d1 = 0.f, d2 = 0.f, d3 = 0.f;
#pragma unroll
    for (int dq = 0; dq < 8; ++dq) {
        const float4 kv = *(const float4*)(kp + dq * 4);
        d0 = fmaf(qrow[dq * 4 + 0], kv.x, d0);
        d1 = fmaf(qrow[dq * 4 + 1], kv.y, d1);
        d2 = fmaf(qrow[dq * 4 + 2], kv.z, d2);
        d3 = fmaf(qrow[dq * 4 + 3], kv.w, d3);
    }
    const float dot = ((d0 + d1) + (d2 + d3)) * 0.17677669529663687f;
    float l0 = b2h, l1 = 0.f;
#pragma unroll
    for (int mm = 0; mm < 16; mm += 2) {
        const float h0 = fmaf(dot, w10p[mm],     fmaf(cw, w11p[mm],     b1p[mm]));
        const float h1 = fmaf(dot, w10p[mm + 1], fmaf(cw, w11p[mm + 1], b1p[mm + 1]));
        l0 = fmaf(fmaxf(h0, 0.f), w2p[mm],     l0);
        l1 = fmaf(fmaxf(h1, 0.f), w2p[mm + 1], l1);
    }
    // s = tanh(l)*10; p = exp(s-10) = exp(-20/(e^{2l}+1)); bounded (no ovf).
    const float ex = __expf(2.f * (l0 + l1));
    return __expf(-20.f / (ex + 1.f));
}

// ---------------------------------------------------------------------------
// Semi-sparse attention: champion, UNCHANGED. ONE WAVE per (b,r,head-quad),
// PV loop unroll 4. Fixed-max-10 softmax:
//   out = (sum_E (p_e - e^{b-10}) V_e + e^{b-10} Vsum) / (sum p + (C-nE) e^{b-10})
// Grid (8, RR, 2): blockIdx.x = (b,hh) -> XCD pin (R6: FETCH -55%).
// ---------------------------------------------------------------------------
__global__ __launch_bounds__(64) void attn_kernel(
    const float* __restrict__ Qb, const float* __restrict__ Kb,
    const float* __restrict__ Vb,
    const int* __restrict__ ecb, const float* __restrict__ ecwb,
    const int* __restrict__ nEb,
    const float* __restrict__ W1, const float* __restrict__ b1,
    const float* __restrict__ W2, const float* __restrict__ b2,
    const float* __restrict__ beta,
    const float* __restrict__ Vsum,
    ushort* __restrict__ Hbh, ushort* __restrict__ Hbl)
{
    const int combo = blockIdx.x;            // 0..7 -> XCD
    const int b = combo >> 1, hh = combo & 1;
    const int r = blockIdx.y;
    const int h0 = hh * 8 + blockIdx.z * 4;  // this wave: heads h0..h0+3
    const int lane = threadIdx.x;
    const int rowIdx = b * RR + r;

    const int nE = nEb[rowIdx];              // wave-uniform
    const float b2A = b2[h0], b2B = b2[h0 + 1], b2C = b2[h0 + 2], b2D = b2[h0 + 3];
    const float ebA = __expf(beta[h0]     - 10.f);
    const float ebB = __expf(beta[h0 + 1] - 10.f);
    const float ebC = __expf(beta[h0 + 2] - 10.f);
    const float ebD = __expf(beta[h0 + 3] - 10.f);

    const float* qA = Qb + (size_t)rowIdx * EE + h0 * DD;    // uniform -> SGPR
    const float* qB = qA + DD;
    const float* qC = qA + 2 * DD;
    const float* qD = qA + 3 * DD;
    const float* w10A = W1 + h0 * 32;
    const float* w11A = w10A + 16;
    const float* b1A  = b1 + h0 * 16;
    const float* w2A  = W2 + h0 * 16;

    // ---- scoring: lane e = edge e, 4 heads (independent chains) ----
    int c0 = 0, c1 = 0;
    float pA0 = 0.f, pB0 = 0.f, pC0 = 0.f, pD0 = 0.f;
    float pA1 = 0.f, pB1 = 0.f, pC1 = 0.f, pD1 = 0.f;
    if (lane < nE) {
        c0 = ecb[rowIdx * MAXE + lane];
        const float cw = ecwb[rowIdx * MAXE + lane];
        pA0 = score_edge(c0, cw, b, h0,     qA, Kb, w10A,      w11A,      b1A,      w2A,      b2A);
        pB0 = score_edge(c0, cw, b, h0 + 1, qB, Kb, w10A + 32, w11A + 32, b1A + 16, w2A + 16, b2B);
        pC0 = score_edge(c0, cw, b, h0 + 2, qC, Kb, w10A + 64, w11A + 64, b1A + 32, w2A + 32, b2C);
        pD0 = score_edge(c0, cw, b, h0 + 3, qD, Kb, w10A + 96, w11A + 96, b1A + 48, w2A + 48, b2D);
    }
    if (nE > 64) {                           // wave-uniform rare branch
        const int e1 = lane + 64;
        if (e1 < nE) {
            c1 = ecb[rowIdx * MAXE + e1];
            const float cw = ecwb[rowIdx * MAXE + e1];
            pA1 = score_edge(c1, cw, b, h0,     qA, Kb, w10A,      w11A,      b1A,      w2A,      b2A);
            pB1 = score_edge(c1, cw, b, h0 + 1, qB, Kb, w10A + 32, w11A + 32, b1A + 16, w2A + 16, b2B);
            pC1 = score_edge(c1, cw, b, h0 + 2, qC, Kb, w10A + 64, w11A + 64, b1A + 32, w2A + 32, b2C);
            pD1 = score_edge(c1, cw, b, h0 + 3, qD, Kb, w10A + 96, w11A + 96, b1A + 48, w2A + 48, b2D);
        }
    }

    // ---- Z: full-wave reduce, 4 heads ----
    float ZA = pA0 + pA1, ZB = pB0 + pB1, ZC = pC0 + pC1, ZD = pD0 + pD1;
#pragma unroll
    for (int off = 1; off < 64; off <<= 1) {
        ZA += __shfl_xor(ZA, off);
        ZB += __shfl_xor(ZB, off);
        ZC += __shfl_xor(ZC, off);
        ZD += __shfl_xor(ZD, off);
    }

    // ---- PV: 2 edges/iter, 4 heads; unroll 4 -> ~16 loads in flight ----
    const int half = lane >> 5, d = lane & 31;
    const float wA0 = pA0 - ebA, wB0 = pB0 - ebB, wC0 = pC0 - ebC, wD0 = pD0 - ebD;
    float accA = 0.f, accB = 0.f, accC = 0.f, accD = 0.f;
    const int lim0 = (nE < 64) ? nE : 64;
#pragma unroll 4
    for (int eo = 0; eo < lim0; eo += 2) {
        const int e = eo + half;
        const float wa = __shfl(wA0, e & 63);
        const float wb = __shfl(wB0, e & 63);
        const float wc = __shfl(wC0, e & 63);
        const float wd = __shfl(wD0, e & 63);
        const int   ce = __shfl(c0, e & 63);   // c0=0 on invalid lanes: safe
        const bool ok = e < lim0;
        const size_t vb0 = ((size_t)b * CC + ce) * EE + h0 * DD + d;
        const float vA = Vb[vb0];
        const float vB = Vb[vb0 + DD];
        const float vC = Vb[vb0 + 2 * DD];
        const float vD = Vb[vb0 + 3 * DD];
        accA = fmaf(ok ? wa : 0.f, vA, accA);
        accB = fmaf(ok ? wb : 0.f, vB, accB);
        accC = fmaf(ok ? wc : 0.f, vC, accC);
        accD = fmaf(ok ? wd : 0.f, vD, accD);
    }
    if (nE > 64) {
        const float wA1 = pA1 - ebA, wB1 = pB1 - ebB, wC1 = pC1 - ebC, wD1 = pD1 - ebD;
        for (int eo = 64; eo < nE; eo += 2) {
            const int e = eo + half;
            const float wa = __shfl(wA1, (e - 64) & 63);
            const float wb = __shfl(wB1, (e - 64) & 63);
            const float wc = __shfl(wC1, (e - 64) & 63);
            const float wd = __shfl(wD1, (e - 64) & 63);
            const int   ce = __shfl(c1, (e - 64) & 63);
            const bool ok = e < nE;
            const size_t vb0 = ((size_t)b * CC + ce) * EE + h0 * DD + d;
            const float vA = Vb[vb0];
            const float vB = Vb[vb0 + DD];
            const float vC = Vb[vb0 + 2 * DD];
            const float vD = Vb[vb0 + 3 * DD];
            accA = fmaf(ok ? wa : 0.f, vA, accA);
            accB = fmaf(ok ? wb : 0.f, vB, accB);
            accC = fmaf(ok ? wc : 0.f, vC, accC);
            accD = fmaf(ok ? wd : 0.f, vD, accD);
        }
    }
    accA += __shfl_xor(accA, 32);
    accB += __shfl_xor(accB, 32);
    accC += __shfl_xor(accC, 32);
    accD += __shfl_xor(accD, 32);

    // ---- epilogue: background via Vsum, write packed hi/lo bf16 ----
    if (lane < 32) {
        const float bgZ = (float)(CC - nE);
        const float invA = 1.f / (ZA + bgZ * ebA);
        const float invB = 1.f / (ZB + bgZ * ebB);
        const float invC = 1.f / (ZC + bgZ * ebC);
        const float invD = 1.f / (ZD + bgZ * ebD);
        const float* vsp = Vsum + (b * HH + h0) * DD + d;
        const float oA = (accA + ebA * vsp[0])      * invA;
        const float oB = (accB + ebB * vsp[DD])     * invB;
        const float oC = (accC + ebC * vsp[2 * DD]) * invC;
        const float oD = (accD + ebD * vsp[3 * DD]) * invD;
        const int rm = rowIdx;
        const int base_in = (d >> 3) * 128 + (rm & 15) * 8 + (d & 7);
        ushort oh, ol;
        split1(oA, oh, ol);
        int dst = ((rm >> 4) * 16 + h0) * 512 + base_in;
        Hbh[dst] = oh; Hbl[dst] = ol;
        split1(oB, oh, ol);
        dst = ((rm >> 4) * 16 + h0 + 1) * 512 + base_in;
        Hbh[dst] = oh; Hbl[dst] = ol;
        split1(oC, oh, ol);
        dst = ((rm >> 4) * 16 + h0 + 2) * 512 + base_in;
        Hbh[dst] = oh; Hbl[dst] = ol;
        split1(oD, oh, ol);
        dst = ((rm >> 4) * 16 + h0 + 3) * 512 + base_in;
        Hbh[dst] = oh; Hbl[dst] = ol;
    }
}

// ---------------------------------------------------------------------------
extern "C" void kernel_launch(void* const* d_in, const int* in_sizes, int n_in,
                              void* d_out, int out_size, void* d_ws, size_t ws_size,
                              hipStream_t stream)
{
    const float* rowe = (const float*)d_in[0];
    const float* cole = (const float*)d_in[1];
    const float* cost = (const float*)d_in[2];
    const float* Wq   = (const float*)d_in[3];
    const float* bq   = (const float*)d_in[4];
    const float* Wk   = (const float*)d_in[5];
    const float* bk   = (const float*)d_in[6];
    const float* Wv   = (const float*)d_in[7];
    const float* bv   = (const float*)d_in[8];
    const float* Wo   = (const float*)d_in[9];
    const float* bo   = (const float*)d_in[10];
    const float* W1   = (const float*)d_in[11];
    const float* b1   = (const float*)d_in[12];
    const float* W2   = (const float*)d_in[13];
    const float* b2   = (const float*)d_in[14];
    const float* beta = (const float*)d_in[15];
    float* out = (float*)d_out;

    // ---- workspace carve ----
    char* cur = (char*)d_ws;
    float* Qb   = (float*)cur; cur += (size_t)MROWS * EE * 4;
    float* Kb   = (float*)cur; cur += (size_t)MROWS * EE * 4;
    float* Vb   = (float*)cur; cur += (size_t)MROWS * EE * 4;
    float* Vsum = (float*)cur; cur += (size_t)BB * HH * DD * 4;
    ushort* reh = (ushort*)cur; cur += (size_t)MROWS * EE * 2;
    ushort* rel = (ushort*)cur; cur += (size_t)MROWS * EE * 2;
    ushort* ceh = (ushort*)cur; cur += (size_t)MROWS * EE * 2;
    ushort* cel = (ushort*)cur; cur += (size_t)MROWS * EE * 2;
    ushort* wqh = (ushort*)cur; cur += (size_t)EE * EE * 2;
    ushort* wql = (ushort*)cur; cur += (size_t)EE * EE * 2;
    ushort* wkh = (ushort*)cur; cur += (size_t)EE * EE * 2;
    ushort* wkl = (ushort*)cur; cur += (size_t)EE * EE * 2;
    ushort* wvh = (ushort*)cur; cur += (size_t)EE * EE * 2;
    ushort* wvl = (ushort*)cur; cur += (size_t)EE * EE * 2;
    ushort* woh = (ushort*)cur; cur += (size_t)EE * EE * 2;
    ushort* wol = (ushort*)cur; cur += (size_t)EE * EE * 2;
    ushort* hbh = (ushort*)cur; cur += (size_t)MROWS * EE * 2;
    ushort* hbl = (ushort*)cur; cur += (size_t)MROWS * EE * 2;
    int*    ecb = (int*)cur;   cur += (size_t)MROWS * MAXE * 4;
    float* ecwb = (float*)cur; cur += (size_t)MROWS * MAXE * 4;
    int*    nEb = (int*)cur;   cur += (size_t)MROWS * 4;
    float* colesum = (float*)cur; cur += (size_t)BB * EE * 4;

    split_kernel<<<dim3(768, 8), 256, 0, stream>>>(
        rowe, cole, Wq, Wk, Wv, Wo, cost,
        reh, rel, ceh, cel, wqh, wql, wkh, wkl, wvh, wvl, woh, wol,
        ecb, ecwb, nEb, colesum);

    dim3 g1(16, 24, 4);   // z<3: QKV GEMMs; z==3: fused Vsum GEMV (64 blocks)
    qkv_kernel<<<g1, 256, 0, stream>>>(reh, rel, ceh, cel,
                                       wqh, wql, wkh, wkl, wvh, wvl,
                                       bq, bk, bv, colesum, Wv, Vsum,
                                       Qb, Kb, Vb);

    dim3 g2(8, RR, 2);   // x = (b,hh) -> XCD pin; y = row; z = head-quad
    attn_kernel<<<g2, 64, 0, stream>>>(Qb, Kb, Vb, ecb, ecwb, nEb,
                                       W1, b1, W2, b2, beta, Vsum, hbh, hbl);

    dim3 g3(16, 24, 1);
    oproj_kernel<<<g3, 256, 0, stream>>>(hbh, hbl, woh, wol, bo, out);
}